// Round 1
// baseline (77648.950 us; speedup 1.0000x reference)
//
#include <hip/hip_runtime.h>
#include <math.h>

#define BB 16
#define HEADS 8
#define DH 64
#define EPSV 1e-5f

// ---------------------------------------------------------------------------
// Patch embed (4x4/4 conv) + pnorm LN, fused. One block per token (65536),
// 128 threads = 128 output channels.
// out layout: [B, 256, 4, 4, 128] flat -> [65536, 128]
// ---------------------------------------------------------------------------
__global__ __launch_bounds__(128) void patch_ln_kernel(
    const float* __restrict__ x, const float* __restrict__ pw,
    const float* __restrict__ pbias, const float* __restrict__ nw,
    const float* __restrict__ nb, float* __restrict__ out) {
  int tk = blockIdx.x;  // b*4096 + n*16 + i*4 + j
  int t = threadIdx.x;  // channel 0..127
  int b = tk >> 12;
  int n = (tk >> 4) & 255;
  int ii = (tk >> 2) & 3;
  int jj = tk & 3;
  int Y = ((n >> 4) << 2) + ii;  // 0..63
  int X = ((n & 15) << 2) + jj;

  __shared__ float px[48];
  __shared__ float redA[2];
  __shared__ float redB[2];
  if (t < 48) {
    int ci = t >> 4, dy = (t >> 2) & 3, dx = t & 3;
    px[t] = x[((b * 3 + ci) * 256 + (Y * 4 + dy)) * 256 + (X * 4 + dx)];
  }
  __syncthreads();

  float acc = pbias[t];
  const float* wr = pw + t * 48;
#pragma unroll
  for (int q = 0; q < 48; ++q) acc += wr[q] * px[q];

  // LN over 128 channels (2 waves)
  float s = acc;
#pragma unroll
  for (int o = 32; o > 0; o >>= 1) s += __shfl_xor(s, o, 64);
  if ((t & 63) == 0) redA[t >> 6] = s;
  __syncthreads();
  float mean = (redA[0] + redA[1]) * (1.0f / 128.0f);
  float d = acc - mean;
  float sq = d * d;
#pragma unroll
  for (int o = 32; o > 0; o >>= 1) sq += __shfl_xor(sq, o, 64);
  if ((t & 63) == 0) redB[t >> 6] = sq;
  __syncthreads();
  float var = (redB[0] + redB[1]) * (1.0f / 128.0f);
  out[tk * 128 + t] = d * rsqrtf(var + EPSV) * nw[t] + nb[t];
}

// ---------------------------------------------------------------------------
// Fused MLP block: x += fc2( gelu( fc1( LN(x) ) ) ). Token tile TT per block,
// hidden chunked by FCH in LDS, fc2 partials in registers.
// ---------------------------------------------------------------------------
template <int C, int F, int TT, int FCH>
__global__ __launch_bounds__(256) void stem_mlp_kernel(
    float* __restrict__ Xg, const float* __restrict__ n2w,
    const float* __restrict__ n2b, const float* __restrict__ f1w,
    const float* __restrict__ f1b, const float* __restrict__ f2w,
    const float* __restrict__ f2b) {
  constexpr int TPT = 256 / TT;  // threads per token (16/32/64)
  constexpr int NV = C / TPT;    // values per thread in LN phase (=8)
  constexpr int NACC = TT * C / 256;
  __shared__ float xn[TT][C];
  __shared__ float hh[TT][FCH];

  int tid = threadIdx.x;
  int tok0 = blockIdx.x * TT;
  int tt = tid / TPT;
  int ll = tid % TPT;

  // phase 1: load token rows, LayerNorm -> xn
  float v[NV];
  const float* xr = Xg + (tok0 + tt) * C + ll * NV;
#pragma unroll
  for (int q = 0; q < NV; q += 4) {
    float4 t4 = *(const float4*)(xr + q);
    v[q] = t4.x; v[q + 1] = t4.y; v[q + 2] = t4.z; v[q + 3] = t4.w;
  }
  float s = 0.f;
#pragma unroll
  for (int q = 0; q < NV; ++q) s += v[q];
#pragma unroll
  for (int o = TPT / 2; o > 0; o >>= 1) s += __shfl_xor(s, o, 64);
  float mean = s * (1.0f / C);
  float sq = 0.f;
#pragma unroll
  for (int q = 0; q < NV; ++q) {
    float d = v[q] - mean;
    sq += d * d;
  }
#pragma unroll
  for (int o = TPT / 2; o > 0; o >>= 1) sq += __shfl_xor(sq, o, 64);
  float rstd = rsqrtf(sq * (1.0f / C) + EPSV);
#pragma unroll
  for (int q = 0; q < NV; ++q) {
    int c = ll * NV + q;
    xn[tt][c] = (v[q] - mean) * rstd * n2w[c] + n2b[c];
  }
  __syncthreads();

  float acc2[NACC];
#pragma unroll
  for (int q = 0; q < NACC; ++q) acc2[q] = 0.f;

  for (int fc0 = 0; fc0 < F; fc0 += FCH) {
    // phase 2: h = gelu(xn @ f1w^T + f1b) for this F-chunk
    for (int f = tid; f < FCH; f += 256) {
      int fg = fc0 + f;
      float a[TT];
#pragma unroll
      for (int t = 0; t < TT; ++t) a[t] = 0.f;
      const float* wr = f1w + fg * C;
      for (int k4 = 0; k4 < C / 4; ++k4) {
        float4 w4 = *(const float4*)(wr + k4 * 4);
#pragma unroll
        for (int t = 0; t < TT; ++t) {
          float4 x4 = *(const float4*)&xn[t][k4 * 4];
          a[t] += w4.x * x4.x + w4.y * x4.y + w4.z * x4.z + w4.w * x4.w;
        }
      }
      float bv = f1b[fg];
#pragma unroll
      for (int t = 0; t < TT; ++t) {
        float z = a[t] + bv;
        hh[t][f] = 0.5f * z * (1.0f + erff(z * 0.70710678118654752f));
      }
    }
    __syncthreads();
    // phase 3: acc2 += h @ f2w_chunk^T
#pragma unroll
    for (int q = 0; q < NACC; ++q) {
      int idx = tid + q * 256;
      int t = idx / C, c = idx % C;
      const float* wr = f2w + c * F + fc0;
      float a = 0.f;
      for (int k4 = 0; k4 < FCH / 4; ++k4) {
        float4 w4 = *(const float4*)(wr + k4 * 4);
        float4 h4 = *(const float4*)&hh[t][k4 * 4];
        a += w4.x * h4.x + w4.y * h4.y + w4.z * h4.z + w4.w * h4.w;
      }
      acc2[q] += a;
    }
    __syncthreads();
  }

  // write: residual add
#pragma unroll
  for (int q = 0; q < NACC; ++q) {
    int idx = tid + q * 256;
    int t = idx / C, c = idx % C;
    Xg[(tok0 + t) * C + c] += acc2[q] + f2b[c];
  }
}

// ---------------------------------------------------------------------------
// Patch merge gather + LN. MODE 0: [B,256,4,4,128] -> 16384 tokens of 512.
// MODE 1: [B,256,2,2,256] -> 4096 tokens of 1024.
// ---------------------------------------------------------------------------
template <int MODE>
__global__ __launch_bounds__(256) void merge_ln_kernel(
    const float* __restrict__ Xin, const float* __restrict__ nw,
    const float* __restrict__ nb, float* __restrict__ out) {
  constexpr int CM = MODE ? 1024 : 512;
  constexpr int NE = CM / 256;
  int ot = blockIdx.x;
  int tid = threadIdx.x;
  __shared__ float redA[4];
  __shared__ float redB[4];

  float v[NE];
#pragma unroll
  for (int e = 0; e < NE; ++e) {
    int cp = tid + e * 256;
    if (MODE == 0) {
      int b = ot >> 10, r = ot & 1023;
      int n = r >> 2, di = (r >> 1) & 1, dj = r & 1;
      int q = cp >> 7, c = cp & 127;
      int i = 2 * di + (q & 1), j = 2 * dj + (q >> 1);
      v[e] = Xin[((b * 256 + n) * 16 + i * 4 + j) * 128 + c];
    } else {
      int b = ot >> 8, n = ot & 255;
      int q = cp >> 8, c = cp & 255;
      int di = q & 1, dj = q >> 1;
      v[e] = Xin[((b * 256 + n) * 4 + di * 2 + dj) * 256 + c];
    }
  }
  float s = 0.f;
#pragma unroll
  for (int e = 0; e < NE; ++e) s += v[e];
#pragma unroll
  for (int o = 32; o > 0; o >>= 1) s += __shfl_xor(s, o, 64);
  if ((tid & 63) == 0) redA[tid >> 6] = s;
  __syncthreads();
  float mean = (redA[0] + redA[1] + redA[2] + redA[3]) * (1.0f / CM);
  float sq = 0.f;
#pragma unroll
  for (int e = 0; e < NE; ++e) {
    float d = v[e] - mean;
    sq += d * d;
  }
#pragma unroll
  for (int o = 32; o > 0; o >>= 1) sq += __shfl_xor(sq, o, 64);
  if ((tid & 63) == 0) redB[tid >> 6] = sq;
  __syncthreads();
  float var = (redB[0] + redB[1] + redB[2] + redB[3]) * (1.0f / CM);
  float rstd = rsqrtf(var + EPSV);
#pragma unroll
  for (int e = 0; e < NE; ++e) {
    int cp = tid + e * 256;
    out[ot * CM + cp] = (v[e] - mean) * rstd * nw[cp] + nb[cp];
  }
}

// ---------------------------------------------------------------------------
// Generic f32 GEMM: C[M,N] = A[M,K] @ W[N,K]^T (+bias) (+epilogue)
// EP 0: none. EP 1: += extra[(m%256)*N + n] (pos embed). EP 2: += extra[m*N+n]
// (residual). 64x64 tile, BK=16, 256 threads, 4x4 micro-tile.
// ---------------------------------------------------------------------------
template <int EP>
__global__ __launch_bounds__(256) void gemm_kernel(
    const float* __restrict__ A, const float* __restrict__ W,
    const float* __restrict__ bias, const float* __restrict__ extra,
    float* __restrict__ Cout, int M, int N, int K) {
  __shared__ float As[16][64];
  __shared__ float Ws[16][64];
  int nb = N >> 6;
  int bx = blockIdx.x % nb, by = blockIdx.x / nb;
  int tid = threadIdx.x;
  int tx = tid & 15, ty = tid >> 4;
  int lr = tid >> 2;
  int lk = (tid & 3) << 2;
  const float* Ag = A + (by * 64 + lr) * K + lk;
  const float* Wg = W + (bx * 64 + lr) * K + lk;

  float acc[4][4];
#pragma unroll
  for (int i = 0; i < 4; ++i)
#pragma unroll
    for (int j = 0; j < 4; ++j) acc[i][j] = 0.f;

  for (int k0 = 0; k0 < K; k0 += 16) {
    float4 av = *(const float4*)(Ag + k0);
    float4 wv = *(const float4*)(Wg + k0);
    As[lk + 0][lr] = av.x; As[lk + 1][lr] = av.y;
    As[lk + 2][lr] = av.z; As[lk + 3][lr] = av.w;
    Ws[lk + 0][lr] = wv.x; Ws[lk + 1][lr] = wv.y;
    Ws[lk + 2][lr] = wv.z; Ws[lk + 3][lr] = wv.w;
    __syncthreads();
#pragma unroll
    for (int k = 0; k < 16; ++k) {
      float4 a4 = *(const float4*)&As[k][ty * 4];
      float4 w4 = *(const float4*)&Ws[k][tx * 4];
      acc[0][0] += a4.x * w4.x; acc[0][1] += a4.x * w4.y;
      acc[0][2] += a4.x * w4.z; acc[0][3] += a4.x * w4.w;
      acc[1][0] += a4.y * w4.x; acc[1][1] += a4.y * w4.y;
      acc[1][2] += a4.y * w4.z; acc[1][3] += a4.y * w4.w;
      acc[2][0] += a4.z * w4.x; acc[2][1] += a4.z * w4.y;
      acc[2][2] += a4.z * w4.z; acc[2][3] += a4.z * w4.w;
      acc[3][0] += a4.w * w4.x; acc[3][1] += a4.w * w4.y;
      acc[3][2] += a4.w * w4.z; acc[3][3] += a4.w * w4.w;
    }
    __syncthreads();
  }

  int m0 = by * 64 + ty * 4, n0 = bx * 64 + tx * 4;
  float4 bv = make_float4(0.f, 0.f, 0.f, 0.f);
  if (bias) bv = *(const float4*)&bias[n0];
#pragma unroll
  for (int i = 0; i < 4; ++i) {
    float4 o;
    o.x = acc[i][0] + bv.x; o.y = acc[i][1] + bv.y;
    o.z = acc[i][2] + bv.z; o.w = acc[i][3] + bv.w;
    if (EP == 1) {
      float4 e4 = *(const float4*)&extra[((m0 + i) & 255) * N + n0];
      o.x += e4.x; o.y += e4.y; o.z += e4.z; o.w += e4.w;
    } else if (EP == 2) {
      float4 e4 = *(const float4*)&extra[(m0 + i) * N + n0];
      o.x += e4.x; o.y += e4.y; o.z += e4.z; o.w += e4.w;
    }
    *(float4*)&Cout[(m0 + i) * N + n0] = o;
  }
}

// ---------------------------------------------------------------------------
// Attention scores + softmax. One block (64 threads) per (b, h, n).
// P[bh][n][m] = softmax_m( q.k * 0.125 + rpb[rpe[n,m]][h] )
// ---------------------------------------------------------------------------
__global__ __launch_bounds__(64) void attn_score_kernel(
    const float* __restrict__ qkv, const float* __restrict__ rpb,
    const int* __restrict__ rpe, float* __restrict__ P) {
  int bid = blockIdx.x;
  int n = bid & 255, h = (bid >> 8) & 7, b = bid >> 11;
  int t = threadIdx.x;
  __shared__ float qsh[64];
  qsh[t] = qkv[(b * 256 + n) * 1536 + h * 64 + t] * 0.125f;
  __syncthreads();

  float s[4];
#pragma unroll
  for (int r = 0; r < 4; ++r) {
    int m = r * 64 + t;
    const float4* kr = (const float4*)(qkv + (b * 256 + m) * 1536 + 512 + h * 64);
    float acc = 0.f;
#pragma unroll
    for (int d4 = 0; d4 < 16; ++d4) {
      float4 k4 = kr[d4];
      float4 q4 = *(const float4*)&qsh[d4 * 4];
      acc += k4.x * q4.x + k4.y * q4.y + k4.z * q4.z + k4.w * q4.w;
    }
    int idx = rpe[n * 256 + m];
    s[r] = acc + rpb[idx * 8 + h];
  }
  float mx = fmaxf(fmaxf(s[0], s[1]), fmaxf(s[2], s[3]));
#pragma unroll
  for (int o = 32; o > 0; o >>= 1) mx = fmaxf(mx, __shfl_xor(mx, o, 64));
  float p[4];
  float sum = 0.f;
#pragma unroll
  for (int r = 0; r < 4; ++r) {
    p[r] = expf(s[r] - mx);
    sum += p[r];
  }
#pragma unroll
  for (int o = 32; o > 0; o >>= 1) sum += __shfl_xor(sum, o, 64);
  float inv = 1.0f / sum;
  float* Pr = P + ((b * 8 + h) * 256 + n) * 256;
#pragma unroll
  for (int r = 0; r < 4; ++r) Pr[r * 64 + t] = p[r] * inv;
}

// ---------------------------------------------------------------------------
// O = P @ V. One block per (b, h, 64-query tile). V staged in LDS.
// O layout [4096, 512] with col = h*64 + d.
// ---------------------------------------------------------------------------
__global__ __launch_bounds__(256) void attn_pv_kernel(
    const float* __restrict__ P, const float* __restrict__ qkv,
    float* __restrict__ O) {
  int bid = blockIdx.x;  // b*32 + h*4 + nt
  int nt = bid & 3, h = (bid >> 2) & 7, b = bid >> 5;
  int tid = threadIdx.x;
  __shared__ float Vsh[256 * 64];
  for (int idx = tid; idx < 4096; idx += 256) {
    int m = idx >> 4, d4 = idx & 15;
    ((float4*)Vsh)[m * 16 + d4] =
        *(const float4*)(qkv + (b * 256 + m) * 1536 + 1024 + h * 64 + d4 * 4);
  }
  __syncthreads();

  int d = tid & 63, ng = tid >> 6;
  const float* Pb = P + ((b * 8 + h) * 256 + nt * 64 + ng * 16) * 256;
#pragma unroll 1
  for (int i = 0; i < 16; ++i) {
    const float4* pr = (const float4*)(Pb + i * 256);
    float a = 0.f;
    for (int m4 = 0; m4 < 64; ++m4) {
      float4 p4 = pr[m4];
      a += p4.x * Vsh[(m4 * 4 + 0) * 64 + d];
      a += p4.y * Vsh[(m4 * 4 + 1) * 64 + d];
      a += p4.z * Vsh[(m4 * 4 + 2) * 64 + d];
      a += p4.w * Vsh[(m4 * 4 + 3) * 64 + d];
    }
    int nn = nt * 64 + ng * 16 + i;
    O[(b * 256 + nn) * 512 + h * 64 + d] = a;
  }
}

// ---------------------------------------------------------------------------
// LayerNorm over 512, one wave per row.
// ---------------------------------------------------------------------------
__global__ __launch_bounds__(64) void ln512_kernel(
    const float* __restrict__ X, const float* __restrict__ w,
    const float* __restrict__ bb, float* __restrict__ out) {
  int row = blockIdx.x, t = threadIdx.x;
  const float4* xr = (const float4*)(X + row * 512);
  float4 v0 = xr[t * 2], v1 = xr[t * 2 + 1];
  float s = v0.x + v0.y + v0.z + v0.w + v1.x + v1.y + v1.z + v1.w;
#pragma unroll
  for (int o = 32; o > 0; o >>= 1) s += __shfl_xor(s, o, 64);
  float mean = s * (1.0f / 512.0f);
  float d0x = v0.x - mean, d0y = v0.y - mean, d0z = v0.z - mean, d0w = v0.w - mean;
  float d1x = v1.x - mean, d1y = v1.y - mean, d1z = v1.z - mean, d1w = v1.w - mean;
  float sq = d0x * d0x + d0y * d0y + d0z * d0z + d0w * d0w +
             d1x * d1x + d1y * d1y + d1z * d1z + d1w * d1w;
#pragma unroll
  for (int o = 32; o > 0; o >>= 1) sq += __shfl_xor(sq, o, 64);
  float rstd = rsqrtf(sq * (1.0f / 512.0f) + EPSV);
  int c = t * 8;
  const float4* w4 = (const float4*)(w + c);
  const float4* b4 = (const float4*)(bb + c);
  float4 o0, o1;
  float4 wa = w4[0], wb = w4[1], ba = b4[0], bc = b4[1];
  o0.x = d0x * rstd * wa.x + ba.x; o0.y = d0y * rstd * wa.y + ba.y;
  o0.z = d0z * rstd * wa.z + ba.z; o0.w = d0w * rstd * wa.w + ba.w;
  o1.x = d1x * rstd * wb.x + bc.x; o1.y = d1y * rstd * wb.y + bc.y;
  o1.z = d1z * rstd * wb.z + bc.z; o1.w = d1w * rstd * wb.w + bc.w;
  ((float4*)(out + row * 512))[t * 2] = o0;
  ((float4*)(out + row * 512))[t * 2 + 1] = o1;
}

// ---------------------------------------------------------------------------
extern "C" void kernel_launch(void* const* d_in, const int* in_sizes, int n_in,
                              void* d_out, int out_size, void* d_ws,
                              size_t ws_size, hipStream_t stream) {
  const float* x = (const float*)d_in[0];
  const float* patch_w = (const float*)d_in[1];
  const float* patch_b = (const float*)d_in[2];
  const float* pnorm_w = (const float*)d_in[3];
  const float* pnorm_b = (const float*)d_in[4];
  const float* s0_n2w = (const float*)d_in[5];
  const float* s0_n2b = (const float*)d_in[6];
  const float* s0_f1w = (const float*)d_in[7];
  const float* s0_f1b = (const float*)d_in[8];
  const float* s0_f2w = (const float*)d_in[9];
  const float* s0_f2b = (const float*)d_in[10];
  const float* m0_nw = (const float*)d_in[11];
  const float* m0_nb = (const float*)d_in[12];
  const float* m0_rw = (const float*)d_in[13];
  const float* s1_n2w = (const float*)d_in[14];
  const float* s1_n2b = (const float*)d_in[15];
  const float* s1_f1w = (const float*)d_in[16];
  const float* s1_f1b = (const float*)d_in[17];
  const float* s1_f2w = (const float*)d_in[18];
  const float* s1_f2b = (const float*)d_in[19];
  const float* m1_nw = (const float*)d_in[20];
  const float* m1_nb = (const float*)d_in[21];
  const float* m1_rw = (const float*)d_in[22];
  const float* pos_embed = (const float*)d_in[23];
  const float* mb_n1w = (const float*)d_in[24];
  const float* mb_n1b = (const float*)d_in[25];
  const float* mb_qkvw = (const float*)d_in[26];
  const float* mb_qkvb = (const float*)d_in[27];
  const float* mb_rpb = (const float*)d_in[28];
  const float* mb_projw = (const float*)d_in[29];
  const float* mb_projb = (const float*)d_in[30];
  const float* mb_n2w = (const float*)d_in[31];
  const float* mb_n2b = (const float*)d_in[32];
  const float* mb_f1w = (const float*)d_in[33];
  const float* mb_f1b = (const float*)d_in[34];
  const float* mb_f2w = (const float*)d_in[35];
  const float* mb_f2b = (const float*)d_in[36];
  const float* fnorm_w = (const float*)d_in[37];
  const float* fnorm_b = (const float*)d_in[38];
  const int* rpe = (const int*)d_in[39];

  float* Xa = (float*)d_ws;          // 8388608 f: activations
  float* Bb = Xa + 8388608;          // 8388608 f: LN out / merged / P
  float* Cc = Bb + 8388608;          // 6291456 f: qkv
  float* Dd = Cc + 6291456;          // 2097152 f: attention O

  // Patch embed + pnorm LN -> Xa [65536,128]
  patch_ln_kernel<<<65536, 128, 0, stream>>>(x, patch_w, patch_b, pnorm_w,
                                             pnorm_b, Xa);
  // Stem stage 0: 8 MLP blocks, dim 128
  for (int i = 0; i < 8; ++i)
    stem_mlp_kernel<128, 384, 16, 384><<<65536 / 16, 256, 0, stream>>>(
        Xa, s0_n2w + i * 128, s0_n2b + i * 128, s0_f1w + i * 49152,
        s0_f1b + i * 384, s0_f2w + i * 49152, s0_f2b + i * 128);
  // Merge 0: -> Bb [16384,512] -> GEMM -> Xa [16384,256]
  merge_ln_kernel<0><<<16384, 256, 0, stream>>>(Xa, m0_nw, m0_nb, Bb);
  gemm_kernel<0><<<(16384 / 64) * (256 / 64), 256, 0, stream>>>(
      Bb, m0_rw, nullptr, nullptr, Xa, 16384, 256, 512);
  // Stem stage 1: 8 MLP blocks, dim 256
  for (int i = 0; i < 8; ++i)
    stem_mlp_kernel<256, 768, 8, 768><<<16384 / 8, 256, 0, stream>>>(
        Xa, s1_n2w + i * 256, s1_n2b + i * 256, s1_f1w + i * 196608,
        s1_f1b + i * 768, s1_f2w + i * 196608, s1_f2b + i * 256);
  // Merge 1: -> Bb [4096,1024] -> GEMM + pos -> Xa [4096,512]
  merge_ln_kernel<1><<<4096, 256, 0, stream>>>(Xa, m1_nw, m1_nb, Bb);
  gemm_kernel<1><<<(4096 / 64) * (512 / 64), 256, 0, stream>>>(
      Bb, m1_rw, nullptr, pos_embed, Xa, 4096, 512, 1024);

  // 20 main attention blocks
  for (int l = 0; l < 20; ++l) {
    ln512_kernel<<<4096, 64, 0, stream>>>(Xa, mb_n1w + l * 512,
                                          mb_n1b + l * 512, Bb);
    gemm_kernel<0><<<(4096 / 64) * (1536 / 64), 256, 0, stream>>>(
        Bb, mb_qkvw + l * 786432, mb_qkvb + l * 1536, nullptr, Cc, 4096, 1536,
        512);
    attn_score_kernel<<<32768, 64, 0, stream>>>(Cc, mb_rpb + l * 7688, rpe, Bb);
    attn_pv_kernel<<<512, 256, 0, stream>>>(Bb, Cc, Dd);
    gemm_kernel<2><<<(4096 / 64) * (512 / 64), 256, 0, stream>>>(
        Dd, mb_projw + l * 262144, mb_projb + l * 512, Xa, Xa, 4096, 512, 512);
    stem_mlp_kernel<512, 2048, 8, 512><<<4096 / 8, 256, 0, stream>>>(
        Xa, mb_n2w + l * 512, mb_n2b + l * 512, mb_f1w + l * 1048576,
        mb_f1b + l * 2048, mb_f2w + l * 1048576, mb_f2b + l * 512);
  }
  // Final LN -> d_out
  ln512_kernel<<<4096, 64, 0, stream>>>(Xa, fnorm_w, fnorm_b, (float*)d_out);
}

// Round 3
// 19795.412 us; speedup vs baseline: 3.9226x; 3.9226x over previous
//
#include <hip/hip_runtime.h>
#include <math.h>

#define EPSV 1e-5f

// ---------------------------------------------------------------------------
// Patch embed (4x4/4 conv) + pnorm LN, fused. One block per token (65536),
// 128 threads = 128 output channels.
// out layout: [B, 256, 4, 4, 128] flat -> [65536, 128]
// ---------------------------------------------------------------------------
__global__ __launch_bounds__(128) void patch_ln_kernel(
    const float* __restrict__ x, const float* __restrict__ pw,
    const float* __restrict__ pbias, const float* __restrict__ nw,
    const float* __restrict__ nb, float* __restrict__ out) {
  int tk = blockIdx.x;  // b*4096 + n*16 + i*4 + j
  int t = threadIdx.x;  // channel 0..127
  int b = tk >> 12;
  int n = (tk >> 4) & 255;
  int ii = (tk >> 2) & 3;
  int jj = tk & 3;
  int Y = ((n >> 4) << 2) + ii;  // 0..63
  int X = ((n & 15) << 2) + jj;

  __shared__ float px[48];
  __shared__ float redA[2];
  __shared__ float redB[2];
  if (t < 48) {
    int ci = t >> 4, dy = (t >> 2) & 3, dx = t & 3;
    px[t] = x[((b * 3 + ci) * 256 + (Y * 4 + dy)) * 256 + (X * 4 + dx)];
  }
  __syncthreads();

  float acc = pbias[t];
  const float* wr = pw + t * 48;
#pragma unroll
  for (int q = 0; q < 48; ++q) acc += wr[q] * px[q];

  float s = acc;
#pragma unroll
  for (int o = 32; o > 0; o >>= 1) s += __shfl_xor(s, o, 64);
  if ((t & 63) == 0) redA[t >> 6] = s;
  __syncthreads();
  float mean = (redA[0] + redA[1]) * (1.0f / 128.0f);
  float d = acc - mean;
  float sq = d * d;
#pragma unroll
  for (int o = 32; o > 0; o >>= 1) sq += __shfl_xor(sq, o, 64);
  if ((t & 63) == 0) redB[t >> 6] = sq;
  __syncthreads();
  float var = (redB[0] + redB[1]) * (1.0f / 128.0f);
  out[tk * 128 + t] = d * rsqrtf(var + EPSV) * nw[t] + nb[t];
}

// ---------------------------------------------------------------------------
// LayerNorm over C (128 or 256), one wave per row, 4 rows per block.
// ---------------------------------------------------------------------------
template <int C>
__global__ __launch_bounds__(256) void lnC_kernel(
    const float* __restrict__ X, const float* __restrict__ w,
    const float* __restrict__ bb, float* __restrict__ out) {
  constexpr int NV = C / 64;  // 2 or 4
  int wave = threadIdx.x >> 6, lane = threadIdx.x & 63;
  int row = blockIdx.x * 4 + wave;
  const float* xr = X + row * C + lane * NV;
  float v[NV];
  if (NV == 2) {
    float2 t2 = *(const float2*)xr;
    v[0] = t2.x; v[1] = t2.y;
  } else {
#pragma unroll
    for (int q = 0; q < NV; q += 4) {
      float4 t4 = *(const float4*)(xr + q);
      v[q] = t4.x; v[q + 1] = t4.y; v[q + 2] = t4.z; v[q + 3] = t4.w;
    }
  }
  float s = 0.f;
#pragma unroll
  for (int q = 0; q < NV; ++q) s += v[q];
#pragma unroll
  for (int o = 32; o > 0; o >>= 1) s += __shfl_xor(s, o, 64);
  float mean = s * (1.0f / C);
  float sq = 0.f;
#pragma unroll
  for (int q = 0; q < NV; ++q) {
    float d = v[q] - mean;
    sq += d * d;
  }
#pragma unroll
  for (int o = 32; o > 0; o >>= 1) sq += __shfl_xor(sq, o, 64);
  float rstd = rsqrtf(sq * (1.0f / C) + EPSV);
#pragma unroll
  for (int q = 0; q < NV; ++q) {
    int c = lane * NV + q;
    out[row * C + c] = (v[q] - mean) * rstd * w[c] + bb[c];
  }
}

// ---------------------------------------------------------------------------
// Patch merge gather + LN. MODE 0: [B,256,4,4,128] -> 16384 tokens of 512.
// MODE 1: [B,256,2,2,256] -> 4096 tokens of 1024.
// ---------------------------------------------------------------------------
template <int MODE>
__global__ __launch_bounds__(256) void merge_ln_kernel(
    const float* __restrict__ Xin, const float* __restrict__ nw,
    const float* __restrict__ nb, float* __restrict__ out) {
  constexpr int CM = MODE ? 1024 : 512;
  constexpr int NE = CM / 256;
  int ot = blockIdx.x;
  int tid = threadIdx.x;
  __shared__ float redA[4];
  __shared__ float redB[4];

  float v[NE];
#pragma unroll
  for (int e = 0; e < NE; ++e) {
    int cp = tid + e * 256;
    if (MODE == 0) {
      int b = ot >> 10, r = ot & 1023;
      int n = r >> 2, di = (r >> 1) & 1, dj = r & 1;
      int q = cp >> 7, c = cp & 127;
      int i = 2 * di + (q & 1), j = 2 * dj + (q >> 1);
      v[e] = Xin[((b * 256 + n) * 16 + i * 4 + j) * 128 + c];
    } else {
      int b = ot >> 8, n = ot & 255;
      int q = cp >> 8, c = cp & 255;
      int di = q & 1, dj = q >> 1;
      v[e] = Xin[((b * 256 + n) * 4 + di * 2 + dj) * 256 + c];
    }
  }
  float s = 0.f;
#pragma unroll
  for (int e = 0; e < NE; ++e) s += v[e];
#pragma unroll
  for (int o = 32; o > 0; o >>= 1) s += __shfl_xor(s, o, 64);
  if ((tid & 63) == 0) redA[tid >> 6] = s;
  __syncthreads();
  float mean = (redA[0] + redA[1] + redA[2] + redA[3]) * (1.0f / CM);
  float sq = 0.f;
#pragma unroll
  for (int e = 0; e < NE; ++e) {
    float d = v[e] - mean;
    sq += d * d;
  }
#pragma unroll
  for (int o = 32; o > 0; o >>= 1) sq += __shfl_xor(sq, o, 64);
  if ((tid & 63) == 0) redB[tid >> 6] = sq;
  __syncthreads();
  float var = (redB[0] + redB[1] + redB[2] + redB[3]) * (1.0f / CM);
  float rstd = rsqrtf(var + EPSV);
#pragma unroll
  for (int e = 0; e < NE; ++e) {
    int cp = tid + e * 256;
    out[ot * CM + cp] = (v[e] - mean) * rstd * nw[cp] + nb[cp];
  }
}

// ---------------------------------------------------------------------------
// Generic f32 GEMM: C[M,N] = A[M,K] @ W[N,K]^T (+bias) (+epilogue)
// EP 0: bias only. EP 1: += extra[(m%256)*N + n] (pos embed).
// EP 2: += extra[m*N+n] (residual; extra may alias Cout).
// EP 3: GELU(acc + bias) (exact erf).
// 64x64 tile, BK=16, 256 threads, 4x4 micro-tile, register prefetch.
// ---------------------------------------------------------------------------
template <int EP>
__global__ __launch_bounds__(256) void gemm_kernel(
    const float* __restrict__ A, const float* __restrict__ W,
    const float* __restrict__ bias, const float* __restrict__ extra,
    float* __restrict__ Cout, int M, int N, int K) {
  __shared__ float As[16][64];
  __shared__ float Ws[16][64];
  int nb = N >> 6;
  int bx = blockIdx.x % nb, by = blockIdx.x / nb;
  int tid = threadIdx.x;
  int tx = tid & 15, ty = tid >> 4;
  int lr = tid >> 2;
  int lk = (tid & 3) << 2;
  const float* Ag = A + (by * 64 + lr) * K + lk;
  const float* Wg = W + (bx * 64 + lr) * K + lk;

  float acc[4][4];
#pragma unroll
  for (int i = 0; i < 4; ++i)
#pragma unroll
    for (int j = 0; j < 4; ++j) acc[i][j] = 0.f;

  float4 av = *(const float4*)Ag;
  float4 wv = *(const float4*)Wg;

  for (int k0 = 0; k0 < K; k0 += 16) {
    As[lk + 0][lr] = av.x; As[lk + 1][lr] = av.y;
    As[lk + 2][lr] = av.z; As[lk + 3][lr] = av.w;
    Ws[lk + 0][lr] = wv.x; Ws[lk + 1][lr] = wv.y;
    Ws[lk + 2][lr] = wv.z; Ws[lk + 3][lr] = wv.w;
    __syncthreads();
    if (k0 + 16 < K) {
      av = *(const float4*)(Ag + k0 + 16);
      wv = *(const float4*)(Wg + k0 + 16);
    }
#pragma unroll
    for (int k = 0; k < 16; ++k) {
      float4 a4 = *(const float4*)&As[k][ty * 4];
      float4 w4 = *(const float4*)&Ws[k][tx * 4];
      acc[0][0] += a4.x * w4.x; acc[0][1] += a4.x * w4.y;
      acc[0][2] += a4.x * w4.z; acc[0][3] += a4.x * w4.w;
      acc[1][0] += a4.y * w4.x; acc[1][1] += a4.y * w4.y;
      acc[1][2] += a4.y * w4.z; acc[1][3] += a4.y * w4.w;
      acc[2][0] += a4.z * w4.x; acc[2][1] += a4.z * w4.y;
      acc[2][2] += a4.z * w4.z; acc[2][3] += a4.z * w4.w;
      acc[3][0] += a4.w * w4.x; acc[3][1] += a4.w * w4.y;
      acc[3][2] += a4.w * w4.z; acc[3][3] += a4.w * w4.w;
    }
    __syncthreads();
  }

  int m0 = by * 64 + ty * 4, n0 = bx * 64 + tx * 4;
  float4 bv = make_float4(0.f, 0.f, 0.f, 0.f);
  if (bias) bv = *(const float4*)&bias[n0];
#pragma unroll
  for (int i = 0; i < 4; ++i) {
    float4 o;
    o.x = acc[i][0] + bv.x; o.y = acc[i][1] + bv.y;
    o.z = acc[i][2] + bv.z; o.w = acc[i][3] + bv.w;
    if (EP == 1) {
      float4 e4 = *(const float4*)&extra[((m0 + i) & 255) * N + n0];
      o.x += e4.x; o.y += e4.y; o.z += e4.z; o.w += e4.w;
    } else if (EP == 2) {
      float4 e4 = *(const float4*)&extra[(m0 + i) * N + n0];
      o.x += e4.x; o.y += e4.y; o.z += e4.z; o.w += e4.w;
    } else if (EP == 3) {
      o.x = 0.5f * o.x * (1.0f + erff(o.x * 0.70710678118654752f));
      o.y = 0.5f * o.y * (1.0f + erff(o.y * 0.70710678118654752f));
      o.z = 0.5f * o.z * (1.0f + erff(o.z * 0.70710678118654752f));
      o.w = 0.5f * o.w * (1.0f + erff(o.w * 0.70710678118654752f));
    }
    *(float4*)&Cout[(m0 + i) * N + n0] = o;
  }
}

// ---------------------------------------------------------------------------
// Attention scores + softmax. One block (64 threads) per (b, h, n).
// ---------------------------------------------------------------------------
__global__ __launch_bounds__(64) void attn_score_kernel(
    const float* __restrict__ qkv, const float* __restrict__ rpb,
    const int* __restrict__ rpe, float* __restrict__ P) {
  int bid = blockIdx.x;
  int n = bid & 255, h = (bid >> 8) & 7, b = bid >> 11;
  int t = threadIdx.x;
  __shared__ float qsh[64];
  qsh[t] = qkv[(b * 256 + n) * 1536 + h * 64 + t] * 0.125f;
  __syncthreads();

  float s[4];
#pragma unroll
  for (int r = 0; r < 4; ++r) {
    int m = r * 64 + t;
    const float4* kr = (const float4*)(qkv + (b * 256 + m) * 1536 + 512 + h * 64);
    float acc = 0.f;
#pragma unroll
    for (int d4 = 0; d4 < 16; ++d4) {
      float4 k4 = kr[d4];
      float4 q4 = *(const float4*)&qsh[d4 * 4];
      acc += k4.x * q4.x + k4.y * q4.y + k4.z * q4.z + k4.w * q4.w;
    }
    int idx = rpe[n * 256 + m];
    s[r] = acc + rpb[idx * 8 + h];
  }
  float mx = fmaxf(fmaxf(s[0], s[1]), fmaxf(s[2], s[3]));
#pragma unroll
  for (int o = 32; o > 0; o >>= 1) mx = fmaxf(mx, __shfl_xor(mx, o, 64));
  float p[4];
  float sum = 0.f;
#pragma unroll
  for (int r = 0; r < 4; ++r) {
    p[r] = expf(s[r] - mx);
    sum += p[r];
  }
#pragma unroll
  for (int o = 32; o > 0; o >>= 1) sum += __shfl_xor(sum, o, 64);
  float inv = 1.0f / sum;
  float* Pr = P + ((b * 8 + h) * 256 + n) * 256;
#pragma unroll
  for (int r = 0; r < 4; ++r) Pr[r * 64 + t] = p[r] * inv;
}

// ---------------------------------------------------------------------------
// O = P @ V. One block per (b, h, 64-query tile). V staged in LDS.
// ---------------------------------------------------------------------------
__global__ __launch_bounds__(256) void attn_pv_kernel(
    const float* __restrict__ P, const float* __restrict__ qkv,
    float* __restrict__ O) {
  int bid = blockIdx.x;  // b*32 + h*4 + nt
  int nt = bid & 3, h = (bid >> 2) & 7, b = bid >> 5;
  int tid = threadIdx.x;
  __shared__ float Vsh[256 * 64];
  for (int idx = tid; idx < 4096; idx += 256) {
    int m = idx >> 4, d4 = idx & 15;
    ((float4*)Vsh)[m * 16 + d4] =
        *(const float4*)(qkv + (b * 256 + m) * 1536 + 1024 + h * 64 + d4 * 4);
  }
  __syncthreads();

  int d = tid & 63, ng = tid >> 6;
  const float* Pb = P + ((b * 8 + h) * 256 + nt * 64 + ng * 16) * 256;
#pragma unroll 1
  for (int i = 0; i < 16; ++i) {
    const float4* pr = (const float4*)(Pb + i * 256);
    float a = 0.f;
    for (int m4 = 0; m4 < 64; ++m4) {
      float4 p4 = pr[m4];
      a += p4.x * Vsh[(m4 * 4 + 0) * 64 + d];
      a += p4.y * Vsh[(m4 * 4 + 1) * 64 + d];
      a += p4.z * Vsh[(m4 * 4 + 2) * 64 + d];
      a += p4.w * Vsh[(m4 * 4 + 3) * 64 + d];
    }
    int nn = nt * 64 + ng * 16 + i;
    O[(b * 256 + nn) * 512 + h * 64 + d] = a;
  }
}

// ---------------------------------------------------------------------------
// LayerNorm over 512, one wave per row.
// ---------------------------------------------------------------------------
__global__ __launch_bounds__(64) void ln512_kernel(
    const float* __restrict__ X, const float* __restrict__ w,
    const float* __restrict__ bb, float* __restrict__ out) {
  int row = blockIdx.x, t = threadIdx.x;
  const float4* xr = (const float4*)(X + row * 512);
  float4 v0 = xr[t * 2], v1 = xr[t * 2 + 1];
  float s = v0.x + v0.y + v0.z + v0.w + v1.x + v1.y + v1.z + v1.w;
#pragma unroll
  for (int o = 32; o > 0; o >>= 1) s += __shfl_xor(s, o, 64);
  float mean = s * (1.0f / 512.0f);
  float d0x = v0.x - mean, d0y = v0.y - mean, d0z = v0.z - mean, d0w = v0.w - mean;
  float d1x = v1.x - mean, d1y = v1.y - mean, d1z = v1.z - mean, d1w = v1.w - mean;
  float sq = d0x * d0x + d0y * d0y + d0z * d0z + d0w * d0w +
             d1x * d1x + d1y * d1y + d1z * d1z + d1w * d1w;
#pragma unroll
  for (int o = 32; o > 0; o >>= 1) sq += __shfl_xor(sq, o, 64);
  float rstd = rsqrtf(sq * (1.0f / 512.0f) + EPSV);
  int c = t * 8;
  const float4* w4 = (const float4*)(w + c);
  const float4* b4 = (const float4*)(bb + c);
  float4 o0, o1;
  float4 wa = w4[0], wb = w4[1], ba = b4[0], bc = b4[1];
  o0.x = d0x * rstd * wa.x + ba.x; o0.y = d0y * rstd * wa.y + ba.y;
  o0.z = d0z * rstd * wa.z + ba.z; o0.w = d0w * rstd * wa.w + ba.w;
  o1.x = d1x * rstd * wb.x + bc.x; o1.y = d1y * rstd * wb.y + bc.y;
  o1.z = d1z * rstd * wb.z + bc.z; o1.w = d1w * rstd * wb.w + bc.w;
  ((float4*)(out + row * 512))[t * 2] = o0;
  ((float4*)(out + row * 512))[t * 2 + 1] = o1;
}

// ---------------------------------------------------------------------------
extern "C" void kernel_launch(void* const* d_in, const int* in_sizes, int n_in,
                              void* d_out, int out_size, void* d_ws,
                              size_t ws_size, hipStream_t stream) {
  const float* x = (const float*)d_in[0];
  const float* patch_w = (const float*)d_in[1];
  const float* patch_b = (const float*)d_in[2];
  const float* pnorm_w = (const float*)d_in[3];
  const float* pnorm_b = (const float*)d_in[4];
  const float* s0_n2w = (const float*)d_in[5];
  const float* s0_n2b = (const float*)d_in[6];
  const float* s0_f1w = (const float*)d_in[7];
  const float* s0_f1b = (const float*)d_in[8];
  const float* s0_f2w = (const float*)d_in[9];
  const float* s0_f2b = (const float*)d_in[10];
  const float* m0_nw = (const float*)d_in[11];
  const float* m0_nb = (const float*)d_in[12];
  const float* m0_rw = (const float*)d_in[13];
  const float* s1_n2w = (const float*)d_in[14];
  const float* s1_n2b = (const float*)d_in[15];
  const float* s1_f1w = (const float*)d_in[16];
  const float* s1_f1b = (const float*)d_in[17];
  const float* s1_f2w = (const float*)d_in[18];
  const float* s1_f2b = (const float*)d_in[19];
  const float* m1_nw = (const float*)d_in[20];
  const float* m1_nb = (const float*)d_in[21];
  const float* m1_rw = (const float*)d_in[22];
  const float* pos_embed = (const float*)d_in[23];
  const float* mb_n1w = (const float*)d_in[24];
  const float* mb_n1b = (const float*)d_in[25];
  const float* mb_qkvw = (const float*)d_in[26];
  const float* mb_qkvb = (const float*)d_in[27];
  const float* mb_rpb = (const float*)d_in[28];
  const float* mb_projw = (const float*)d_in[29];
  const float* mb_projb = (const float*)d_in[30];
  const float* mb_n2w = (const float*)d_in[31];
  const float* mb_n2b = (const float*)d_in[32];
  const float* mb_f1w = (const float*)d_in[33];
  const float* mb_f1b = (const float*)d_in[34];
  const float* mb_f2w = (const float*)d_in[35];
  const float* mb_f2b = (const float*)d_in[36];
  const float* fnorm_w = (const float*)d_in[37];
  const float* fnorm_b = (const float*)d_in[38];
  const int* rpe = (const int*)d_in[39];

  float* Xa = (float*)d_ws;          // 8388608 f: activations
  float* Bb = Xa + 8388608;          // 8388608 f: LN out / hidden / P
  float* Cc = Bb + 8388608;          // 6291456 f: qkv / stem hidden chunk
  float* Dd = Cc + 6291456;          // 2097152 f: attn O / main LN out

  // Patch embed + pnorm LN -> Xa [65536,128]
  patch_ln_kernel<<<65536, 128, 0, stream>>>(x, patch_w, patch_b, pnorm_w,
                                             pnorm_b, Xa);

  // Stem stage 0: 8 MLP blocks, dim 128, hidden 384 (token-chunked x4)
  for (int i = 0; i < 8; ++i) {
    lnC_kernel<128><<<65536 / 4, 256, 0, stream>>>(Xa, s0_n2w + i * 128,
                                                   s0_n2b + i * 128, Bb);
    for (int c = 0; c < 4; ++c) {
      const float* Ain = Bb + c * 16384 * 128;
      float* Xc = Xa + c * 16384 * 128;
      gemm_kernel<3><<<(16384 / 64) * (384 / 64), 256, 0, stream>>>(
          Ain, s0_f1w + i * 49152, s0_f1b + i * 384, nullptr, Cc, 16384, 384,
          128);
      gemm_kernel<2><<<(16384 / 64) * (128 / 64), 256, 0, stream>>>(
          Cc, s0_f2w + i * 49152, s0_f2b + i * 128, Xc, Xc, 16384, 128, 384);
    }
  }
  // Merge 0: -> Bb [16384,512] -> GEMM -> Xa [16384,256]
  merge_ln_kernel<0><<<16384, 256, 0, stream>>>(Xa, m0_nw, m0_nb, Bb);
  gemm_kernel<0><<<(16384 / 64) * (256 / 64), 256, 0, stream>>>(
      Bb, m0_rw, nullptr, nullptr, Xa, 16384, 256, 512);

  // Stem stage 1: 8 MLP blocks, dim 256, hidden 768 (token-chunked x2)
  for (int i = 0; i < 8; ++i) {
    lnC_kernel<256><<<16384 / 4, 256, 0, stream>>>(Xa, s1_n2w + i * 256,
                                                   s1_n2b + i * 256, Bb);
    for (int c = 0; c < 2; ++c) {
      const float* Ain = Bb + c * 8192 * 256;
      float* Xc = Xa + c * 8192 * 256;
      gemm_kernel<3><<<(8192 / 64) * (768 / 64), 256, 0, stream>>>(
          Ain, s1_f1w + i * 196608, s1_f1b + i * 768, nullptr, Cc, 8192, 768,
          256);
      gemm_kernel<2><<<(8192 / 64) * (256 / 64), 256, 0, stream>>>(
          Cc, s1_f2w + i * 196608, s1_f2b + i * 256, Xc, Xc, 8192, 256, 768);
    }
  }
  // Merge 1: -> Bb [4096,1024] -> GEMM + pos -> Xa [4096,512]
  merge_ln_kernel<1><<<4096, 256, 0, stream>>>(Xa, m1_nw, m1_nb, Bb);
  gemm_kernel<1><<<(4096 / 64) * (512 / 64), 256, 0, stream>>>(
      Bb, m1_rw, nullptr, pos_embed, Xa, 4096, 512, 1024);

  // 20 main attention blocks
  for (int l = 0; l < 20; ++l) {
    // attention
    ln512_kernel<<<4096, 64, 0, stream>>>(Xa, mb_n1w + l * 512,
                                          mb_n1b + l * 512, Bb);
    gemm_kernel<0><<<(4096 / 64) * (1536 / 64), 256, 0, stream>>>(
        Bb, mb_qkvw + l * 786432, mb_qkvb + l * 1536, nullptr, Cc, 4096, 1536,
        512);
    attn_score_kernel<<<32768, 64, 0, stream>>>(Cc, mb_rpb + l * 7688, rpe, Bb);
    attn_pv_kernel<<<512, 256, 0, stream>>>(Bb, Cc, Dd);
    gemm_kernel<2><<<(4096 / 64) * (512 / 64), 256, 0, stream>>>(
        Dd, mb_projw + l * 262144, mb_projb + l * 512, Xa, Xa, 4096, 512, 512);
    // MLP: LN -> Dd, fc1+gelu -> Bb, fc2+residual -> Xa
    ln512_kernel<<<4096, 64, 0, stream>>>(Xa, mb_n2w + l * 512,
                                          mb_n2b + l * 512, Dd);
    gemm_kernel<3><<<(4096 / 64) * (2048 / 64), 256, 0, stream>>>(
        Dd, mb_f1w + l * 1048576, mb_f1b + l * 2048, nullptr, Bb, 4096, 2048,
        512);
    gemm_kernel<2><<<(4096 / 64) * (512 / 64), 256, 0, stream>>>(
        Bb, mb_f2w + l * 1048576, mb_f2b + l * 512, Xa, Xa, 4096, 512, 2048);
  }
  // Final LN -> d_out
  ln512_kernel<<<4096, 64, 0, stream>>>(Xa, fnorm_w, fnorm_b, (float*)d_out);
}

// Round 5
// 14419.908 us; speedup vs baseline: 5.3848x; 1.3728x over previous
//
#include <hip/hip_runtime.h>
#include <math.h>

#define EPSV 1e-5f

typedef __attribute__((ext_vector_type(8))) short bf16x8;
typedef __attribute__((ext_vector_type(4))) float f32x4;

__device__ inline unsigned short f2bf(float x) {
  unsigned u = __builtin_bit_cast(unsigned, x);
  u += 0x7FFFu + ((u >> 16) & 1u);
  return (unsigned short)(u >> 16);
}
__device__ inline float bf2f(unsigned short h) {
  unsigned u = ((unsigned)h) << 16;
  return __builtin_bit_cast(float, u);
}

// ---------------------------------------------------------------------------
// Patch embed (4x4/4 conv) + pnorm LN, fused.
// ---------------------------------------------------------------------------
__global__ __launch_bounds__(128) void patch_ln_kernel(
    const float* __restrict__ x, const float* __restrict__ pw,
    const float* __restrict__ pbias, const float* __restrict__ nw,
    const float* __restrict__ nb, float* __restrict__ out) {
  int tk = blockIdx.x;  // b*4096 + n*16 + i*4 + j
  int t = threadIdx.x;  // channel 0..127
  int b = tk >> 12;
  int n = (tk >> 4) & 255;
  int ii = (tk >> 2) & 3;
  int jj = tk & 3;
  int Y = ((n >> 4) << 2) + ii;
  int X = ((n & 15) << 2) + jj;

  __shared__ float px[48];
  __shared__ float redA[2];
  __shared__ float redB[2];
  if (t < 48) {
    int ci = t >> 4, dy = (t >> 2) & 3, dx = t & 3;
    px[t] = x[((b * 3 + ci) * 256 + (Y * 4 + dy)) * 256 + (X * 4 + dx)];
  }
  __syncthreads();

  float acc = pbias[t];
  const float* wr = pw + t * 48;
#pragma unroll
  for (int q = 0; q < 48; ++q) acc += wr[q] * px[q];

  float s = acc;
#pragma unroll
  for (int o = 32; o > 0; o >>= 1) s += __shfl_xor(s, o, 64);
  if ((t & 63) == 0) redA[t >> 6] = s;
  __syncthreads();
  float mean = (redA[0] + redA[1]) * (1.0f / 128.0f);
  float d = acc - mean;
  float sq = d * d;
#pragma unroll
  for (int o = 32; o > 0; o >>= 1) sq += __shfl_xor(sq, o, 64);
  if ((t & 63) == 0) redB[t >> 6] = sq;
  __syncthreads();
  float var = (redB[0] + redB[1]) * (1.0f / 128.0f);
  out[tk * 128 + t] = d * rsqrtf(var + EPSV) * nw[t] + nb[t];
}

// ---------------------------------------------------------------------------
// LayerNorm over C (128 or 256), one wave per row, 4 rows per block.
// ---------------------------------------------------------------------------
template <int C>
__global__ __launch_bounds__(256) void lnC_kernel(
    const float* __restrict__ X, const float* __restrict__ w,
    const float* __restrict__ bb, float* __restrict__ out) {
  constexpr int NV = C / 64;
  int wave = threadIdx.x >> 6, lane = threadIdx.x & 63;
  int row = blockIdx.x * 4 + wave;
  const float* xr = X + row * C + lane * NV;
  float v[NV];
  if (NV == 2) {
    float2 t2 = *(const float2*)xr;
    v[0] = t2.x; v[1] = t2.y;
  } else {
#pragma unroll
    for (int q = 0; q < NV; q += 4) {
      float4 t4 = *(const float4*)(xr + q);
      v[q] = t4.x; v[q + 1] = t4.y; v[q + 2] = t4.z; v[q + 3] = t4.w;
    }
  }
  float s = 0.f;
#pragma unroll
  for (int q = 0; q < NV; ++q) s += v[q];
#pragma unroll
  for (int o = 32; o > 0; o >>= 1) s += __shfl_xor(s, o, 64);
  float mean = s * (1.0f / C);
  float sq = 0.f;
#pragma unroll
  for (int q = 0; q < NV; ++q) {
    float d = v[q] - mean;
    sq += d * d;
  }
#pragma unroll
  for (int o = 32; o > 0; o >>= 1) sq += __shfl_xor(sq, o, 64);
  float rstd = rsqrtf(sq * (1.0f / C) + EPSV);
#pragma unroll
  for (int q = 0; q < NV; ++q) {
    int c = lane * NV + q;
    out[row * C + c] = (v[q] - mean) * rstd * w[c] + bb[c];
  }
}

// ---------------------------------------------------------------------------
// Patch merge gather + LN.
// ---------------------------------------------------------------------------
template <int MODE>
__global__ __launch_bounds__(256) void merge_ln_kernel(
    const float* __restrict__ Xin, const float* __restrict__ nw,
    const float* __restrict__ nb, float* __restrict__ out) {
  constexpr int CM = MODE ? 1024 : 512;
  constexpr int NE = CM / 256;
  int ot = blockIdx.x;
  int tid = threadIdx.x;
  __shared__ float redA[4];
  __shared__ float redB[4];

  float v[NE];
#pragma unroll
  for (int e = 0; e < NE; ++e) {
    int cp = tid + e * 256;
    if (MODE == 0) {
      int b = ot >> 10, r = ot & 1023;
      int n = r >> 2, di = (r >> 1) & 1, dj = r & 1;
      int q = cp >> 7, c = cp & 127;
      int i = 2 * di + (q & 1), j = 2 * dj + (q >> 1);
      v[e] = Xin[((b * 256 + n) * 16 + i * 4 + j) * 128 + c];
    } else {
      int b = ot >> 8, n = ot & 255;
      int q = cp >> 8, c = cp & 255;
      int di = q & 1, dj = q >> 1;
      v[e] = Xin[((b * 256 + n) * 4 + di * 2 + dj) * 256 + c];
    }
  }
  float s = 0.f;
#pragma unroll
  for (int e = 0; e < NE; ++e) s += v[e];
#pragma unroll
  for (int o = 32; o > 0; o >>= 1) s += __shfl_xor(s, o, 64);
  if ((tid & 63) == 0) redA[tid >> 6] = s;
  __syncthreads();
  float mean = (redA[0] + redA[1] + redA[2] + redA[3]) * (1.0f / CM);
  float sq = 0.f;
#pragma unroll
  for (int e = 0; e < NE; ++e) {
    float d = v[e] - mean;
    sq += d * d;
  }
#pragma unroll
  for (int o = 32; o > 0; o >>= 1) sq += __shfl_xor(sq, o, 64);
  if ((tid & 63) == 0) redB[tid >> 6] = sq;
  __syncthreads();
  float var = (redB[0] + redB[1] + redB[2] + redB[3]) * (1.0f / CM);
  float rstd = rsqrtf(var + EPSV);
#pragma unroll
  for (int e = 0; e < NE; ++e) {
    int cp = tid + e * 256;
    out[ot * CM + cp] = (v[e] - mean) * rstd * nw[cp] + nb[cp];
  }
}

// ---------------------------------------------------------------------------
// Split-bf16 MFMA GEMM: C[M,N] = A[M,K] @ W[N,K]^T (+bias)(+epilogue).
// f32 operands split as hi+lo bf16; D = Ah*Bh + Al*Bh + Ah*Bl (f32 accum).
// Tile 128x128, BK=32, 256 threads (4 waves, 2x2 of 64x64 each).
// LDS row: [hi 32 bf16 | lo 32 bf16 | 8 pad] = 72 shorts (144 B, 16B-aligned).
// EP 0: bias. EP 1: +extra[(m&255)*N+n] (pos). EP 2: +extra[m*N+n] (residual).
// EP 3: gelu(acc+bias).
// ---------------------------------------------------------------------------
__device__ inline void split16(const float4* p4, short* hi, short* lo) {
#pragma unroll
  for (int q = 0; q < 4; ++q) {
    float4 v = p4[q];
    float vv[4] = {v.x, v.y, v.z, v.w};
#pragma unroll
    for (int e = 0; e < 4; ++e) {
      unsigned short hb = f2bf(vv[e]);
      hi[q * 4 + e] = (short)hb;
      lo[q * 4 + e] = (short)f2bf(vv[e] - bf2f(hb));
    }
  }
}

template <int EP>
__global__ __launch_bounds__(256) void mgemm_kernel(
    const float* __restrict__ A, const float* __restrict__ W,
    const float* __restrict__ bias, const float* __restrict__ extra,
    float* __restrict__ Cout, int M, int N, int K) {
  __shared__ __align__(16) short Al[128 * 72];
  __shared__ __align__(16) short Wl[128 * 72];
  int nb = N >> 7;
  int bx = blockIdx.x % nb, by = blockIdx.x / nb;
  int tid = threadIdx.x;
  int r = tid >> 1, hf = tid & 1;  // staging: row, k-half
  const float* Ag = A + (by * 128 + r) * K + hf * 16;
  const float* Wg = W + (bx * 128 + r) * K + hf * 16;

  int lane = tid & 63;
  int wv = tid >> 6;
  int wm = (wv >> 1) * 64;
  int wn = (wv & 1) * 64;
  int fr = lane & 15;
  int fq = lane >> 4;

  f32x4 acc[4][4];
#pragma unroll
  for (int i = 0; i < 4; ++i)
#pragma unroll
    for (int j = 0; j < 4; ++j) acc[i][j] = {0.f, 0.f, 0.f, 0.f};

  float4 pa[4], pw[4];
#pragma unroll
  for (int q = 0; q < 4; ++q) {
    pa[q] = *(const float4*)(Ag + q * 4);
    pw[q] = *(const float4*)(Wg + q * 4);
  }

  for (int k0 = 0; k0 < K; k0 += 32) {
    {
      short ha[16], la[16], hw[16], lw[16];
      split16(pa, ha, la);
      split16(pw, hw, lw);
      short* ab = &Al[r * 72 + hf * 16];
      *(bf16x8*)(ab + 0) = *(const bf16x8*)&ha[0];
      *(bf16x8*)(ab + 8) = *(const bf16x8*)&ha[8];
      *(bf16x8*)(ab + 32) = *(const bf16x8*)&la[0];
      *(bf16x8*)(ab + 40) = *(const bf16x8*)&la[8];
      short* wb = &Wl[r * 72 + hf * 16];
      *(bf16x8*)(wb + 0) = *(const bf16x8*)&hw[0];
      *(bf16x8*)(wb + 8) = *(const bf16x8*)&hw[8];
      *(bf16x8*)(wb + 32) = *(const bf16x8*)&lw[0];
      *(bf16x8*)(wb + 40) = *(const bf16x8*)&lw[8];
    }
    __syncthreads();
    if (k0 + 32 < K) {
#pragma unroll
      for (int q = 0; q < 4; ++q) {
        pa[q] = *(const float4*)(Ag + k0 + 32 + q * 4);
        pw[q] = *(const float4*)(Wg + k0 + 32 + q * 4);
      }
    }
    bf16x8 ah[4], alo[4], bh[4], blo[4];
#pragma unroll
    for (int i = 0; i < 4; ++i) {
      int arow = (wm + i * 16 + fr) * 72 + fq * 8;
      ah[i] = *(const bf16x8*)&Al[arow];
      alo[i] = *(const bf16x8*)&Al[arow + 32];
      int wrow = (wn + i * 16 + fr) * 72 + fq * 8;
      bh[i] = *(const bf16x8*)&Wl[wrow];
      blo[i] = *(const bf16x8*)&Wl[wrow + 32];
    }
#pragma unroll
    for (int i = 0; i < 4; ++i)
#pragma unroll
      for (int j = 0; j < 4; ++j) {
        acc[i][j] =
            __builtin_amdgcn_mfma_f32_16x16x32_bf16(ah[i], bh[j], acc[i][j], 0, 0, 0);
        acc[i][j] =
            __builtin_amdgcn_mfma_f32_16x16x32_bf16(alo[i], bh[j], acc[i][j], 0, 0, 0);
        acc[i][j] =
            __builtin_amdgcn_mfma_f32_16x16x32_bf16(ah[i], blo[j], acc[i][j], 0, 0, 0);
      }
    __syncthreads();
  }

  int row0 = by * 128 + wm;
  int col0 = bx * 128 + wn;
#pragma unroll
  for (int j = 0; j < 4; ++j) {
    int col = col0 + j * 16 + fr;
    float bvv = bias ? bias[col] : 0.f;
#pragma unroll
    for (int i = 0; i < 4; ++i) {
#pragma unroll
      for (int e = 0; e < 4; ++e) {
        int row = row0 + i * 16 + fq * 4 + e;
        float o = acc[i][j][e] + bvv;
        if (EP == 1) {
          o += extra[(row & 255) * N + col];
        } else if (EP == 2) {
          o += extra[row * N + col];
        } else if (EP == 3) {
          o = 0.5f * o * (1.0f + erff(o * 0.70710678118654752f));
        }
        Cout[row * N + col] = o;
      }
    }
  }
}

// ---------------------------------------------------------------------------
// Attention scores + softmax. One block (64 threads) per (b, h, n).
// ---------------------------------------------------------------------------
__global__ __launch_bounds__(64) void attn_score_kernel(
    const float* __restrict__ qkv, const float* __restrict__ rpb,
    const int* __restrict__ rpe, float* __restrict__ P) {
  int bid = blockIdx.x;
  int n = bid & 255, h = (bid >> 8) & 7, b = bid >> 11;
  int t = threadIdx.x;
  __shared__ float qsh[64];
  qsh[t] = qkv[(b * 256 + n) * 1536 + h * 64 + t] * 0.125f;
  __syncthreads();

  float s[4];
#pragma unroll
  for (int r = 0; r < 4; ++r) {
    int m = r * 64 + t;
    const float4* kr = (const float4*)(qkv + (b * 256 + m) * 1536 + 512 + h * 64);
    float acc = 0.f;
#pragma unroll
    for (int d4 = 0; d4 < 16; ++d4) {
      float4 k4 = kr[d4];
      float4 q4 = *(const float4*)&qsh[d4 * 4];
      acc += k4.x * q4.x + k4.y * q4.y + k4.z * q4.z + k4.w * q4.w;
    }
    int idx = rpe[n * 256 + m];
    s[r] = acc + rpb[idx * 8 + h];
  }
  float mx = fmaxf(fmaxf(s[0], s[1]), fmaxf(s[2], s[3]));
#pragma unroll
  for (int o = 32; o > 0; o >>= 1) mx = fmaxf(mx, __shfl_xor(mx, o, 64));
  float p[4];
  float sum = 0.f;
#pragma unroll
  for (int r = 0; r < 4; ++r) {
    p[r] = expf(s[r] - mx);
    sum += p[r];
  }
#pragma unroll
  for (int o = 32; o > 0; o >>= 1) sum += __shfl_xor(sum, o, 64);
  float inv = 1.0f / sum;
  float* Pr = P + ((b * 8 + h) * 256 + n) * 256;
#pragma unroll
  for (int r = 0; r < 4; ++r) Pr[r * 64 + t] = p[r] * inv;
}

// ---------------------------------------------------------------------------
// O = P @ V. One block per (b, h, 64-query tile). V staged in LDS.
// ---------------------------------------------------------------------------
__global__ __launch_bounds__(256) void attn_pv_kernel(
    const float* __restrict__ P, const float* __restrict__ qkv,
    float* __restrict__ O) {
  int bid = blockIdx.x;  // b*32 + h*4 + nt
  int nt = bid & 3, h = (bid >> 2) & 7, b = bid >> 5;
  int tid = threadIdx.x;
  __shared__ float Vsh[256 * 64];
  for (int idx = tid; idx < 4096; idx += 256) {
    int m = idx >> 4, d4 = idx & 15;
    ((float4*)Vsh)[m * 16 + d4] =
        *(const float4*)(qkv + (b * 256 + m) * 1536 + 1024 + h * 64 + d4 * 4);
  }
  __syncthreads();

  int d = tid & 63, ng = tid >> 6;
  const float* Pb = P + ((b * 8 + h) * 256 + nt * 64 + ng * 16) * 256;
#pragma unroll 1
  for (int i = 0; i < 16; ++i) {
    const float4* pr = (const float4*)(Pb + i * 256);
    float a = 0.f;
    for (int m4 = 0; m4 < 64; ++m4) {
      float4 p4 = pr[m4];
      a += p4.x * Vsh[(m4 * 4 + 0) * 64 + d];
      a += p4.y * Vsh[(m4 * 4 + 1) * 64 + d];
      a += p4.z * Vsh[(m4 * 4 + 2) * 64 + d];
      a += p4.w * Vsh[(m4 * 4 + 3) * 64 + d];
    }
    int nn = nt * 64 + ng * 16 + i;
    O[(b * 256 + nn) * 512 + h * 64 + d] = a;
  }
}

// ---------------------------------------------------------------------------
// LayerNorm over 512, one wave per row.
// ---------------------------------------------------------------------------
__global__ __launch_bounds__(64) void ln512_kernel(
    const float* __restrict__ X, const float* __restrict__ w,
    const float* __restrict__ bb, float* __restrict__ out) {
  int row = blockIdx.x, t = threadIdx.x;
  const float4* xr = (const float4*)(X + row * 512);
  float4 v0 = xr[t * 2], v1 = xr[t * 2 + 1];
  float s = v0.x + v0.y + v0.z + v0.w + v1.x + v1.y + v1.z + v1.w;
#pragma unroll
  for (int o = 32; o > 0; o >>= 1) s += __shfl_xor(s, o, 64);
  float mean = s * (1.0f / 512.0f);
  float d0x = v0.x - mean, d0y = v0.y - mean, d0z = v0.z - mean, d0w = v0.w - mean;
  float d1x = v1.x - mean, d1y = v1.y - mean, d1z = v1.z - mean, d1w = v1.w - mean;
  float sq = d0x * d0x + d0y * d0y + d0z * d0z + d0w * d0w +
             d1x * d1x + d1y * d1y + d1z * d1z + d1w * d1w;
#pragma unroll
  for (int o = 32; o > 0; o >>= 1) sq += __shfl_xor(sq, o, 64);
  float rstd = rsqrtf(sq * (1.0f / 512.0f) + EPSV);
  int c = t * 8;
  const float4* w4 = (const float4*)(w + c);
  const float4* b4 = (const float4*)(bb + c);
  float4 o0, o1;
  float4 wa = w4[0], wb = w4[1], ba = b4[0], bc = b4[1];
  o0.x = d0x * rstd * wa.x + ba.x; o0.y = d0y * rstd * wa.y + ba.y;
  o0.z = d0z * rstd * wa.z + ba.z; o0.w = d0w * rstd * wa.w + ba.w;
  o1.x = d1x * rstd * wb.x + bc.x; o1.y = d1y * rstd * wb.y + bc.y;
  o1.z = d1z * rstd * wb.z + bc.z; o1.w = d1w * rstd * wb.w + bc.w;
  ((float4*)(out + row * 512))[t * 2] = o0;
  ((float4*)(out + row * 512))[t * 2 + 1] = o1;
}

// ---------------------------------------------------------------------------
extern "C" void kernel_launch(void* const* d_in, const int* in_sizes, int n_in,
                              void* d_out, int out_size, void* d_ws,
                              size_t ws_size, hipStream_t stream) {
  const float* x = (const float*)d_in[0];
  const float* patch_w = (const float*)d_in[1];
  const float* patch_b = (const float*)d_in[2];
  const float* pnorm_w = (const float*)d_in[3];
  const float* pnorm_b = (const float*)d_in[4];
  const float* s0_n2w = (const float*)d_in[5];
  const float* s0_n2b = (const float*)d_in[6];
  const float* s0_f1w = (const float*)d_in[7];
  const float* s0_f1b = (const float*)d_in[8];
  const float* s0_f2w = (const float*)d_in[9];
  const float* s0_f2b = (const float*)d_in[10];
  const float* m0_nw = (const float*)d_in[11];
  const float* m0_nb = (const float*)d_in[12];
  const float* m0_rw = (const float*)d_in[13];
  const float* s1_n2w = (const float*)d_in[14];
  const float* s1_n2b = (const float*)d_in[15];
  const float* s1_f1w = (const float*)d_in[16];
  const float* s1_f1b = (const float*)d_in[17];
  const float* s1_f2w = (const float*)d_in[18];
  const float* s1_f2b = (const float*)d_in[19];
  const float* m1_nw = (const float*)d_in[20];
  const float* m1_nb = (const float*)d_in[21];
  const float* m1_rw = (const float*)d_in[22];
  const float* pos_embed = (const float*)d_in[23];
  const float* mb_n1w = (const float*)d_in[24];
  const float* mb_n1b = (const float*)d_in[25];
  const float* mb_qkvw = (const float*)d_in[26];
  const float* mb_qkvb = (const float*)d_in[27];
  const float* mb_rpb = (const float*)d_in[28];
  const float* mb_projw = (const float*)d_in[29];
  const float* mb_projb = (const float*)d_in[30];
  const float* mb_n2w = (const float*)d_in[31];
  const float* mb_n2b = (const float*)d_in[32];
  const float* mb_f1w = (const float*)d_in[33];
  const float* mb_f1b = (const float*)d_in[34];
  const float* mb_f2w = (const float*)d_in[35];
  const float* mb_f2b = (const float*)d_in[36];
  const float* fnorm_w = (const float*)d_in[37];
  const float* fnorm_b = (const float*)d_in[38];
  const int* rpe = (const int*)d_in[39];

  float* Xa = (float*)d_ws;          // 8388608 f: activations
  float* Bb = Xa + 8388608;          // 8388608 f: LN out / hidden / P
  float* Cc = Bb + 8388608;          // 6291456 f: qkv / stem hidden chunk
  float* Dd = Cc + 6291456;          // 2097152 f: attn O / main LN out

  // Patch embed + pnorm LN -> Xa [65536,128]
  patch_ln_kernel<<<65536, 128, 0, stream>>>(x, patch_w, patch_b, pnorm_w,
                                             pnorm_b, Xa);

  // Stem stage 0: 8 MLP blocks, dim 128, hidden 384 (token-chunked x4)
  for (int i = 0; i < 8; ++i) {
    lnC_kernel<128><<<65536 / 4, 256, 0, stream>>>(Xa, s0_n2w + i * 128,
                                                   s0_n2b + i * 128, Bb);
    for (int c = 0; c < 4; ++c) {
      const float* Ain = Bb + c * 16384 * 128;
      float* Xc = Xa + c * 16384 * 128;
      mgemm_kernel<3><<<(16384 / 128) * (384 / 128), 256, 0, stream>>>(
          Ain, s0_f1w + i * 49152, s0_f1b + i * 384, nullptr, Cc, 16384, 384,
          128);
      mgemm_kernel<2><<<(16384 / 128) * (128 / 128), 256, 0, stream>>>(
          Cc, s0_f2w + i * 49152, s0_f2b + i * 128, Xc, Xc, 16384, 128, 384);
    }
  }
  // Merge 0: -> Bb [16384,512] -> GEMM -> Xa [16384,256]
  merge_ln_kernel<0><<<16384, 256, 0, stream>>>(Xa, m0_nw, m0_nb, Bb);
  mgemm_kernel<0><<<(16384 / 128) * (256 / 128), 256, 0, stream>>>(
      Bb, m0_rw, nullptr, nullptr, Xa, 16384, 256, 512);

  // Stem stage 1: 8 MLP blocks, dim 256, hidden 768 (token-chunked x2)
  for (int i = 0; i < 8; ++i) {
    lnC_kernel<256><<<16384 / 4, 256, 0, stream>>>(Xa, s1_n2w + i * 256,
                                                   s1_n2b + i * 256, Bb);
    for (int c = 0; c < 2; ++c) {
      const float* Ain = Bb + c * 8192 * 256;
      float* Xc = Xa + c * 8192 * 256;
      mgemm_kernel<3><<<(8192 / 128) * (768 / 128), 256, 0, stream>>>(
          Ain, s1_f1w + i * 196608, s1_f1b + i * 768, nullptr, Cc, 8192, 768,
          256);
      mgemm_kernel<2><<<(8192 / 128) * (256 / 128), 256, 0, stream>>>(
          Cc, s1_f2w + i * 196608, s1_f2b + i * 256, Xc, Xc, 8192, 256, 768);
    }
  }
  // Merge 1: -> Bb [4096,1024] -> GEMM + pos -> Xa [4096,512]
  merge_ln_kernel<1><<<4096, 256, 0, stream>>>(Xa, m1_nw, m1_nb, Bb);
  mgemm_kernel<1><<<(4096 / 128) * (512 / 128), 256, 0, stream>>>(
      Bb, m1_rw, nullptr, pos_embed, Xa, 4096, 512, 1024);

  // 20 main attention blocks
  for (int l = 0; l < 20; ++l) {
    ln512_kernel<<<4096, 64, 0, stream>>>(Xa, mb_n1w + l * 512,
                                          mb_n1b + l * 512, Bb);
    mgemm_kernel<0><<<(4096 / 128) * (1536 / 128), 256, 0, stream>>>(
        Bb, mb_qkvw + l * 786432, mb_qkvb + l * 1536, nullptr, Cc, 4096, 1536,
        512);
    attn_score_kernel<<<32768, 64, 0, stream>>>(Cc, mb_rpb + l * 7688, rpe, Bb);
    attn_pv_kernel<<<512, 256, 0, stream>>>(Bb, Cc, Dd);
    mgemm_kernel<2><<<(4096 / 128) * (512 / 128), 256, 0, stream>>>(
        Dd, mb_projw + l * 262144, mb_projb + l * 512, Xa, Xa, 4096, 512, 512);
    ln512_kernel<<<4096, 64, 0, stream>>>(Xa, mb_n2w + l * 512,
                                          mb_n2b + l * 512, Dd);
    mgemm_kernel<3><<<(4096 / 128) * (2048 / 128), 256, 0, stream>>>(
        Dd, mb_f1w + l * 1048576, mb_f1b + l * 2048, nullptr, Bb, 4096, 2048,
        512);
    mgemm_kernel<2><<<(4096 / 128) * (512 / 128), 256, 0, stream>>>(
        Bb, mb_f2w + l * 1048576, mb_f2b + l * 512, Xa, Xa, 4096, 512, 2048);
  }
  // Final LN -> d_out
  ln512_kernel<<<4096, 64, 0, stream>>>(Xa, fnorm_w, fnorm_b, (float*)d_out);
}

// Round 6
// 14269.612 us; speedup vs baseline: 5.4416x; 1.0105x over previous
//
#include <hip/hip_runtime.h>
#include <math.h>

#define EPSV 1e-5f

typedef __attribute__((ext_vector_type(8))) short bf16x8;
typedef __attribute__((ext_vector_type(4))) float f32x4;
typedef unsigned short ushort;

__device__ inline ushort f2bf(float x) {
  unsigned u = __builtin_bit_cast(unsigned, x);
  u += 0x7FFFu + ((u >> 16) & 1u);
  return (ushort)(u >> 16);
}
__device__ inline float bf2f(ushort h) {
  unsigned u = ((unsigned)h) << 16;
  return __builtin_bit_cast(float, u);
}

// async global->LDS, 16 bytes per lane; dest = wave-uniform base + lane*16
#define GLOAD16(lptr, gptr)                                              \
  __builtin_amdgcn_global_load_lds(                                      \
      (const __attribute__((address_space(1))) unsigned int*)(gptr),     \
      (__attribute__((address_space(3))) unsigned int*)(lptr), 16, 0, 0)

// ---------------------------------------------------------------------------
// f32 -> (hi,lo) bf16 plane conversion (weights). n4 = count/4.
// ---------------------------------------------------------------------------
__global__ __launch_bounds__(256) void convhl_kernel(
    const float* __restrict__ in, ushort* __restrict__ hi,
    ushort* __restrict__ lo, int n4) {
  int i = blockIdx.x * 256 + threadIdx.x;
  if (i >= n4) return;
  float4 v = ((const float4*)in)[i];
  float vv[4] = {v.x, v.y, v.z, v.w};
  unsigned hw[4], lw[4];
#pragma unroll
  for (int e = 0; e < 4; ++e) {
    ushort h = f2bf(vv[e]);
    hw[e] = h;
    lw[e] = f2bf(vv[e] - bf2f(h));
  }
  ((uint2*)hi)[i] = make_uint2(hw[0] | (hw[1] << 16), hw[2] | (hw[3] << 16));
  ((uint2*)lo)[i] = make_uint2(lw[0] | (lw[1] << 16), lw[2] | (lw[3] << 16));
}

// ---------------------------------------------------------------------------
// Patch embed (4x4/4 conv) + pnorm LN, fused. Writes f32 residual state.
// ---------------------------------------------------------------------------
__global__ __launch_bounds__(128) void patch_ln_kernel(
    const float* __restrict__ x, const float* __restrict__ pw,
    const float* __restrict__ pbias, const float* __restrict__ nw,
    const float* __restrict__ nb, float* __restrict__ out) {
  int tk = blockIdx.x;
  int t = threadIdx.x;
  int b = tk >> 12;
  int n = (tk >> 4) & 255;
  int ii = (tk >> 2) & 3;
  int jj = tk & 3;
  int Y = ((n >> 4) << 2) + ii;
  int X = ((n & 15) << 2) + jj;

  __shared__ float px[48];
  __shared__ float redA[2];
  __shared__ float redB[2];
  if (t < 48) {
    int ci = t >> 4, dy = (t >> 2) & 3, dx = t & 3;
    px[t] = x[((b * 3 + ci) * 256 + (Y * 4 + dy)) * 256 + (X * 4 + dx)];
  }
  __syncthreads();

  float acc = pbias[t];
  const float* wr = pw + t * 48;
#pragma unroll
  for (int q = 0; q < 48; ++q) acc += wr[q] * px[q];

  float s = acc;
#pragma unroll
  for (int o = 32; o > 0; o >>= 1) s += __shfl_xor(s, o, 64);
  if ((t & 63) == 0) redA[t >> 6] = s;
  __syncthreads();
  float mean = (redA[0] + redA[1]) * (1.0f / 128.0f);
  float d = acc - mean;
  float sq = d * d;
#pragma unroll
  for (int o = 32; o > 0; o >>= 1) sq += __shfl_xor(sq, o, 64);
  if ((t & 63) == 0) redB[t >> 6] = sq;
  __syncthreads();
  float var = (redB[0] + redB[1]) * (1.0f / 128.0f);
  out[tk * 128 + t] = d * rsqrtf(var + EPSV) * nw[t] + nb[t];
}

// ---------------------------------------------------------------------------
// LayerNorm over C (128/256), one wave per row, 4 rows/block -> hi/lo planes.
// ---------------------------------------------------------------------------
template <int C>
__global__ __launch_bounds__(256) void lnC_kernel(
    const float* __restrict__ X, const float* __restrict__ w,
    const float* __restrict__ bb, ushort* __restrict__ outH,
    ushort* __restrict__ outL) {
  constexpr int NV = C / 64;
  int wave = threadIdx.x >> 6, lane = threadIdx.x & 63;
  int row = blockIdx.x * 4 + wave;
  const float* xr = X + (size_t)row * C + lane * NV;
  float v[NV];
  if (NV == 2) {
    float2 t2 = *(const float2*)xr;
    v[0] = t2.x; v[1] = t2.y;
  } else {
#pragma unroll
    for (int q = 0; q < NV; q += 4) {
      float4 t4 = *(const float4*)(xr + q);
      v[q] = t4.x; v[q + 1] = t4.y; v[q + 2] = t4.z; v[q + 3] = t4.w;
    }
  }
  float s = 0.f;
#pragma unroll
  for (int q = 0; q < NV; ++q) s += v[q];
#pragma unroll
  for (int o = 32; o > 0; o >>= 1) s += __shfl_xor(s, o, 64);
  float mean = s * (1.0f / C);
  float sq = 0.f;
#pragma unroll
  for (int q = 0; q < NV; ++q) {
    float d = v[q] - mean;
    sq += d * d;
  }
#pragma unroll
  for (int o = 32; o > 0; o >>= 1) sq += __shfl_xor(sq, o, 64);
  float rstd = rsqrtf(sq * (1.0f / C) + EPSV);
#pragma unroll
  for (int q = 0; q < NV; ++q) {
    int c = lane * NV + q;
    float o = (v[q] - mean) * rstd * w[c] + bb[c];
    ushort h = f2bf(o);
    outH[(size_t)row * C + c] = h;
    outL[(size_t)row * C + c] = f2bf(o - bf2f(h));
  }
}

// ---------------------------------------------------------------------------
// Patch merge gather + LN -> hi/lo planes.
// ---------------------------------------------------------------------------
template <int MODE>
__global__ __launch_bounds__(256) void merge_ln_kernel(
    const float* __restrict__ Xin, const float* __restrict__ nw,
    const float* __restrict__ nb, ushort* __restrict__ outH,
    ushort* __restrict__ outL) {
  constexpr int CM = MODE ? 1024 : 512;
  constexpr int NE = CM / 256;
  int ot = blockIdx.x;
  int tid = threadIdx.x;
  __shared__ float redA[4];
  __shared__ float redB[4];

  float v[NE];
#pragma unroll
  for (int e = 0; e < NE; ++e) {
    int cp = tid + e * 256;
    if (MODE == 0) {
      int b = ot >> 10, r = ot & 1023;
      int n = r >> 2, di = (r >> 1) & 1, dj = r & 1;
      int q = cp >> 7, c = cp & 127;
      int i = 2 * di + (q & 1), j = 2 * dj + (q >> 1);
      v[e] = Xin[((b * 256 + n) * 16 + i * 4 + j) * 128 + c];
    } else {
      int b = ot >> 8, n = ot & 255;
      int q = cp >> 8, c = cp & 255;
      int di = q & 1, dj = q >> 1;
      v[e] = Xin[((b * 256 + n) * 4 + di * 2 + dj) * 256 + c];
    }
  }
  float s = 0.f;
#pragma unroll
  for (int e = 0; e < NE; ++e) s += v[e];
#pragma unroll
  for (int o = 32; o > 0; o >>= 1) s += __shfl_xor(s, o, 64);
  if ((tid & 63) == 0) redA[tid >> 6] = s;
  __syncthreads();
  float mean = (redA[0] + redA[1] + redA[2] + redA[3]) * (1.0f / CM);
  float sq = 0.f;
#pragma unroll
  for (int e = 0; e < NE; ++e) {
    float d = v[e] - mean;
    sq += d * d;
  }
#pragma unroll
  for (int o = 32; o > 0; o >>= 1) sq += __shfl_xor(sq, o, 64);
  if ((tid & 63) == 0) redB[tid >> 6] = sq;
  __syncthreads();
  float var = (redB[0] + redB[1] + redB[2] + redB[3]) * (1.0f / CM);
  float rstd = rsqrtf(var + EPSV);
#pragma unroll
  for (int e = 0; e < NE; ++e) {
    int cp = tid + e * 256;
    float o = (v[e] - mean) * rstd * nw[cp] + nb[cp];
    ushort h = f2bf(o);
    outH[(size_t)ot * CM + cp] = h;
    outL[(size_t)ot * CM + cp] = f2bf(o - bf2f(h));
  }
}

// ---------------------------------------------------------------------------
// Pure-bf16 MFMA GEMM over preconverted hi/lo planes.
// C = Ah*Wh^T + Al*Wh^T + Ah*Wl^T (f32 accum). Tile 128x128, BK=32,
// 256 thr (4 waves 2x2), global_load_lds staging (linear LDS, 32 KB).
// EP 0: bias->f32. EP 1: +pos[(m&255)*N+n]->f32. EP 2: +extra[m*N+n]->f32.
// EP 3: gelu(acc+bias) -> hi/lo planes.
// ---------------------------------------------------------------------------
template <int EP>
__global__ __launch_bounds__(256) void mgemm2_kernel(
    const ushort* __restrict__ Ah, const ushort* __restrict__ Al,
    const ushort* __restrict__ Wh, const ushort* __restrict__ Wl,
    const float* __restrict__ bias, const float* __restrict__ extra,
    float* __restrict__ outF, ushort* __restrict__ outH,
    ushort* __restrict__ outL, int M, int N, int K) {
  __shared__ __align__(16) ushort Lds[16384];  // Ah|Al|Wh|Wl, 4096 shorts each
  int nb = N >> 7;
  int bx = blockIdx.x % nb, by = blockIdx.x / nb;
  int tid = threadIdx.x;
  int r0 = tid >> 2;
  int cc = (tid & 3) << 3;
  const ushort* aS0 = Ah + (size_t)(by * 128 + r0) * K + cc;
  const ushort* aS1 = aS0 + (size_t)64 * K;
  const ushort* lS0 = Al + (size_t)(by * 128 + r0) * K + cc;
  const ushort* lS1 = lS0 + (size_t)64 * K;
  const ushort* wS0 = Wh + (size_t)(bx * 128 + r0) * K + cc;
  const ushort* wS1 = wS0 + (size_t)64 * K;
  const ushort* vS0 = Wl + (size_t)(bx * 128 + r0) * K + cc;
  const ushort* vS1 = vS0 + (size_t)64 * K;
  int wv = tid >> 6;
  ushort* dA0 = Lds + wv * 512;
  ushort* dA1 = Lds + 2048 + wv * 512;
  ushort* dL0 = Lds + 4096 + wv * 512;
  ushort* dL1 = Lds + 6144 + wv * 512;
  ushort* dW0 = Lds + 8192 + wv * 512;
  ushort* dW1 = Lds + 10240 + wv * 512;
  ushort* dV0 = Lds + 12288 + wv * 512;
  ushort* dV1 = Lds + 14336 + wv * 512;

  int lane = tid & 63;
  int wm = (wv >> 1) * 64, wn = (wv & 1) * 64;
  int fr = lane & 15, fq = lane >> 4;
  const ushort* raA = Lds + (wm + fr) * 32 + fq * 8;
  const ushort* raW = Lds + 8192 + (wn + fr) * 32 + fq * 8;

  f32x4 acc[4][4];
#pragma unroll
  for (int i = 0; i < 4; ++i)
#pragma unroll
    for (int j = 0; j < 4; ++j) acc[i][j] = {0.f, 0.f, 0.f, 0.f};

  for (int k0 = 0; k0 < K; k0 += 32) {
    GLOAD16(dA0, aS0 + k0);
    GLOAD16(dA1, aS1 + k0);
    GLOAD16(dL0, lS0 + k0);
    GLOAD16(dL1, lS1 + k0);
    GLOAD16(dW0, wS0 + k0);
    GLOAD16(dW1, wS1 + k0);
    GLOAD16(dV0, vS0 + k0);
    GLOAD16(dV1, vS1 + k0);
    __syncthreads();  // drains vmcnt(0): tiles resident

    bf16x8 fa[4], fl[4], fb[4], fv[4];
#pragma unroll
    for (int i = 0; i < 4; ++i) {
      fa[i] = *(const bf16x8*)(raA + i * 512);
      fl[i] = *(const bf16x8*)(raA + 4096 + i * 512);
      fb[i] = *(const bf16x8*)(raW + i * 512);
      fv[i] = *(const bf16x8*)(raW + 4096 + i * 512);
    }
#pragma unroll
    for (int i = 0; i < 4; ++i)
#pragma unroll
      for (int j = 0; j < 4; ++j) {
        acc[i][j] = __builtin_amdgcn_mfma_f32_16x16x32_bf16(fa[i], fb[j],
                                                            acc[i][j], 0, 0, 0);
        acc[i][j] = __builtin_amdgcn_mfma_f32_16x16x32_bf16(fl[i], fb[j],
                                                            acc[i][j], 0, 0, 0);
        acc[i][j] = __builtin_amdgcn_mfma_f32_16x16x32_bf16(fa[i], fv[j],
                                                            acc[i][j], 0, 0, 0);
      }
    __syncthreads();  // LDS safe to overwrite
  }

  int row0 = by * 128 + wm;
  int col0 = bx * 128 + wn;
#pragma unroll
  for (int j = 0; j < 4; ++j) {
    int col = col0 + j * 16 + fr;
    float bvv = bias ? bias[col] : 0.f;
#pragma unroll
    for (int i = 0; i < 4; ++i) {
#pragma unroll
      for (int e = 0; e < 4; ++e) {
        int row = row0 + i * 16 + fq * 4 + e;
        float o = acc[i][j][e] + bvv;
        if (EP == 1) {
          o += extra[(row & 255) * N + col];
          outF[(size_t)row * N + col] = o;
        } else if (EP == 2) {
          o += extra[(size_t)row * N + col];
          outF[(size_t)row * N + col] = o;
        } else if (EP == 3) {
          o = 0.5f * o * (1.0f + erff(o * 0.70710678118654752f));
          ushort h = f2bf(o);
          outH[(size_t)row * N + col] = h;
          outL[(size_t)row * N + col] = f2bf(o - bf2f(h));
        } else {
          outF[(size_t)row * N + col] = o;
        }
      }
    }
  }
}

// ---------------------------------------------------------------------------
// Attention scores + softmax. One block (64 threads) per (b, h, n).
// ---------------------------------------------------------------------------
__global__ __launch_bounds__(64) void attn_score_kernel(
    const float* __restrict__ qkv, const float* __restrict__ rpb,
    const int* __restrict__ rpe, float* __restrict__ P) {
  int bid = blockIdx.x;
  int n = bid & 255, h = (bid >> 8) & 7, b = bid >> 11;
  int t = threadIdx.x;
  __shared__ float qsh[64];
  qsh[t] = qkv[(b * 256 + n) * 1536 + h * 64 + t] * 0.125f;
  __syncthreads();

  float s[4];
#pragma unroll
  for (int r = 0; r < 4; ++r) {
    int m = r * 64 + t;
    const float4* kr = (const float4*)(qkv + (b * 256 + m) * 1536 + 512 + h * 64);
    float acc = 0.f;
#pragma unroll
    for (int d4 = 0; d4 < 16; ++d4) {
      float4 k4 = kr[d4];
      float4 q4 = *(const float4*)&qsh[d4 * 4];
      acc += k4.x * q4.x + k4.y * q4.y + k4.z * q4.z + k4.w * q4.w;
    }
    int idx = rpe[n * 256 + m];
    s[r] = acc + rpb[idx * 8 + h];
  }
  float mx = fmaxf(fmaxf(s[0], s[1]), fmaxf(s[2], s[3]));
#pragma unroll
  for (int o = 32; o > 0; o >>= 1) mx = fmaxf(mx, __shfl_xor(mx, o, 64));
  float p[4];
  float sum = 0.f;
#pragma unroll
  for (int r = 0; r < 4; ++r) {
    p[r] = expf(s[r] - mx);
    sum += p[r];
  }
#pragma unroll
  for (int o = 32; o > 0; o >>= 1) sum += __shfl_xor(sum, o, 64);
  float inv = 1.0f / sum;
  float* Pr = P + ((size_t)(b * 8 + h) * 256 + n) * 256;
#pragma unroll
  for (int r = 0; r < 4; ++r) Pr[r * 64 + t] = p[r] * inv;
}

// ---------------------------------------------------------------------------
// O = P @ V -> hi/lo planes. One block per (b, h, 64-query tile).
// ---------------------------------------------------------------------------
__global__ __launch_bounds__(256) void attn_pv_kernel(
    const float* __restrict__ P, const float* __restrict__ qkv,
    ushort* __restrict__ outH, ushort* __restrict__ outL) {
  int bid = blockIdx.x;
  int nt = bid & 3, h = (bid >> 2) & 7, b = bid >> 5;
  int tid = threadIdx.x;
  __shared__ float Vsh[256 * 64];
  for (int idx = tid; idx < 4096; idx += 256) {
    int m = idx >> 4, d4 = idx & 15;
    ((float4*)Vsh)[m * 16 + d4] =
        *(const float4*)(qkv + (b * 256 + m) * 1536 + 1024 + h * 64 + d4 * 4);
  }
  __syncthreads();

  int d = tid & 63, ng = tid >> 6;
  const float* Pb = P + ((size_t)(b * 8 + h) * 256 + nt * 64 + ng * 16) * 256;
#pragma unroll 1
  for (int i = 0; i < 16; ++i) {
    const float4* pr = (const float4*)(Pb + i * 256);
    float a = 0.f;
    for (int m4 = 0; m4 < 64; ++m4) {
      float4 p4 = pr[m4];
      a += p4.x * Vsh[(m4 * 4 + 0) * 64 + d];
      a += p4.y * Vsh[(m4 * 4 + 1) * 64 + d];
      a += p4.z * Vsh[(m4 * 4 + 2) * 64 + d];
      a += p4.w * Vsh[(m4 * 4 + 3) * 64 + d];
    }
    int nn = nt * 64 + ng * 16 + i;
    size_t oidx = (size_t)(b * 256 + nn) * 512 + h * 64 + d;
    ushort hh = f2bf(a);
    outH[oidx] = hh;
    outL[oidx] = f2bf(a - bf2f(hh));
  }
}

// ---------------------------------------------------------------------------
// LayerNorm over 512, one wave per row. HL=0 -> f32, HL=1 -> hi/lo planes.
// ---------------------------------------------------------------------------
template <int HL>
__global__ __launch_bounds__(64) void ln512_kernel(
    const float* __restrict__ X, const float* __restrict__ w,
    const float* __restrict__ bb, float* __restrict__ outF,
    ushort* __restrict__ outH, ushort* __restrict__ outL) {
  int row = blockIdx.x, t = threadIdx.x;
  const float4* xr = (const float4*)(X + (size_t)row * 512);
  float4 v0 = xr[t * 2], v1 = xr[t * 2 + 1];
  float s = v0.x + v0.y + v0.z + v0.w + v1.x + v1.y + v1.z + v1.w;
#pragma unroll
  for (int o = 32; o > 0; o >>= 1) s += __shfl_xor(s, o, 64);
  float mean = s * (1.0f / 512.0f);
  float dv[8] = {v0.x - mean, v0.y - mean, v0.z - mean, v0.w - mean,
                 v1.x - mean, v1.y - mean, v1.z - mean, v1.w - mean};
  float sq = 0.f;
#pragma unroll
  for (int e = 0; e < 8; ++e) sq += dv[e] * dv[e];
#pragma unroll
  for (int o = 32; o > 0; o >>= 1) sq += __shfl_xor(sq, o, 64);
  float rstd = rsqrtf(sq * (1.0f / 512.0f) + EPSV);
  int c = t * 8;
  float ov[8];
#pragma unroll
  for (int e = 0; e < 8; ++e) ov[e] = dv[e] * rstd * w[c + e] + bb[c + e];
  if (HL == 0) {
    float4 o0 = {ov[0], ov[1], ov[2], ov[3]};
    float4 o1 = {ov[4], ov[5], ov[6], ov[7]};
    ((float4*)(outF + (size_t)row * 512))[t * 2] = o0;
    ((float4*)(outF + (size_t)row * 512))[t * 2 + 1] = o1;
  } else {
    __align__(16) ushort h8[8], l8[8];
#pragma unroll
    for (int e = 0; e < 8; ++e) {
      h8[e] = f2bf(ov[e]);
      l8[e] = f2bf(ov[e] - bf2f(h8[e]));
    }
    *(bf16x8*)(outH + (size_t)row * 512 + c) = *(bf16x8*)h8;
    *(bf16x8*)(outL + (size_t)row * 512 + c) = *(bf16x8*)l8;
  }
}

// ---------------------------------------------------------------------------
extern "C" void kernel_launch(void* const* d_in, const int* in_sizes, int n_in,
                              void* d_out, int out_size, void* d_ws,
                              size_t ws_size, hipStream_t stream) {
  const float* x = (const float*)d_in[0];
  const float* patch_w = (const float*)d_in[1];
  const float* patch_b = (const float*)d_in[2];
  const float* pnorm_w = (const float*)d_in[3];
  const float* pnorm_b = (const float*)d_in[4];
  const float* s0_n2w = (const float*)d_in[5];
  const float* s0_n2b = (const float*)d_in[6];
  const float* s0_f1w = (const float*)d_in[7];
  const float* s0_f1b = (const float*)d_in[8];
  const float* s0_f2w = (const float*)d_in[9];
  const float* s0_f2b = (const float*)d_in[10];
  const float* m0_nw = (const float*)d_in[11];
  const float* m0_nb = (const float*)d_in[12];
  const float* m0_rw = (const float*)d_in[13];
  const float* s1_n2w = (const float*)d_in[14];
  const float* s1_n2b = (const float*)d_in[15];
  const float* s1_f1w = (const float*)d_in[16];
  const float* s1_f1b = (const float*)d_in[17];
  const float* s1_f2w = (const float*)d_in[18];
  const float* s1_f2b = (const float*)d_in[19];
  const float* m1_nw = (const float*)d_in[20];
  const float* m1_nb = (const float*)d_in[21];
  const float* m1_rw = (const float*)d_in[22];
  const float* pos_embed = (const float*)d_in[23];
  const float* mb_n1w = (const float*)d_in[24];
  const float* mb_n1b = (const float*)d_in[25];
  const float* mb_qkvw = (const float*)d_in[26];
  const float* mb_qkvb = (const float*)d_in[27];
  const float* mb_rpb = (const float*)d_in[28];
  const float* mb_projw = (const float*)d_in[29];
  const float* mb_projb = (const float*)d_in[30];
  const float* mb_n2w = (const float*)d_in[31];
  const float* mb_n2b = (const float*)d_in[32];
  const float* mb_f1w = (const float*)d_in[33];
  const float* mb_f1b = (const float*)d_in[34];
  const float* mb_f2w = (const float*)d_in[35];
  const float* mb_f2b = (const float*)d_in[36];
  const float* fnorm_w = (const float*)d_in[37];
  const float* fnorm_b = (const float*)d_in[38];
  const int* rpe = (const int*)d_in[39];

  // Workspace: 27,262,976 floats = 109.1 MB
  float* Xa = (float*)d_ws;                     // 8,388,608 f (residual state)
  ushort* R1h = (ushort*)(Xa + 8388608);        // 2,097,152 sh
  ushort* R1l = R1h + 2097152;                  // 2,097,152 sh
  float* R2f = (float*)(R1l + 2097152);         // 8,388,608 f (P / gelu planes)
  ushort* R2h = (ushort*)R2f;
  ushort* R2l = R2h + 8388608;
  float* Qkv = R2f + 8388608;                   // 6,291,456 f
  ushort* W1h = (ushort*)(Qkv + 6291456);       // 1,048,576 sh
  ushort* W1l = W1h + 1048576;
  ushort* W2h = W1l + 1048576;
  ushort* W2l = W2h + 1048576;

#define CONV(src, cnt, dh, dl)                                            \
  convhl_kernel<<<((cnt) / 4 + 255) / 256, 256, 0, stream>>>(src, dh, dl, \
                                                             (cnt) / 4)

  // Patch embed + pnorm LN -> Xa [65536,128]
  patch_ln_kernel<<<65536, 128, 0, stream>>>(x, patch_w, patch_b, pnorm_w,
                                             pnorm_b, Xa);

  // Stem stage 0: 8 MLP blocks, dim 128, hidden 384 (token-chunked x4)
  for (int i = 0; i < 8; ++i) {
    CONV(s0_f1w + i * 49152, 49152, W1h, W1l);
    CONV(s0_f2w + i * 49152, 49152, W2h, W2l);
    for (int c = 0; c < 4; ++c) {
      float* Xc = Xa + (size_t)c * 16384 * 128;
      lnC_kernel<128><<<16384 / 4, 256, 0, stream>>>(Xc, s0_n2w + i * 128,
                                                     s0_n2b + i * 128, R1h, R1l);
      mgemm2_kernel<3><<<(16384 / 128) * (384 / 128), 256, 0, stream>>>(
          R1h, R1l, W1h, W1l, s0_f1b + i * 384, nullptr, nullptr, R2h, R2l,
          16384, 384, 128);
      mgemm2_kernel<2><<<(16384 / 128) * (128 / 128), 256, 0, stream>>>(
          R2h, R2l, W2h, W2l, s0_f2b + i * 128, Xc, Xc, nullptr, nullptr,
          16384, 128, 384);
    }
  }
  // Merge 0 -> R2 planes [16384,512] -> GEMM -> Xa [16384,256]
  merge_ln_kernel<0><<<16384, 256, 0, stream>>>(Xa, m0_nw, m0_nb, R2h, R2l);
  CONV(m0_rw, 131072, W1h, W1l);
  mgemm2_kernel<0><<<(16384 / 128) * (256 / 128), 256, 0, stream>>>(
      R2h, R2l, W1h, W1l, nullptr, nullptr, Xa, nullptr, nullptr, 16384, 256,
      512);

  // Stem stage 1: 8 MLP blocks, dim 256, hidden 768 (token-chunked x2)
  for (int i = 0; i < 8; ++i) {
    CONV(s1_f1w + i * 196608, 196608, W1h, W1l);
    CONV(s1_f2w + i * 196608, 196608, W2h, W2l);
    for (int c = 0; c < 2; ++c) {
      float* Xc = Xa + (size_t)c * 8192 * 256;
      lnC_kernel<256><<<8192 / 4, 256, 0, stream>>>(Xc, s1_n2w + i * 256,
                                                    s1_n2b + i * 256, R1h, R1l);
      mgemm2_kernel<3><<<(8192 / 128) * (768 / 128), 256, 0, stream>>>(
          R1h, R1l, W1h, W1l, s1_f1b + i * 768, nullptr, nullptr, R2h, R2l,
          8192, 768, 256);
      mgemm2_kernel<2><<<(8192 / 128) * (256 / 128), 256, 0, stream>>>(
          R2h, R2l, W2h, W2l, s1_f2b + i * 256, Xc, Xc, nullptr, nullptr, 8192,
          256, 768);
    }
  }
  // Merge 1 -> R2 planes [4096,1024] -> GEMM + pos -> Xa [4096,512]
  merge_ln_kernel<1><<<4096, 256, 0, stream>>>(Xa, m1_nw, m1_nb, R2h, R2l);
  CONV(m1_rw, 524288, W1h, W1l);
  mgemm2_kernel<1><<<(4096 / 128) * (512 / 128), 256, 0, stream>>>(
      R2h, R2l, W1h, W1l, nullptr, pos_embed, Xa, nullptr, nullptr, 4096, 512,
      1024);

  // 20 main attention blocks
  for (int l = 0; l < 20; ++l) {
    ln512_kernel<1><<<4096, 64, 0, stream>>>(Xa, mb_n1w + l * 512,
                                             mb_n1b + l * 512, nullptr, R1h,
                                             R1l);
    CONV(mb_qkvw + l * 786432, 786432, W1h, W1l);
    mgemm2_kernel<0><<<(4096 / 128) * (1536 / 128), 256, 0, stream>>>(
        R1h, R1l, W1h, W1l, mb_qkvb + l * 1536, nullptr, Qkv, nullptr, nullptr,
        4096, 1536, 512);
    attn_score_kernel<<<32768, 64, 0, stream>>>(Qkv, mb_rpb + l * 7688, rpe,
                                                R2f);
    attn_pv_kernel<<<512, 256, 0, stream>>>(R2f, Qkv, R1h, R1l);
    CONV(mb_projw + l * 262144, 262144, W1h, W1l);
    mgemm2_kernel<2><<<(4096 / 128) * (512 / 128), 256, 0, stream>>>(
        R1h, R1l, W1h, W1l, mb_projb + l * 512, Xa, Xa, nullptr, nullptr, 4096,
        512, 512);
    ln512_kernel<1><<<4096, 64, 0, stream>>>(Xa, mb_n2w + l * 512,
                                             mb_n2b + l * 512, nullptr, R1h,
                                             R1l);
    CONV(mb_f1w + l * 1048576, 1048576, W1h, W1l);
    CONV(mb_f2w + l * 1048576, 1048576, W2h, W2l);
    mgemm2_kernel<3><<<(4096 / 128) * (2048 / 128), 256, 0, stream>>>(
        R1h, R1l, W1h, W1l, mb_f1b + l * 2048, nullptr, nullptr, R2h, R2l,
        4096, 2048, 512);
    mgemm2_kernel<2><<<(4096 / 128) * (512 / 128), 256, 0, stream>>>(
        R2h, R2l, W2h, W2l, mb_f2b + l * 512, Xa, Xa, nullptr, nullptr, 4096,
        512, 2048);
  }
  // Final LN -> d_out (f32)
  ln512_kernel<0><<<4096, 64, 0, stream>>>(Xa, fnorm_w, fnorm_b,
                                           (float*)d_out, nullptr, nullptr);
}

// Round 7
// 8475.299 us; speedup vs baseline: 9.1618x; 1.6837x over previous
//
#include <hip/hip_runtime.h>
#include <math.h>

#define EPSV 1e-5f

typedef __attribute__((ext_vector_type(8))) short bf16x8;
typedef __attribute__((ext_vector_type(4))) float f32x4;
typedef unsigned short ushort;

__device__ inline ushort f2bf(float x) {
  unsigned u = __builtin_bit_cast(unsigned, x);
  u += 0x7FFFu + ((u >> 16) & 1u);
  return (ushort)(u >> 16);
}
__device__ inline float bf2f(ushort h) {
  unsigned u = ((unsigned)h) << 16;
  return __builtin_bit_cast(float, u);
}

// async global->LDS, 16 bytes per lane; dest = wave-uniform base + lane*16
#define GLOAD16(lptr, gptr)                                              \
  __builtin_amdgcn_global_load_lds(                                      \
      (const __attribute__((address_space(1))) unsigned int*)(gptr),     \
      (__attribute__((address_space(3))) unsigned int*)(lptr), 16, 0, 0)

// ---------------------------------------------------------------------------
// f32 -> (hi,lo) bf16 plane conversion (weights). n4 = count/4.
// ---------------------------------------------------------------------------
__global__ __launch_bounds__(256) void convhl_kernel(
    const float* __restrict__ in, ushort* __restrict__ hi,
    ushort* __restrict__ lo, int n4) {
  int i = blockIdx.x * 256 + threadIdx.x;
  if (i >= n4) return;
  float4 v = ((const float4*)in)[i];
  float vv[4] = {v.x, v.y, v.z, v.w};
  unsigned hw[4], lw[4];
#pragma unroll
  for (int e = 0; e < 4; ++e) {
    ushort h = f2bf(vv[e]);
    hw[e] = h;
    lw[e] = f2bf(vv[e] - bf2f(h));
  }
  ((uint2*)hi)[i] = make_uint2(hw[0] | (hw[1] << 16), hw[2] | (hw[3] << 16));
  ((uint2*)lo)[i] = make_uint2(lw[0] | (lw[1] << 16), lw[2] | (lw[3] << 16));
}

// ---------------------------------------------------------------------------
// Patch embed (4x4/4 conv) + pnorm LN, fused. Writes f32 residual state.
// ---------------------------------------------------------------------------
__global__ __launch_bounds__(128) void patch_ln_kernel(
    const float* __restrict__ x, const float* __restrict__ pw,
    const float* __restrict__ pbias, const float* __restrict__ nw,
    const float* __restrict__ nb, float* __restrict__ out) {
  int tk = blockIdx.x;
  int t = threadIdx.x;
  int b = tk >> 12;
  int n = (tk >> 4) & 255;
  int ii = (tk >> 2) & 3;
  int jj = tk & 3;
  int Y = ((n >> 4) << 2) + ii;
  int X = ((n & 15) << 2) + jj;

  __shared__ float px[48];
  __shared__ float redA[2];
  __shared__ float redB[2];
  if (t < 48) {
    int ci = t >> 4, dy = (t >> 2) & 3, dx = t & 3;
    px[t] = x[((b * 3 + ci) * 256 + (Y * 4 + dy)) * 256 + (X * 4 + dx)];
  }
  __syncthreads();

  float acc = pbias[t];
  const float* wr = pw + t * 48;
#pragma unroll
  for (int q = 0; q < 48; ++q) acc += wr[q] * px[q];

  float s = acc;
#pragma unroll
  for (int o = 32; o > 0; o >>= 1) s += __shfl_xor(s, o, 64);
  if ((t & 63) == 0) redA[t >> 6] = s;
  __syncthreads();
  float mean = (redA[0] + redA[1]) * (1.0f / 128.0f);
  float d = acc - mean;
  float sq = d * d;
#pragma unroll
  for (int o = 32; o > 0; o >>= 1) sq += __shfl_xor(sq, o, 64);
  if ((t & 63) == 0) redB[t >> 6] = sq;
  __syncthreads();
  float var = (redB[0] + redB[1]) * (1.0f / 128.0f);
  out[tk * 128 + t] = d * rsqrtf(var + EPSV) * nw[t] + nb[t];
}

// ---------------------------------------------------------------------------
// LayerNorm over C (128/256), one wave per row, 4 rows/block -> hi/lo planes.
// ---------------------------------------------------------------------------
template <int C>
__global__ __launch_bounds__(256) void lnC_kernel(
    const float* __restrict__ X, const float* __restrict__ w,
    const float* __restrict__ bb, ushort* __restrict__ outH,
    ushort* __restrict__ outL) {
  constexpr int NV = C / 64;
  int wave = threadIdx.x >> 6, lane = threadIdx.x & 63;
  int row = blockIdx.x * 4 + wave;
  const float* xr = X + (size_t)row * C + lane * NV;
  float v[NV];
  if (NV == 2) {
    float2 t2 = *(const float2*)xr;
    v[0] = t2.x; v[1] = t2.y;
  } else {
#pragma unroll
    for (int q = 0; q < NV; q += 4) {
      float4 t4 = *(const float4*)(xr + q);
      v[q] = t4.x; v[q + 1] = t4.y; v[q + 2] = t4.z; v[q + 3] = t4.w;
    }
  }
  float s = 0.f;
#pragma unroll
  for (int q = 0; q < NV; ++q) s += v[q];
#pragma unroll
  for (int o = 32; o > 0; o >>= 1) s += __shfl_xor(s, o, 64);
  float mean = s * (1.0f / C);
  float sq = 0.f;
#pragma unroll
  for (int q = 0; q < NV; ++q) {
    float d = v[q] - mean;
    sq += d * d;
  }
#pragma unroll
  for (int o = 32; o > 0; o >>= 1) sq += __shfl_xor(sq, o, 64);
  float rstd = rsqrtf(sq * (1.0f / C) + EPSV);
#pragma unroll
  for (int q = 0; q < NV; ++q) {
    int c = lane * NV + q;
    float o = (v[q] - mean) * rstd * w[c] + bb[c];
    ushort h = f2bf(o);
    outH[(size_t)row * C + c] = h;
    outL[(size_t)row * C + c] = f2bf(o - bf2f(h));
  }
}

// ---------------------------------------------------------------------------
// Patch merge gather + LN -> hi/lo planes.
// ---------------------------------------------------------------------------
template <int MODE>
__global__ __launch_bounds__(256) void merge_ln_kernel(
    const float* __restrict__ Xin, const float* __restrict__ nw,
    const float* __restrict__ nb, ushort* __restrict__ outH,
    ushort* __restrict__ outL) {
  constexpr int CM = MODE ? 1024 : 512;
  constexpr int NE = CM / 256;
  int ot = blockIdx.x;
  int tid = threadIdx.x;
  __shared__ float redA[4];
  __shared__ float redB[4];

  float v[NE];
#pragma unroll
  for (int e = 0; e < NE; ++e) {
    int cp = tid + e * 256;
    if (MODE == 0) {
      int b = ot >> 10, r = ot & 1023;
      int n = r >> 2, di = (r >> 1) & 1, dj = r & 1;
      int q = cp >> 7, c = cp & 127;
      int i = 2 * di + (q & 1), j = 2 * dj + (q >> 1);
      v[e] = Xin[((b * 256 + n) * 16 + i * 4 + j) * 128 + c];
    } else {
      int b = ot >> 8, n = ot & 255;
      int q = cp >> 8, c = cp & 255;
      int di = q & 1, dj = q >> 1;
      v[e] = Xin[((b * 256 + n) * 4 + di * 2 + dj) * 256 + c];
    }
  }
  float s = 0.f;
#pragma unroll
  for (int e = 0; e < NE; ++e) s += v[e];
#pragma unroll
  for (int o = 32; o > 0; o >>= 1) s += __shfl_xor(s, o, 64);
  if ((tid & 63) == 0) redA[tid >> 6] = s;
  __syncthreads();
  float mean = (redA[0] + redA[1] + redA[2] + redA[3]) * (1.0f / CM);
  float sq = 0.f;
#pragma unroll
  for (int e = 0; e < NE; ++e) {
    float d = v[e] - mean;
    sq += d * d;
  }
#pragma unroll
  for (int o = 32; o > 0; o >>= 1) sq += __shfl_xor(sq, o, 64);
  if ((tid & 63) == 0) redB[tid >> 6] = sq;
  __syncthreads();
  float var = (redB[0] + redB[1] + redB[2] + redB[3]) * (1.0f / CM);
  float rstd = rsqrtf(var + EPSV);
#pragma unroll
  for (int e = 0; e < NE; ++e) {
    int cp = tid + e * 256;
    float o = (v[e] - mean) * rstd * nw[cp] + nb[cp];
    ushort h = f2bf(o);
    outH[(size_t)ot * CM + cp] = h;
    outL[(size_t)ot * CM + cp] = f2bf(o - bf2f(h));
  }
}

// ---------------------------------------------------------------------------
// Pure-bf16 MFMA GEMM over preconverted hi/lo planes (unchanged from r6).
// ---------------------------------------------------------------------------
template <int EP>
__global__ __launch_bounds__(256) void mgemm2_kernel(
    const ushort* __restrict__ Ah, const ushort* __restrict__ Al,
    const ushort* __restrict__ Wh, const ushort* __restrict__ Wl,
    const float* __restrict__ bias, const float* __restrict__ extra,
    float* __restrict__ outF, ushort* __restrict__ outH,
    ushort* __restrict__ outL, int M, int N, int K) {
  __shared__ __align__(16) ushort Lds[16384];
  int nb = N >> 7;
  int bx = blockIdx.x % nb, by = blockIdx.x / nb;
  int tid = threadIdx.x;
  int r0 = tid >> 2;
  int cc = (tid & 3) << 3;
  const ushort* aS0 = Ah + (size_t)(by * 128 + r0) * K + cc;
  const ushort* aS1 = aS0 + (size_t)64 * K;
  const ushort* lS0 = Al + (size_t)(by * 128 + r0) * K + cc;
  const ushort* lS1 = lS0 + (size_t)64 * K;
  const ushort* wS0 = Wh + (size_t)(bx * 128 + r0) * K + cc;
  const ushort* wS1 = wS0 + (size_t)64 * K;
  const ushort* vS0 = Wl + (size_t)(bx * 128 + r0) * K + cc;
  const ushort* vS1 = vS0 + (size_t)64 * K;
  int wv = tid >> 6;
  ushort* dA0 = Lds + wv * 512;
  ushort* dA1 = Lds + 2048 + wv * 512;
  ushort* dL0 = Lds + 4096 + wv * 512;
  ushort* dL1 = Lds + 6144 + wv * 512;
  ushort* dW0 = Lds + 8192 + wv * 512;
  ushort* dW1 = Lds + 10240 + wv * 512;
  ushort* dV0 = Lds + 12288 + wv * 512;
  ushort* dV1 = Lds + 14336 + wv * 512;

  int lane = tid & 63;
  int wm = (wv >> 1) * 64, wn = (wv & 1) * 64;
  int fr = lane & 15, fq = lane >> 4;
  const ushort* raA = Lds + (wm + fr) * 32 + fq * 8;
  const ushort* raW = Lds + 8192 + (wn + fr) * 32 + fq * 8;

  f32x4 acc[4][4];
#pragma unroll
  for (int i = 0; i < 4; ++i)
#pragma unroll
    for (int j = 0; j < 4; ++j) acc[i][j] = {0.f, 0.f, 0.f, 0.f};

  for (int k0 = 0; k0 < K; k0 += 32) {
    GLOAD16(dA0, aS0 + k0);
    GLOAD16(dA1, aS1 + k0);
    GLOAD16(dL0, lS0 + k0);
    GLOAD16(dL1, lS1 + k0);
    GLOAD16(dW0, wS0 + k0);
    GLOAD16(dW1, wS1 + k0);
    GLOAD16(dV0, vS0 + k0);
    GLOAD16(dV1, vS1 + k0);
    __syncthreads();

    bf16x8 fa[4], fl[4], fb[4], fv[4];
#pragma unroll
    for (int i = 0; i < 4; ++i) {
      fa[i] = *(const bf16x8*)(raA + i * 512);
      fl[i] = *(const bf16x8*)(raA + 4096 + i * 512);
      fb[i] = *(const bf16x8*)(raW + i * 512);
      fv[i] = *(const bf16x8*)(raW + 4096 + i * 512);
    }
#pragma unroll
    for (int i = 0; i < 4; ++i)
#pragma unroll
      for (int j = 0; j < 4; ++j) {
        acc[i][j] = __builtin_amdgcn_mfma_f32_16x16x32_bf16(fa[i], fb[j],
                                                            acc[i][j], 0, 0, 0);
        acc[i][j] = __builtin_amdgcn_mfma_f32_16x16x32_bf16(fl[i], fb[j],
                                                            acc[i][j], 0, 0, 0);
        acc[i][j] = __builtin_amdgcn_mfma_f32_16x16x32_bf16(fa[i], fv[j],
                                                            acc[i][j], 0, 0, 0);
      }
    __syncthreads();
  }

  int row0 = by * 128 + wm;
  int col0 = bx * 128 + wn;
#pragma unroll
  for (int j = 0; j < 4; ++j) {
    int col = col0 + j * 16 + fr;
    float bvv = bias ? bias[col] : 0.f;
#pragma unroll
    for (int i = 0; i < 4; ++i) {
#pragma unroll
      for (int e = 0; e < 4; ++e) {
        int row = row0 + i * 16 + fq * 4 + e;
        float o = acc[i][j][e] + bvv;
        if (EP == 1) {
          o += extra[(row & 255) * N + col];
          outF[(size_t)row * N + col] = o;
        } else if (EP == 2) {
          o += extra[(size_t)row * N + col];
          outF[(size_t)row * N + col] = o;
        } else if (EP == 3) {
          o = 0.5f * o * (1.0f + erff(o * 0.70710678118654752f));
          ushort h = f2bf(o);
          outH[(size_t)row * N + col] = h;
          outL[(size_t)row * N + col] = f2bf(o - bf2f(h));
        } else {
          outF[(size_t)row * N + col] = o;
        }
      }
    }
  }
}

// ---------------------------------------------------------------------------
// K transpose: qkv K-part -> kT[b*8+h][d][m] (coalesced both sides via LDS).
// Grid: (b*8+h)*4 + mchunk, 256 threads.
// ---------------------------------------------------------------------------
__global__ __launch_bounds__(256) void ktrans_kernel(
    const float* __restrict__ qkv, float* __restrict__ kT) {
  int bid = blockIdx.x;
  int mc = bid & 3, bh = bid >> 2;
  int b = bh >> 3, h = bh & 7;
  int tid = threadIdx.x;
  __shared__ float tile[64][68];
  int mi = tid >> 2, sg = (tid & 3) * 16;
  const float* src =
      qkv + ((size_t)(b * 256 + mc * 64 + mi)) * 1536 + 512 + h * 64 + sg;
#pragma unroll
  for (int e = 0; e < 4; ++e)
    *(float4*)&tile[mi][sg + e * 4] = ((const float4*)src)[e];
  __syncthreads();
  int dd = tid >> 2;
  float* dst = kT + (size_t)bh * 16384 + dd * 256 + mc * 64 + sg;
  float o[16];
#pragma unroll
  for (int q = 0; q < 16; ++q) o[q] = tile[sg + q][dd];
#pragma unroll
  for (int e = 0; e < 4; ++e) *(float4*)(dst + e * 4) = *(float4*)&o[e * 4];
}

// ---------------------------------------------------------------------------
// Attention scores + softmax v2. Block = (b,h, 32 q-rows), 256 thr (4 waves).
// lane = m (coalesced kT/rpe); wave handles 8 q-rows; softmax via shfl_xor.
// ---------------------------------------------------------------------------
__global__ __launch_bounds__(256) void attn_score_kernel(
    const float* __restrict__ qkv, const float* __restrict__ kT,
    const float* __restrict__ rpb, const int* __restrict__ rpe,
    float* __restrict__ P) {
  int bid = blockIdx.x;
  int nb = bid & 7, bh = bid >> 3;
  int b = bh >> 3, h = bh & 7;
  int n0 = nb * 32;
  int tid = threadIdx.x;
  int wv = tid >> 6, lane = tid & 63;
  __shared__ float qs[32][68];
  __shared__ float kts[64][68];
  {
    int r = tid >> 3, seg = (tid & 7) * 8;
    const float* src =
        qkv + ((size_t)(b * 256 + n0 + r)) * 1536 + h * 64 + seg;
    float4 a0 = ((const float4*)src)[0];
    float4 a1 = ((const float4*)src)[1];
    float4 s0 = {a0.x * 0.125f, a0.y * 0.125f, a0.z * 0.125f, a0.w * 0.125f};
    float4 s1 = {a1.x * 0.125f, a1.y * 0.125f, a1.z * 0.125f, a1.w * 0.125f};
    *(float4*)&qs[r][seg] = s0;
    *(float4*)&qs[r][seg + 4] = s1;
  }
  float sreg[8][4];
#pragma unroll 1
  for (int c = 0; c < 4; ++c) {
    __syncthreads();
    {
      int dd = tid >> 2, sg = (tid & 3) * 16;
      const float* ksrc = kT + (size_t)bh * 16384 + dd * 256 + c * 64 + sg;
#pragma unroll
      for (int e = 0; e < 4; ++e)
        *(float4*)&kts[dd][sg + e * 4] = ((const float4*)ksrc)[e];
    }
    __syncthreads();
    float acc[8];
#pragma unroll
    for (int nn = 0; nn < 8; ++nn) acc[nn] = 0.f;
#pragma unroll 4
    for (int d0 = 0; d0 < 64; d0 += 4) {
      float kv0 = kts[d0 + 0][lane];
      float kv1 = kts[d0 + 1][lane];
      float kv2 = kts[d0 + 2][lane];
      float kv3 = kts[d0 + 3][lane];
#pragma unroll
      for (int nn = 0; nn < 8; ++nn) {
        float4 q4 = *(const float4*)&qs[wv * 8 + nn][d0];
        acc[nn] += q4.x * kv0 + q4.y * kv1 + q4.z * kv2 + q4.w * kv3;
      }
    }
#pragma unroll
    for (int nn = 0; nn < 8; ++nn) {
      int n = n0 + wv * 8 + nn;
      int idx = rpe[n * 256 + c * 64 + lane];
      sreg[nn][c] = acc[nn] + rpb[idx * 8 + h];
    }
  }
  // softmax over m (4 chunk values x 64 lanes) per row
#pragma unroll
  for (int nn = 0; nn < 8; ++nn) {
    int n = n0 + wv * 8 + nn;
    float mx = fmaxf(fmaxf(sreg[nn][0], sreg[nn][1]),
                     fmaxf(sreg[nn][2], sreg[nn][3]));
#pragma unroll
    for (int o = 32; o > 0; o >>= 1) mx = fmaxf(mx, __shfl_xor(mx, o, 64));
    float sum = 0.f;
#pragma unroll
    for (int c = 0; c < 4; ++c) {
      sreg[nn][c] = expf(sreg[nn][c] - mx);
      sum += sreg[nn][c];
    }
#pragma unroll
    for (int o = 32; o > 0; o >>= 1) sum += __shfl_xor(sum, o, 64);
    float inv = 1.0f / sum;
    float* Pr = P + ((size_t)bh * 256 + n) * 256;
#pragma unroll
    for (int c = 0; c < 4; ++c) Pr[c * 64 + lane] = sreg[nn][c] * inv;
  }
}

// ---------------------------------------------------------------------------
// O = P @ V -> hi/lo planes. Block per (b,h,64-q tile); V staged as float4
// rows ([m][d4], b128 LDS reads); thread = (d4, 4 queries), V regs reused.
// ---------------------------------------------------------------------------
__global__ __launch_bounds__(256) void attn_pv_kernel(
    const float* __restrict__ P, const float* __restrict__ qkv,
    ushort* __restrict__ outH, ushort* __restrict__ outL) {
  int bid = blockIdx.x;  // b*32 + h*4 + nt
  int nt = bid & 3, h = (bid >> 2) & 7, b = bid >> 5;
  int tid = threadIdx.x;
  __shared__ float4 Vs4[256 * 16];
  for (int idx = tid; idx < 4096; idx += 256) {
    int m = idx >> 4, d4 = idx & 15;
    Vs4[m * 16 + d4] = *(const float4*)(
        qkv + ((size_t)(b * 256 + m)) * 1536 + 1024 + h * 64 + d4 * 4);
  }
  __syncthreads();

  int d4 = tid & 15, ng = tid >> 4;
  int nbase = nt * 64 + ng * 4;
  const float* P0 = P + ((size_t)((b * 8 + h) * 256 + nbase)) * 256;
  float4 a0 = {0, 0, 0, 0}, a1 = a0, a2 = a0, a3 = a0;
#pragma unroll 2
  for (int m4 = 0; m4 < 64; ++m4) {
    float4 v0 = Vs4[(m4 * 4 + 0) * 16 + d4];
    float4 v1 = Vs4[(m4 * 4 + 1) * 16 + d4];
    float4 v2 = Vs4[(m4 * 4 + 2) * 16 + d4];
    float4 v3 = Vs4[(m4 * 4 + 3) * 16 + d4];
    float4 p;
#define PVACC(A, ROW)                                              \
  p = ((const float4*)(P0 + (ROW)*256))[m4];                       \
  A.x += p.x * v0.x + p.y * v1.x + p.z * v2.x + p.w * v3.x;        \
  A.y += p.x * v0.y + p.y * v1.y + p.z * v2.y + p.w * v3.y;        \
  A.z += p.x * v0.z + p.y * v1.z + p.z * v2.z + p.w * v3.z;        \
  A.w += p.x * v0.w + p.y * v1.w + p.z * v2.w + p.w * v3.w;
    PVACC(a0, 0)
    PVACC(a1, 1)
    PVACC(a2, 2)
    PVACC(a3, 3)
#undef PVACC
  }
  float4 accs[4] = {a0, a1, a2, a3};
#pragma unroll
  for (int i = 0; i < 4; ++i) {
    int n = nbase + i;
    size_t oidx = ((size_t)(b * 256 + n)) * 512 + h * 64 + d4 * 4;
    float vv[4] = {accs[i].x, accs[i].y, accs[i].z, accs[i].w};
    unsigned hw[4], lw[4];
#pragma unroll
    for (int e = 0; e < 4; ++e) {
      ushort hh = f2bf(vv[e]);
      hw[e] = hh;
      lw[e] = f2bf(vv[e] - bf2f(hh));
    }
    *(uint2*)(outH + oidx) =
        make_uint2(hw[0] | (hw[1] << 16), hw[2] | (hw[3] << 16));
    *(uint2*)(outL + oidx) =
        make_uint2(lw[0] | (lw[1] << 16), lw[2] | (lw[3] << 16));
  }
}

// ---------------------------------------------------------------------------
// LayerNorm over 512, wave per row, 4 rows/block. HL=0 f32, HL=1 hi/lo.
// ---------------------------------------------------------------------------
template <int HL>
__global__ __launch_bounds__(256) void ln512_kernel(
    const float* __restrict__ X, const float* __restrict__ w,
    const float* __restrict__ bb, float* __restrict__ outF,
    ushort* __restrict__ outH, ushort* __restrict__ outL) {
  int row = blockIdx.x * 4 + (threadIdx.x >> 6);
  int t = threadIdx.x & 63;
  const float4* xr = (const float4*)(X + (size_t)row * 512);
  float4 v0 = xr[t * 2], v1 = xr[t * 2 + 1];
  float s = v0.x + v0.y + v0.z + v0.w + v1.x + v1.y + v1.z + v1.w;
#pragma unroll
  for (int o = 32; o > 0; o >>= 1) s += __shfl_xor(s, o, 64);
  float mean = s * (1.0f / 512.0f);
  float dv[8] = {v0.x - mean, v0.y - mean, v0.z - mean, v0.w - mean,
                 v1.x - mean, v1.y - mean, v1.z - mean, v1.w - mean};
  float sq = 0.f;
#pragma unroll
  for (int e = 0; e < 8; ++e) sq += dv[e] * dv[e];
#pragma unroll
  for (int o = 32; o > 0; o >>= 1) sq += __shfl_xor(sq, o, 64);
  float rstd = rsqrtf(sq * (1.0f / 512.0f) + EPSV);
  int c = t * 8;
  float ov[8];
#pragma unroll
  for (int e = 0; e < 8; ++e) ov[e] = dv[e] * rstd * w[c + e] + bb[c + e];
  if (HL == 0) {
    float4 o0 = {ov[0], ov[1], ov[2], ov[3]};
    float4 o1 = {ov[4], ov[5], ov[6], ov[7]};
    ((float4*)(outF + (size_t)row * 512))[t * 2] = o0;
    ((float4*)(outF + (size_t)row * 512))[t * 2 + 1] = o1;
  } else {
    __align__(16) ushort h8[8], l8[8];
#pragma unroll
    for (int e = 0; e < 8; ++e) {
      h8[e] = f2bf(ov[e]);
      l8[e] = f2bf(ov[e] - bf2f(h8[e]));
    }
    *(bf16x8*)(outH + (size_t)row * 512 + c) = *(bf16x8*)h8;
    *(bf16x8*)(outL + (size_t)row * 512 + c) = *(bf16x8*)l8;
  }
}

// ---------------------------------------------------------------------------
extern "C" void kernel_launch(void* const* d_in, const int* in_sizes, int n_in,
                              void* d_out, int out_size, void* d_ws,
                              size_t ws_size, hipStream_t stream) {
  const float* x = (const float*)d_in[0];
  const float* patch_w = (const float*)d_in[1];
  const float* patch_b = (const float*)d_in[2];
  const float* pnorm_w = (const float*)d_in[3];
  const float* pnorm_b = (const float*)d_in[4];
  const float* s0_n2w = (const float*)d_in[5];
  const float* s0_n2b = (const float*)d_in[6];
  const float* s0_f1w = (const float*)d_in[7];
  const float* s0_f1b = (const float*)d_in[8];
  const float* s0_f2w = (const float*)d_in[9];
  const float* s0_f2b = (const float*)d_in[10];
  const float* m0_nw = (const float*)d_in[11];
  const float* m0_nb = (const float*)d_in[12];
  const float* m0_rw = (const float*)d_in[13];
  const float* s1_n2w = (const float*)d_in[14];
  const float* s1_n2b = (const float*)d_in[15];
  const float* s1_f1w = (const float*)d_in[16];
  const float* s1_f1b = (const float*)d_in[17];
  const float* s1_f2w = (const float*)d_in[18];
  const float* s1_f2b = (const float*)d_in[19];
  const float* m1_nw = (const float*)d_in[20];
  const float* m1_nb = (const float*)d_in[21];
  const float* m1_rw = (const float*)d_in[22];
  const float* pos_embed = (const float*)d_in[23];
  const float* mb_n1w = (const float*)d_in[24];
  const float* mb_n1b = (const float*)d_in[25];
  const float* mb_qkvw = (const float*)d_in[26];
  const float* mb_qkvb = (const float*)d_in[27];
  const float* mb_rpb = (const float*)d_in[28];
  const float* mb_projw = (const float*)d_in[29];
  const float* mb_projb = (const float*)d_in[30];
  const float* mb_n2w = (const float*)d_in[31];
  const float* mb_n2b = (const float*)d_in[32];
  const float* mb_f1w = (const float*)d_in[33];
  const float* mb_f1b = (const float*)d_in[34];
  const float* mb_f2w = (const float*)d_in[35];
  const float* mb_f2b = (const float*)d_in[36];
  const float* fnorm_w = (const float*)d_in[37];
  const float* fnorm_b = (const float*)d_in[38];
  const int* rpe = (const int*)d_in[39];

  // Workspace: 27,262,976 floats = 109.1 MB (same as round 6)
  float* Xa = (float*)d_ws;                     // 8,388,608 f
  ushort* R1h = (ushort*)(Xa + 8388608);        // 2,097,152 sh
  ushort* R1l = R1h + 2097152;                  // 2,097,152 sh
  float* Kt = (float*)R1h;                      // 2,097,152 f (aliases R1h/R1l)
  float* R2f = (float*)(R1l + 2097152);         // 8,388,608 f
  ushort* R2h = (ushort*)R2f;
  ushort* R2l = R2h + 8388608;
  float* Qkv = R2f + 8388608;                   // 6,291,456 f
  ushort* W1h = (ushort*)(Qkv + 6291456);       // 1,048,576 sh
  ushort* W1l = W1h + 1048576;
  ushort* W2h = W1l + 1048576;
  ushort* W2l = W2h + 1048576;

#define CONV(src, cnt, dh, dl)                                            \
  convhl_kernel<<<((cnt) / 4 + 255) / 256, 256, 0, stream>>>(src, dh, dl, \
                                                             (cnt) / 4)

  // Patch embed + pnorm LN -> Xa [65536,128]
  patch_ln_kernel<<<65536, 128, 0, stream>>>(x, patch_w, patch_b, pnorm_w,
                                             pnorm_b, Xa);

  // Stem stage 0: 8 MLP blocks, dim 128, hidden 384 (token-chunked x4)
  for (int i = 0; i < 8; ++i) {
    CONV(s0_f1w + i * 49152, 49152, W1h, W1l);
    CONV(s0_f2w + i * 49152, 49152, W2h, W2l);
    for (int c = 0; c < 4; ++c) {
      float* Xc = Xa + (size_t)c * 16384 * 128;
      lnC_kernel<128><<<16384 / 4, 256, 0, stream>>>(Xc, s0_n2w + i * 128,
                                                     s0_n2b + i * 128, R1h, R1l);
      mgemm2_kernel<3><<<(16384 / 128) * (384 / 128), 256, 0, stream>>>(
          R1h, R1l, W1h, W1l, s0_f1b + i * 384, nullptr, nullptr, R2h, R2l,
          16384, 384, 128);
      mgemm2_kernel<2><<<(16384 / 128) * (128 / 128), 256, 0, stream>>>(
          R2h, R2l, W2h, W2l, s0_f2b + i * 128, Xc, Xc, nullptr, nullptr,
          16384, 128, 384);
    }
  }
  // Merge 0 -> R2 planes [16384,512] -> GEMM -> Xa [16384,256]
  merge_ln_kernel<0><<<16384, 256, 0, stream>>>(Xa, m0_nw, m0_nb, R2h, R2l);
  CONV(m0_rw, 131072, W1h, W1l);
  mgemm2_kernel<0><<<(16384 / 128) * (256 / 128), 256, 0, stream>>>(
      R2h, R2l, W1h, W1l, nullptr, nullptr, Xa, nullptr, nullptr, 16384, 256,
      512);

  // Stem stage 1: 8 MLP blocks, dim 256, hidden 768 (token-chunked x2)
  for (int i = 0; i < 8; ++i) {
    CONV(s1_f1w + i * 196608, 196608, W1h, W1l);
    CONV(s1_f2w + i * 196608, 196608, W2h, W2l);
    for (int c = 0; c < 2; ++c) {
      float* Xc = Xa + (size_t)c * 8192 * 256;
      lnC_kernel<256><<<8192 / 4, 256, 0, stream>>>(Xc, s1_n2w + i * 256,
                                                    s1_n2b + i * 256, R1h, R1l);
      mgemm2_kernel<3><<<(8192 / 128) * (768 / 128), 256, 0, stream>>>(
          R1h, R1l, W1h, W1l, s1_f1b + i * 768, nullptr, nullptr, R2h, R2l,
          8192, 768, 256);
      mgemm2_kernel<2><<<(8192 / 128) * (256 / 128), 256, 0, stream>>>(
          R2h, R2l, W2h, W2l, s1_f2b + i * 256, Xc, Xc, nullptr, nullptr, 8192,
          256, 768);
    }
  }
  // Merge 1 -> R2 planes [4096,1024] -> GEMM + pos -> Xa [4096,512]
  merge_ln_kernel<1><<<4096, 256, 0, stream>>>(Xa, m1_nw, m1_nb, R2h, R2l);
  CONV(m1_rw, 524288, W1h, W1l);
  mgemm2_kernel<1><<<(4096 / 128) * (512 / 128), 256, 0, stream>>>(
      R2h, R2l, W1h, W1l, nullptr, pos_embed, Xa, nullptr, nullptr, 4096, 512,
      1024);

  // 20 main attention blocks
  for (int l = 0; l < 20; ++l) {
    ln512_kernel<1><<<1024, 256, 0, stream>>>(Xa, mb_n1w + l * 512,
                                              mb_n1b + l * 512, nullptr, R1h,
                                              R1l);
    CONV(mb_qkvw + l * 786432, 786432, W1h, W1l);
    mgemm2_kernel<0><<<(4096 / 128) * (1536 / 128), 256, 0, stream>>>(
        R1h, R1l, W1h, W1l, mb_qkvb + l * 1536, nullptr, Qkv, nullptr, nullptr,
        4096, 1536, 512);
    ktrans_kernel<<<512, 256, 0, stream>>>(Qkv, Kt);
    attn_score_kernel<<<1024, 256, 0, stream>>>(Qkv, Kt, mb_rpb + l * 7688,
                                                rpe, R2f);
    attn_pv_kernel<<<512, 256, 0, stream>>>(R2f, Qkv, R1h, R1l);
    CONV(mb_projw + l * 262144, 262144, W1h, W1l);
    mgemm2_kernel<2><<<(4096 / 128) * (512 / 128), 256, 0, stream>>>(
        R1h, R1l, W1h, W1l, mb_projb + l * 512, Xa, Xa, nullptr, nullptr, 4096,
        512, 512);
    ln512_kernel<1><<<1024, 256, 0, stream>>>(Xa, mb_n2w + l * 512,
                                              mb_n2b + l * 512, nullptr, R1h,
                                              R1l);
    CONV(mb_f1w + l * 1048576, 1048576, W1h, W1l);
    CONV(mb_f2w + l * 1048576, 1048576, W2h, W2l);
    mgemm2_kernel<3><<<(4096 / 128) * (2048 / 128), 256, 0, stream>>>(
        R1h, R1l, W1h, W1l, mb_f1b + l * 2048, nullptr, nullptr, R2h, R2l,
        4096, 2048, 512);
    mgemm2_kernel<2><<<(4096 / 128) * (512 / 128), 256, 0, stream>>>(
        R2h, R2l, W2h, W2l, mb_f2b + l * 512, Xa, Xa, nullptr, nullptr, 4096,
        512, 2048);
  }
  // Final LN -> d_out (f32)
  ln512_kernel<0><<<1024, 256, 0, stream>>>(Xa, fnorm_w, fnorm_b,
                                            (float*)d_out, nullptr, nullptr);
}

// Round 8
// 7711.353 us; speedup vs baseline: 10.0694x; 1.0991x over previous
//
#include <hip/hip_runtime.h>
#include <math.h>

#define EPSV 1e-5f

typedef __attribute__((ext_vector_type(8))) short bf16x8;
typedef __attribute__((ext_vector_type(4))) float f32x4;
typedef unsigned short ushort;

__device__ inline ushort f2bf(float x) {
  unsigned u = __builtin_bit_cast(unsigned, x);
  u += 0x7FFFu + ((u >> 16) & 1u);
  return (ushort)(u >> 16);
}
__device__ inline float bf2f(ushort h) {
  unsigned u = ((unsigned)h) << 16;
  return __builtin_bit_cast(float, u);
}

// async global->LDS, 16 bytes per lane; dest = wave-uniform base + lane*16
#define GLOAD16(lptr, gptr)                                              \
  __builtin_amdgcn_global_load_lds(                                      \
      (const __attribute__((address_space(1))) unsigned int*)(gptr),     \
      (__attribute__((address_space(3))) unsigned int*)(lptr), 16, 0, 0)

// ---------------------------------------------------------------------------
// f32 -> (hi,lo) bf16 plane conversion (weights). n4 = count/4.
// ---------------------------------------------------------------------------
__global__ __launch_bounds__(256) void convhl_kernel(
    const float* __restrict__ in, ushort* __restrict__ hi,
    ushort* __restrict__ lo, int n4) {
  int i = blockIdx.x * 256 + threadIdx.x;
  if (i >= n4) return;
  float4 v = ((const float4*)in)[i];
  float vv[4] = {v.x, v.y, v.z, v.w};
  unsigned hw[4], lw[4];
#pragma unroll
  for (int e = 0; e < 4; ++e) {
    ushort h = f2bf(vv[e]);
    hw[e] = h;
    lw[e] = f2bf(vv[e] - bf2f(h));
  }
  ((uint2*)hi)[i] = make_uint2(hw[0] | (hw[1] << 16), hw[2] | (hw[3] << 16));
  ((uint2*)lo)[i] = make_uint2(lw[0] | (lw[1] << 16), lw[2] | (lw[3] << 16));
}

// ---------------------------------------------------------------------------
// Patch embed (4x4/4 conv) + pnorm LN, fused. Writes f32 residual state.
// ---------------------------------------------------------------------------
__global__ __launch_bounds__(128) void patch_ln_kernel(
    const float* __restrict__ x, const float* __restrict__ pw,
    const float* __restrict__ pbias, const float* __restrict__ nw,
    const float* __restrict__ nb, float* __restrict__ out) {
  int tk = blockIdx.x;
  int t = threadIdx.x;
  int b = tk >> 12;
  int n = (tk >> 4) & 255;
  int ii = (tk >> 2) & 3;
  int jj = tk & 3;
  int Y = ((n >> 4) << 2) + ii;
  int X = ((n & 15) << 2) + jj;

  __shared__ float px[48];
  __shared__ float redA[2];
  __shared__ float redB[2];
  if (t < 48) {
    int ci = t >> 4, dy = (t >> 2) & 3, dx = t & 3;
    px[t] = x[((b * 3 + ci) * 256 + (Y * 4 + dy)) * 256 + (X * 4 + dx)];
  }
  __syncthreads();

  float acc = pbias[t];
  const float* wr = pw + t * 48;
#pragma unroll
  for (int q = 0; q < 48; ++q) acc += wr[q] * px[q];

  float s = acc;
#pragma unroll
  for (int o = 32; o > 0; o >>= 1) s += __shfl_xor(s, o, 64);
  if ((t & 63) == 0) redA[t >> 6] = s;
  __syncthreads();
  float mean = (redA[0] + redA[1]) * (1.0f / 128.0f);
  float d = acc - mean;
  float sq = d * d;
#pragma unroll
  for (int o = 32; o > 0; o >>= 1) sq += __shfl_xor(sq, o, 64);
  if ((t & 63) == 0) redB[t >> 6] = sq;
  __syncthreads();
  float var = (redB[0] + redB[1]) * (1.0f / 128.0f);
  out[tk * 128 + t] = d * rsqrtf(var + EPSV) * nw[t] + nb[t];
}

// ---------------------------------------------------------------------------
// LayerNorm over C (128/256), one wave per row, 4 rows/block -> hi/lo planes.
// ---------------------------------------------------------------------------
template <int C>
__global__ __launch_bounds__(256) void lnC_kernel(
    const float* __restrict__ X, const float* __restrict__ w,
    const float* __restrict__ bb, ushort* __restrict__ outH,
    ushort* __restrict__ outL) {
  constexpr int NV = C / 64;
  int wave = threadIdx.x >> 6, lane = threadIdx.x & 63;
  int row = blockIdx.x * 4 + wave;
  const float* xr = X + (size_t)row * C + lane * NV;
  float v[NV];
  if (NV == 2) {
    float2 t2 = *(const float2*)xr;
    v[0] = t2.x; v[1] = t2.y;
  } else {
#pragma unroll
    for (int q = 0; q < NV; q += 4) {
      float4 t4 = *(const float4*)(xr + q);
      v[q] = t4.x; v[q + 1] = t4.y; v[q + 2] = t4.z; v[q + 3] = t4.w;
    }
  }
  float s = 0.f;
#pragma unroll
  for (int q = 0; q < NV; ++q) s += v[q];
#pragma unroll
  for (int o = 32; o > 0; o >>= 1) s += __shfl_xor(s, o, 64);
  float mean = s * (1.0f / C);
  float sq = 0.f;
#pragma unroll
  for (int q = 0; q < NV; ++q) {
    float d = v[q] - mean;
    sq += d * d;
  }
#pragma unroll
  for (int o = 32; o > 0; o >>= 1) sq += __shfl_xor(sq, o, 64);
  float rstd = rsqrtf(sq * (1.0f / C) + EPSV);
#pragma unroll
  for (int q = 0; q < NV; ++q) {
    int c = lane * NV + q;
    float o = (v[q] - mean) * rstd * w[c] + bb[c];
    ushort h = f2bf(o);
    outH[(size_t)row * C + c] = h;
    outL[(size_t)row * C + c] = f2bf(o - bf2f(h));
  }
}

// ---------------------------------------------------------------------------
// Patch merge gather + LN -> hi/lo planes.
// ---------------------------------------------------------------------------
template <int MODE>
__global__ __launch_bounds__(256) void merge_ln_kernel(
    const float* __restrict__ Xin, const float* __restrict__ nw,
    const float* __restrict__ nb, ushort* __restrict__ outH,
    ushort* __restrict__ outL) {
  constexpr int CM = MODE ? 1024 : 512;
  constexpr int NE = CM / 256;
  int ot = blockIdx.x;
  int tid = threadIdx.x;
  __shared__ float redA[4];
  __shared__ float redB[4];

  float v[NE];
#pragma unroll
  for (int e = 0; e < NE; ++e) {
    int cp = tid + e * 256;
    if (MODE == 0) {
      int b = ot >> 10, r = ot & 1023;
      int n = r >> 2, di = (r >> 1) & 1, dj = r & 1;
      int q = cp >> 7, c = cp & 127;
      int i = 2 * di + (q & 1), j = 2 * dj + (q >> 1);
      v[e] = Xin[((b * 256 + n) * 16 + i * 4 + j) * 128 + c];
    } else {
      int b = ot >> 8, n = ot & 255;
      int q = cp >> 8, c = cp & 255;
      int di = q & 1, dj = q >> 1;
      v[e] = Xin[((b * 256 + n) * 4 + di * 2 + dj) * 256 + c];
    }
  }
  float s = 0.f;
#pragma unroll
  for (int e = 0; e < NE; ++e) s += v[e];
#pragma unroll
  for (int o = 32; o > 0; o >>= 1) s += __shfl_xor(s, o, 64);
  if ((tid & 63) == 0) redA[tid >> 6] = s;
  __syncthreads();
  float mean = (redA[0] + redA[1] + redA[2] + redA[3]) * (1.0f / CM);
  float sq = 0.f;
#pragma unroll
  for (int e = 0; e < NE; ++e) {
    float d = v[e] - mean;
    sq += d * d;
  }
#pragma unroll
  for (int o = 32; o > 0; o >>= 1) sq += __shfl_xor(sq, o, 64);
  if ((tid & 63) == 0) redB[tid >> 6] = sq;
  __syncthreads();
  float var = (redB[0] + redB[1] + redB[2] + redB[3]) * (1.0f / CM);
  float rstd = rsqrtf(var + EPSV);
#pragma unroll
  for (int e = 0; e < NE; ++e) {
    int cp = tid + e * 256;
    float o = (v[e] - mean) * rstd * nw[cp] + nb[cp];
    ushort h = f2bf(o);
    outH[(size_t)ot * CM + cp] = h;
    outL[(size_t)ot * CM + cp] = f2bf(o - bf2f(h));
  }
}

// ---------------------------------------------------------------------------
// Pure-bf16 MFMA GEMM over hi/lo planes. Tile BM x 128 (BM 64 or 128),
// BK=32, 256 thr (4 waves). BM=128: waves 2x2 of 64x64; BM=64: 2x2 of 32x64.
// ---------------------------------------------------------------------------
template <int EP, int BM>
__global__ __launch_bounds__(256) void mgemm2_kernel(
    const ushort* __restrict__ Ah, const ushort* __restrict__ Al,
    const ushort* __restrict__ Wh, const ushort* __restrict__ Wl,
    const float* __restrict__ bias, const float* __restrict__ extra,
    float* __restrict__ outF, ushort* __restrict__ outH,
    ushort* __restrict__ outL, int M, int N, int K) {
  constexpr int NI = BM / 32;           // row fragments per wave
  constexpr int APL = BM * 32;          // A plane size in shorts
  __shared__ __align__(16) ushort Lds[2 * APL + 8192];
  int nb = N >> 7;
  int bx = blockIdx.x % nb, by = blockIdx.x / nb;
  int tid = threadIdx.x;
  int r0 = tid >> 2;
  int cc = (tid & 3) << 3;
  const ushort* aS0 = Ah + (size_t)(by * BM + r0) * K + cc;
  const ushort* lS0 = Al + (size_t)(by * BM + r0) * K + cc;
  const ushort* wS0 = Wh + (size_t)(bx * 128 + r0) * K + cc;
  const ushort* wS1 = wS0 + (size_t)64 * K;
  const ushort* vS0 = Wl + (size_t)(bx * 128 + r0) * K + cc;
  const ushort* vS1 = vS0 + (size_t)64 * K;
  int wv = tid >> 6;
  ushort* dA0 = Lds + wv * 512;
  ushort* dL0 = Lds + APL + wv * 512;
  ushort* dW0 = Lds + 2 * APL + wv * 512;
  ushort* dW1 = Lds + 2 * APL + 2048 + wv * 512;
  ushort* dV0 = Lds + 2 * APL + 4096 + wv * 512;
  ushort* dV1 = Lds + 2 * APL + 6144 + wv * 512;

  int lane = tid & 63;
  int wm = (wv >> 1) * (BM / 2), wn = (wv & 1) * 64;
  int fr = lane & 15, fq = lane >> 4;
  const ushort* raA = Lds + (wm + fr) * 32 + fq * 8;
  const ushort* raW = Lds + 2 * APL + (wn + fr) * 32 + fq * 8;

  f32x4 acc[NI][4];
#pragma unroll
  for (int i = 0; i < NI; ++i)
#pragma unroll
    for (int j = 0; j < 4; ++j) acc[i][j] = {0.f, 0.f, 0.f, 0.f};

  for (int k0 = 0; k0 < K; k0 += 32) {
    GLOAD16(dA0, aS0 + k0);
    if (BM == 128) GLOAD16(dA0 + 2048, aS0 + (size_t)64 * K + k0);
    GLOAD16(dL0, lS0 + k0);
    if (BM == 128) GLOAD16(dL0 + 2048, lS0 + (size_t)64 * K + k0);
    GLOAD16(dW0, wS0 + k0);
    GLOAD16(dW1, wS1 + k0);
    GLOAD16(dV0, vS0 + k0);
    GLOAD16(dV1, vS1 + k0);
    __syncthreads();

    bf16x8 fa[NI], fl[NI], fb[4], fv[4];
#pragma unroll
    for (int i = 0; i < NI; ++i) {
      fa[i] = *(const bf16x8*)(raA + i * 512);
      fl[i] = *(const bf16x8*)(raA + APL + i * 512);
    }
#pragma unroll
    for (int j = 0; j < 4; ++j) {
      fb[j] = *(const bf16x8*)(raW + j * 512);
      fv[j] = *(const bf16x8*)(raW + 4096 + j * 512);
    }
#pragma unroll
    for (int i = 0; i < NI; ++i)
#pragma unroll
      for (int j = 0; j < 4; ++j) {
        acc[i][j] = __builtin_amdgcn_mfma_f32_16x16x32_bf16(fa[i], fb[j],
                                                            acc[i][j], 0, 0, 0);
        acc[i][j] = __builtin_amdgcn_mfma_f32_16x16x32_bf16(fl[i], fb[j],
                                                            acc[i][j], 0, 0, 0);
        acc[i][j] = __builtin_amdgcn_mfma_f32_16x16x32_bf16(fa[i], fv[j],
                                                            acc[i][j], 0, 0, 0);
      }
    __syncthreads();
  }

  int row0 = by * BM + wm;
  int col0 = bx * 128 + wn;
#pragma unroll
  for (int j = 0; j < 4; ++j) {
    int col = col0 + j * 16 + fr;
    float bvv = bias ? bias[col] : 0.f;
#pragma unroll
    for (int i = 0; i < NI; ++i) {
#pragma unroll
      for (int e = 0; e < 4; ++e) {
        int row = row0 + i * 16 + fq * 4 + e;
        float o = acc[i][j][e] + bvv;
        if (EP == 1) {
          o += extra[(row & 255) * N + col];
          outF[(size_t)row * N + col] = o;
        } else if (EP == 2) {
          o += extra[(size_t)row * N + col];
          outF[(size_t)row * N + col] = o;
        } else if (EP == 3) {
          o = 0.5f * o * (1.0f + erff(o * 0.70710678118654752f));
          ushort h = f2bf(o);
          outH[(size_t)row * N + col] = h;
          outL[(size_t)row * N + col] = f2bf(o - bf2f(h));
        } else {
          outF[(size_t)row * N + col] = o;
        }
      }
    }
  }
}

// ---------------------------------------------------------------------------
// Attention scores + softmax. Block = (b,h, 32 q-rows), 256 thr (4 waves).
// K transposed in-LDS from qkv directly (stride-65 pad => 2-way only).
// ---------------------------------------------------------------------------
__global__ __launch_bounds__(256) void attn_score_kernel(
    const float* __restrict__ qkv, const float* __restrict__ rpb,
    const int* __restrict__ rpe, float* __restrict__ P) {
  int bid = blockIdx.x;
  int nb = bid & 7, bh = bid >> 3;
  int b = bh >> 3, h = bh & 7;
  int n0 = nb * 32;
  int tid = threadIdx.x;
  int wv = tid >> 6, lane = tid & 63;
  __shared__ float qs[32][68];
  __shared__ float kts[64][65];
  {
    int r = tid >> 3, seg = (tid & 7) * 8;
    const float* src =
        qkv + ((size_t)(b * 256 + n0 + r)) * 1536 + h * 64 + seg;
    float4 a0 = ((const float4*)src)[0];
    float4 a1 = ((const float4*)src)[1];
    float4 s0 = {a0.x * 0.125f, a0.y * 0.125f, a0.z * 0.125f, a0.w * 0.125f};
    float4 s1 = {a1.x * 0.125f, a1.y * 0.125f, a1.z * 0.125f, a1.w * 0.125f};
    *(float4*)&qs[r][seg] = s0;
    *(float4*)&qs[r][seg + 4] = s1;
  }
  float sreg[8][4];
#pragma unroll 1
  for (int c = 0; c < 4; ++c) {
    __syncthreads();
    {
      // load K rows m = c*64 + mi, transpose into kts[d][m]
      int mi = tid >> 2, sg = (tid & 3) * 16;
      const float* ksrc =
          qkv + ((size_t)(b * 256 + c * 64 + mi)) * 1536 + 512 + h * 64 + sg;
#pragma unroll
      for (int e = 0; e < 4; ++e) {
        float4 k4 = ((const float4*)ksrc)[e];
        kts[sg + e * 4 + 0][mi] = k4.x;
        kts[sg + e * 4 + 1][mi] = k4.y;
        kts[sg + e * 4 + 2][mi] = k4.z;
        kts[sg + e * 4 + 3][mi] = k4.w;
      }
    }
    __syncthreads();
    float acc[8];
#pragma unroll
    for (int nn = 0; nn < 8; ++nn) acc[nn] = 0.f;
#pragma unroll 4
    for (int d0 = 0; d0 < 64; d0 += 4) {
      float kv0 = kts[d0 + 0][lane];
      float kv1 = kts[d0 + 1][lane];
      float kv2 = kts[d0 + 2][lane];
      float kv3 = kts[d0 + 3][lane];
#pragma unroll
      for (int nn = 0; nn < 8; ++nn) {
        float4 q4 = *(const float4*)&qs[wv * 8 + nn][d0];
        acc[nn] += q4.x * kv0 + q4.y * kv1 + q4.z * kv2 + q4.w * kv3;
      }
    }
#pragma unroll
    for (int nn = 0; nn < 8; ++nn) {
      int n = n0 + wv * 8 + nn;
      int idx = rpe[n * 256 + c * 64 + lane];
      sreg[nn][c] = acc[nn] + rpb[idx * 8 + h];
    }
  }
  // softmax over m per row
#pragma unroll
  for (int nn = 0; nn < 8; ++nn) {
    int n = n0 + wv * 8 + nn;
    float mx = fmaxf(fmaxf(sreg[nn][0], sreg[nn][1]),
                     fmaxf(sreg[nn][2], sreg[nn][3]));
#pragma unroll
    for (int o = 32; o > 0; o >>= 1) mx = fmaxf(mx, __shfl_xor(mx, o, 64));
    float sum = 0.f;
#pragma unroll
    for (int c = 0; c < 4; ++c) {
      sreg[nn][c] = expf(sreg[nn][c] - mx);
      sum += sreg[nn][c];
    }
#pragma unroll
    for (int o = 32; o > 0; o >>= 1) sum += __shfl_xor(sum, o, 64);
    float inv = 1.0f / sum;
    float* Pr = P + ((size_t)bh * 256 + n) * 256;
#pragma unroll
    for (int c = 0; c < 4; ++c) Pr[c * 64 + lane] = sreg[nn][c] * inv;
  }
}

// ---------------------------------------------------------------------------
// O = P @ V -> hi/lo planes. Block per (b,h,64-q tile); V as float4 rows.
// ---------------------------------------------------------------------------
__global__ __launch_bounds__(256) void attn_pv_kernel(
    const float* __restrict__ P, const float* __restrict__ qkv,
    ushort* __restrict__ outH, ushort* __restrict__ outL) {
  int bid = blockIdx.x;  // b*32 + h*4 + nt
  int nt = bid & 3, h = (bid >> 2) & 7, b = bid >> 5;
  int tid = threadIdx.x;
  __shared__ float4 Vs4[256 * 16];
  for (int idx = tid; idx < 4096; idx += 256) {
    int m = idx >> 4, d4 = idx & 15;
    Vs4[m * 16 + d4] = *(const float4*)(
        qkv + ((size_t)(b * 256 + m)) * 1536 + 1024 + h * 64 + d4 * 4);
  }
  __syncthreads();

  int d4 = tid & 15, ng = tid >> 4;
  int nbase = nt * 64 + ng * 4;
  const float* P0 = P + ((size_t)((b * 8 + h) * 256 + nbase)) * 256;
  float4 a0 = {0, 0, 0, 0}, a1 = a0, a2 = a0, a3 = a0;
#pragma unroll 2
  for (int m4 = 0; m4 < 64; ++m4) {
    float4 v0 = Vs4[(m4 * 4 + 0) * 16 + d4];
    float4 v1 = Vs4[(m4 * 4 + 1) * 16 + d4];
    float4 v2 = Vs4[(m4 * 4 + 2) * 16 + d4];
    float4 v3 = Vs4[(m4 * 4 + 3) * 16 + d4];
    float4 p;
#define PVACC(A, ROW)                                              \
  p = ((const float4*)(P0 + (ROW)*256))[m4];                       \
  A.x += p.x * v0.x + p.y * v1.x + p.z * v2.x + p.w * v3.x;        \
  A.y += p.x * v0.y + p.y * v1.y + p.z * v2.y + p.w * v3.y;        \
  A.z += p.x * v0.z + p.y * v1.z + p.z * v2.z + p.w * v3.z;        \
  A.w += p.x * v0.w + p.y * v1.w + p.z * v2.w + p.w * v3.w;
    PVACC(a0, 0)
    PVACC(a1, 1)
    PVACC(a2, 2)
    PVACC(a3, 3)
#undef PVACC
  }
  float4 accs[4] = {a0, a1, a2, a3};
#pragma unroll
  for (int i = 0; i < 4; ++i) {
    int n = nbase + i;
    size_t oidx = ((size_t)(b * 256 + n)) * 512 + h * 64 + d4 * 4;
    float vv[4] = {accs[i].x, accs[i].y, accs[i].z, accs[i].w};
    unsigned hw[4], lw[4];
#pragma unroll
    for (int e = 0; e < 4; ++e) {
      ushort hh = f2bf(vv[e]);
      hw[e] = hh;
      lw[e] = f2bf(vv[e] - bf2f(hh));
    }
    *(uint2*)(outH + oidx) =
        make_uint2(hw[0] | (hw[1] << 16), hw[2] | (hw[3] << 16));
    *(uint2*)(outL + oidx) =
        make_uint2(lw[0] | (lw[1] << 16), lw[2] | (lw[3] << 16));
  }
}

// ---------------------------------------------------------------------------
// LayerNorm over 512, wave per row, 4 rows/block. HL=0 f32, HL=1 hi/lo.
// ---------------------------------------------------------------------------
template <int HL>
__global__ __launch_bounds__(256) void ln512_kernel(
    const float* __restrict__ X, const float* __restrict__ w,
    const float* __restrict__ bb, float* __restrict__ outF,
    ushort* __restrict__ outH, ushort* __restrict__ outL) {
  int row = blockIdx.x * 4 + (threadIdx.x >> 6);
  int t = threadIdx.x & 63;
  const float4* xr = (const float4*)(X + (size_t)row * 512);
  float4 v0 = xr[t * 2], v1 = xr[t * 2 + 1];
  float s = v0.x + v0.y + v0.z + v0.w + v1.x + v1.y + v1.z + v1.w;
#pragma unroll
  for (int o = 32; o > 0; o >>= 1) s += __shfl_xor(s, o, 64);
  float mean = s * (1.0f / 512.0f);
  float dv[8] = {v0.x - mean, v0.y - mean, v0.z - mean, v0.w - mean,
                 v1.x - mean, v1.y - mean, v1.z - mean, v1.w - mean};
  float sq = 0.f;
#pragma unroll
  for (int e = 0; e < 8; ++e) sq += dv[e] * dv[e];
#pragma unroll
  for (int o = 32; o > 0; o >>= 1) sq += __shfl_xor(sq, o, 64);
  float rstd = rsqrtf(sq * (1.0f / 512.0f) + EPSV);
  int c = t * 8;
  float ov[8];
#pragma unroll
  for (int e = 0; e < 8; ++e) ov[e] = dv[e] * rstd * w[c + e] + bb[c + e];
  if (HL == 0) {
    float4 o0 = {ov[0], ov[1], ov[2], ov[3]};
    float4 o1 = {ov[4], ov[5], ov[6], ov[7]};
    ((float4*)(outF + (size_t)row * 512))[t * 2] = o0;
    ((float4*)(outF + (size_t)row * 512))[t * 2 + 1] = o1;
  } else {
    __align__(16) ushort h8[8], l8[8];
#pragma unroll
    for (int e = 0; e < 8; ++e) {
      h8[e] = f2bf(ov[e]);
      l8[e] = f2bf(ov[e] - bf2f(h8[e]));
    }
    *(bf16x8*)(outH + (size_t)row * 512 + c) = *(bf16x8*)h8;
    *(bf16x8*)(outL + (size_t)row * 512 + c) = *(bf16x8*)l8;
  }
}

// ---------------------------------------------------------------------------
extern "C" void kernel_launch(void* const* d_in, const int* in_sizes, int n_in,
                              void* d_out, int out_size, void* d_ws,
                              size_t ws_size, hipStream_t stream) {
  const float* x = (const float*)d_in[0];
  const float* patch_w = (const float*)d_in[1];
  const float* patch_b = (const float*)d_in[2];
  const float* pnorm_w = (const float*)d_in[3];
  const float* pnorm_b = (const float*)d_in[4];
  const float* s0_n2w = (const float*)d_in[5];
  const float* s0_n2b = (const float*)d_in[6];
  const float* s0_f1w = (const float*)d_in[7];
  const float* s0_f1b = (const float*)d_in[8];
  const float* s0_f2w = (const float*)d_in[9];
  const float* s0_f2b = (const float*)d_in[10];
  const float* m0_nw = (const float*)d_in[11];
  const float* m0_nb = (const float*)d_in[12];
  const float* m0_rw = (const float*)d_in[13];
  const float* s1_n2w = (const float*)d_in[14];
  const float* s1_n2b = (const float*)d_in[15];
  const float* s1_f1w = (const float*)d_in[16];
  const float* s1_f1b = (const float*)d_in[17];
  const float* s1_f2w = (const float*)d_in[18];
  const float* s1_f2b = (const float*)d_in[19];
  const float* m1_nw = (const float*)d_in[20];
  const float* m1_nb = (const float*)d_in[21];
  const float* m1_rw = (const float*)d_in[22];
  const float* pos_embed = (const float*)d_in[23];
  const float* mb_n1w = (const float*)d_in[24];
  const float* mb_n1b = (const float*)d_in[25];
  const float* mb_qkvw = (const float*)d_in[26];
  const float* mb_qkvb = (const float*)d_in[27];
  const float* mb_rpb = (const float*)d_in[28];
  const float* mb_projw = (const float*)d_in[29];
  const float* mb_projb = (const float*)d_in[30];
  const float* mb_n2w = (const float*)d_in[31];
  const float* mb_n2b = (const float*)d_in[32];
  const float* mb_f1w = (const float*)d_in[33];
  const float* mb_f1b = (const float*)d_in[34];
  const float* mb_f2w = (const float*)d_in[35];
  const float* mb_f2b = (const float*)d_in[36];
  const float* fnorm_w = (const float*)d_in[37];
  const float* fnorm_b = (const float*)d_in[38];
  const int* rpe = (const int*)d_in[39];

  // Workspace: 27,262,976 floats = 109.1 MB
  float* Xa = (float*)d_ws;                     // 8,388,608 f (residual)
  ushort* R1h = (ushort*)(Xa + 8388608);        // 2,097,152 sh
  ushort* R1l = R1h + 2097152;                  // 2,097,152 sh
  float* R2f = (float*)(R1l + 2097152);         // 8,388,608 f
  ushort* R2h = (ushort*)R2f;                   // 8,388,608 sh
  ushort* R2l = R2h + 8388608;                  // 8,388,608 sh
  float* Qkv = R2f + 8388608;                   // 6,291,456 f
  ushort* Hh = (ushort*)Qkv;                    // 6,291,456 sh (stem hidden)
  ushort* Hl = Hh + 6291456;                    // 6,291,456 sh
  ushort* W1h = (ushort*)(Qkv + 6291456);       // 1,048,576 sh
  ushort* W1l = W1h + 1048576;
  ushort* W2h = W1l + 1048576;
  ushort* W2l = W2h + 1048576;

#define CONV(src, cnt, dh, dl)                                            \
  convhl_kernel<<<((cnt) / 4 + 255) / 256, 256, 0, stream>>>(src, dh, dl, \
                                                             (cnt) / 4)

  // Patch embed + pnorm LN -> Xa [65536,128]
  patch_ln_kernel<<<65536, 128, 0, stream>>>(x, patch_w, patch_b, pnorm_w,
                                             pnorm_b, Xa);

  // Stem stage 0: 8 MLP blocks, dim 128, hidden 384 (GEMM token-chunked x4)
  for (int i = 0; i < 8; ++i) {
    CONV(s0_f1w + i * 49152, 49152, W1h, W1l);
    CONV(s0_f2w + i * 49152, 49152, W2h, W2l);
    lnC_kernel<128><<<65536 / 4, 256, 0, stream>>>(Xa, s0_n2w + i * 128,
                                                   s0_n2b + i * 128, R2h, R2l);
    for (int c = 0; c < 4; ++c) {
      size_t off = (size_t)c * 16384 * 128;
      float* Xc = Xa + off;
      mgemm2_kernel<3, 128><<<(16384 / 128) * (384 / 128), 256, 0, stream>>>(
          R2h + off, R2l + off, W1h, W1l, s0_f1b + i * 384, nullptr, nullptr,
          Hh, Hl, 16384, 384, 128);
      mgemm2_kernel<2, 64><<<(16384 / 64) * (128 / 128), 256, 0, stream>>>(
          Hh, Hl, W2h, W2l, s0_f2b + i * 128, Xc, Xc, nullptr, nullptr, 16384,
          128, 384);
    }
  }
  // Merge 0 -> R2 planes [16384,512] -> GEMM -> Xa [16384,256]
  merge_ln_kernel<0><<<16384, 256, 0, stream>>>(Xa, m0_nw, m0_nb, R2h, R2l);
  CONV(m0_rw, 131072, W1h, W1l);
  mgemm2_kernel<0, 128><<<(16384 / 128) * (256 / 128), 256, 0, stream>>>(
      R2h, R2l, W1h, W1l, nullptr, nullptr, Xa, nullptr, nullptr, 16384, 256,
      512);

  // Stem stage 1: 8 MLP blocks, dim 256, hidden 768 (GEMM token-chunked x2)
  for (int i = 0; i < 8; ++i) {
    CONV(s1_f1w + i * 196608, 196608, W1h, W1l);
    CONV(s1_f2w + i * 196608, 196608, W2h, W2l);
    lnC_kernel<256><<<16384 / 4, 256, 0, stream>>>(Xa, s1_n2w + i * 256,
                                                   s1_n2b + i * 256, R2h, R2l);
    for (int c = 0; c < 2; ++c) {
      size_t off = (size_t)c * 8192 * 256;
      float* Xc = Xa + off;
      mgemm2_kernel<3, 128><<<(8192 / 128) * (768 / 128), 256, 0, stream>>>(
          R2h + off, R2l + off, W1h, W1l, s1_f1b + i * 768, nullptr, nullptr,
          Hh, Hl, 8192, 768, 256);
      mgemm2_kernel<2, 64><<<(8192 / 64) * (256 / 128), 256, 0, stream>>>(
          Hh, Hl, W2h, W2l, s1_f2b + i * 256, Xc, Xc, nullptr, nullptr, 8192,
          256, 768);
    }
  }
  // Merge 1 -> R2 planes [4096,1024] -> GEMM + pos -> Xa [4096,512]
  merge_ln_kernel<1><<<4096, 256, 0, stream>>>(Xa, m1_nw, m1_nb, R2h, R2l);
  CONV(m1_rw, 524288, W1h, W1l);
  mgemm2_kernel<1, 64><<<(4096 / 64) * (512 / 128), 256, 0, stream>>>(
      R2h, R2l, W1h, W1l, nullptr, pos_embed, Xa, nullptr, nullptr, 4096, 512,
      1024);

  // 20 main attention blocks
  for (int l = 0; l < 20; ++l) {
    ln512_kernel<1><<<1024, 256, 0, stream>>>(Xa, mb_n1w + l * 512,
                                              mb_n1b + l * 512, nullptr, R1h,
                                              R1l);
    CONV(mb_qkvw + l * 786432, 786432, W1h, W1l);
    mgemm2_kernel<0, 128><<<(4096 / 128) * (1536 / 128), 256, 0, stream>>>(
        R1h, R1l, W1h, W1l, mb_qkvb + l * 1536, nullptr, Qkv, nullptr, nullptr,
        4096, 1536, 512);
    attn_score_kernel<<<1024, 256, 0, stream>>>(Qkv, mb_rpb + l * 7688, rpe,
                                                R2f);
    attn_pv_kernel<<<512, 256, 0, stream>>>(R2f, Qkv, R1h, R1l);
    CONV(mb_projw + l * 262144, 262144, W1h, W1l);
    mgemm2_kernel<2, 64><<<(4096 / 64) * (512 / 128), 256, 0, stream>>>(
        R1h, R1l, W1h, W1l, mb_projb + l * 512, Xa, Xa, nullptr, nullptr, 4096,
        512, 512);
    ln512_kernel<1><<<1024, 256, 0, stream>>>(Xa, mb_n2w + l * 512,
                                              mb_n2b + l * 512, nullptr, R1h,
                                              R1l);
    CONV(mb_f1w + l * 1048576, 1048576, W1h, W1l);
    CONV(mb_f2w + l * 1048576, 1048576, W2h, W2l);
    mgemm2_kernel<3, 128><<<(4096 / 128) * (2048 / 128), 256, 0, stream>>>(
        R1h, R1l, W1h, W1l, mb_f1b + l * 2048, nullptr, nullptr, R2h, R2l,
        4096, 2048, 512);
    mgemm2_kernel<2, 64><<<(4096 / 64) * (512 / 128), 256, 0, stream>>>(
        R2h, R2l, W2h, W2l, mb_f2b + l * 512, Xa, Xa, nullptr, nullptr, 4096,
        512, 2048);
  }
  // Final LN -> d_out (f32)
  ln512_kernel<0><<<1024, 256, 0, stream>>>(Xa, fnorm_w, fnorm_b,
                                            (float*)d_out, nullptr, nullptr);
}

// Round 9
// 5313.719 us; speedup vs baseline: 14.6129x; 1.4512x over previous
//
#include <hip/hip_runtime.h>
#include <math.h>

#define EPSV 1e-5f

typedef __attribute__((ext_vector_type(8))) short bf16x8;
typedef __attribute__((ext_vector_type(4))) float f32x4;
typedef unsigned short ushort;

__device__ inline ushort f2bf(float x) {
  unsigned u = __builtin_bit_cast(unsigned, x);
  u += 0x7FFFu + ((u >> 16) & 1u);
  return (ushort)(u >> 16);
}

// async global->LDS, 16 bytes per lane; dest = wave-uniform base + lane*16
#define GLOAD16(lptr, gptr)                                              \
  __builtin_amdgcn_global_load_lds(                                      \
      (const __attribute__((address_space(1))) unsigned int*)(gptr),     \
      (__attribute__((address_space(3))) unsigned int*)(lptr), 16, 0, 0)

// ---------------------------------------------------------------------------
// f32 -> bf16 plane conversion (weights). n4 = count/4.
// ---------------------------------------------------------------------------
__global__ __launch_bounds__(256) void convh_kernel(
    const float* __restrict__ in, ushort* __restrict__ hi, int n4) {
  int i = blockIdx.x * 256 + threadIdx.x;
  if (i >= n4) return;
  float4 v = ((const float4*)in)[i];
  float vv[4] = {v.x, v.y, v.z, v.w};
  unsigned hw[4];
#pragma unroll
  for (int e = 0; e < 4; ++e) hw[e] = f2bf(vv[e]);
  ((uint2*)hi)[i] = make_uint2(hw[0] | (hw[1] << 16), hw[2] | (hw[3] << 16));
}

// ---------------------------------------------------------------------------
// Patch embed + pnorm LN v2. Block = (b, n): 16 tokens x 128 ch, 256 thr.
// Input 16x16x3 region + weights staged in LDS; LN via width-16 shfl.
// ---------------------------------------------------------------------------
__global__ __launch_bounds__(256) void patch_ln2_kernel(
    const float* __restrict__ x, const float* __restrict__ pw,
    const float* __restrict__ pbias, const float* __restrict__ nw,
    const float* __restrict__ nb, float* __restrict__ out) {
  int bid = blockIdx.x;  // b*256 + n
  int b = bid >> 8, n = bid & 255;
  int py = (n >> 4) * 16, px0 = (n & 15) * 16;
  __shared__ float xin[3][16][16];
  __shared__ float wls[128][52];
  __shared__ float pbs[128];
  int tid = threadIdx.x;
  if (tid < 192) {
    int ci = tid / 64, rr = (tid % 64) >> 2, c4 = tid & 3;
    const float* src =
        x + ((size_t)(b * 3 + ci) * 256 + (py + rr)) * 256 + px0 + c4 * 4;
    *(float4*)&xin[ci][rr][c4 * 4] = *(const float4*)src;
  }
  for (int idx = tid; idx < 6144; idx += 256) {
    int c = idx / 48, q = idx % 48;
    wls[c][q] = pw[c * 48 + q];
  }
  if (tid < 128) pbs[tid] = pbias[tid];
  __syncthreads();

  int tt = tid >> 4, cg = tid & 15;
  int ii = tt >> 2, jj = tt & 3;
  float xv[48];
#pragma unroll
  for (int ci = 0; ci < 3; ++ci)
#pragma unroll
    for (int dy = 0; dy < 4; ++dy)
#pragma unroll
      for (int dx = 0; dx < 4; ++dx)
        xv[ci * 16 + dy * 4 + dx] = xin[ci][ii * 4 + dy][jj * 4 + dx];

  float o[8];
#pragma unroll
  for (int e = 0; e < 8; ++e) {
    int c = cg + e * 16;
    float a = pbs[c];
#pragma unroll
    for (int q4 = 0; q4 < 12; ++q4) {
      float4 w4 = *(const float4*)&wls[c][q4 * 4];
      a += w4.x * xv[q4 * 4] + w4.y * xv[q4 * 4 + 1] + w4.z * xv[q4 * 4 + 2] +
           w4.w * xv[q4 * 4 + 3];
    }
    o[e] = a;
  }
  float s = 0.f;
#pragma unroll
  for (int e = 0; e < 8; ++e) s += o[e];
#pragma unroll
  for (int off = 8; off > 0; off >>= 1) s += __shfl_xor(s, off, 16);
  float mean = s * (1.0f / 128.0f);
  float sq = 0.f;
#pragma unroll
  for (int e = 0; e < 8; ++e) {
    float d = o[e] - mean;
    sq += d * d;
  }
#pragma unroll
  for (int off = 8; off > 0; off >>= 1) sq += __shfl_xor(sq, off, 16);
  float rstd = rsqrtf(sq * (1.0f / 128.0f) + EPSV);
  size_t base = ((size_t)bid * 16 + tt) * 128;
#pragma unroll
  for (int e = 0; e < 8; ++e) {
    int c = cg + e * 16;
    out[base + c] = (o[e] - mean) * rstd * nw[c] + nb[c];
  }
}

// ---------------------------------------------------------------------------
// LayerNorm over C (128/256), one wave per row, 4 rows/block -> bf16 plane.
// ---------------------------------------------------------------------------
template <int C>
__global__ __launch_bounds__(256) void lnC_kernel(
    const float* __restrict__ X, const float* __restrict__ w,
    const float* __restrict__ bb, ushort* __restrict__ outH) {
  constexpr int NV = C / 64;
  int wave = threadIdx.x >> 6, lane = threadIdx.x & 63;
  int row = blockIdx.x * 4 + wave;
  const float* xr = X + (size_t)row * C + lane * NV;
  float v[NV];
  if (NV == 2) {
    float2 t2 = *(const float2*)xr;
    v[0] = t2.x; v[1] = t2.y;
  } else {
#pragma unroll
    for (int q = 0; q < NV; q += 4) {
      float4 t4 = *(const float4*)(xr + q);
      v[q] = t4.x; v[q + 1] = t4.y; v[q + 2] = t4.z; v[q + 3] = t4.w;
    }
  }
  float s = 0.f;
#pragma unroll
  for (int q = 0; q < NV; ++q) s += v[q];
#pragma unroll
  for (int o = 32; o > 0; o >>= 1) s += __shfl_xor(s, o, 64);
  float mean = s * (1.0f / C);
  float sq = 0.f;
#pragma unroll
  for (int q = 0; q < NV; ++q) {
    float d = v[q] - mean;
    sq += d * d;
  }
#pragma unroll
  for (int o = 32; o > 0; o >>= 1) sq += __shfl_xor(sq, o, 64);
  float rstd = rsqrtf(sq * (1.0f / C) + EPSV);
#pragma unroll
  for (int q = 0; q < NV; ++q) {
    int c = lane * NV + q;
    outH[(size_t)row * C + c] = f2bf((v[q] - mean) * rstd * w[c] + bb[c]);
  }
}

// ---------------------------------------------------------------------------
// Patch merge gather + LN -> bf16 plane.
// ---------------------------------------------------------------------------
template <int MODE>
__global__ __launch_bounds__(256) void merge_ln_kernel(
    const float* __restrict__ Xin, const float* __restrict__ nw,
    const float* __restrict__ nb, ushort* __restrict__ outH) {
  constexpr int CM = MODE ? 1024 : 512;
  constexpr int NE = CM / 256;
  int ot = blockIdx.x;
  int tid = threadIdx.x;
  __shared__ float redA[4];
  __shared__ float redB[4];

  float v[NE];
#pragma unroll
  for (int e = 0; e < NE; ++e) {
    int cp = tid + e * 256;
    if (MODE == 0) {
      int b = ot >> 10, r = ot & 1023;
      int n = r >> 2, di = (r >> 1) & 1, dj = r & 1;
      int q = cp >> 7, c = cp & 127;
      int i = 2 * di + (q & 1), j = 2 * dj + (q >> 1);
      v[e] = Xin[((b * 256 + n) * 16 + i * 4 + j) * 128 + c];
    } else {
      int b = ot >> 8, n = ot & 255;
      int q = cp >> 8, c = cp & 255;
      int di = q & 1, dj = q >> 1;
      v[e] = Xin[((b * 256 + n) * 4 + di * 2 + dj) * 256 + c];
    }
  }
  float s = 0.f;
#pragma unroll
  for (int e = 0; e < NE; ++e) s += v[e];
#pragma unroll
  for (int o = 32; o > 0; o >>= 1) s += __shfl_xor(s, o, 64);
  if ((tid & 63) == 0) redA[tid >> 6] = s;
  __syncthreads();
  float mean = (redA[0] + redA[1] + redA[2] + redA[3]) * (1.0f / CM);
  float sq = 0.f;
#pragma unroll
  for (int e = 0; e < NE; ++e) {
    float d = v[e] - mean;
    sq += d * d;
  }
#pragma unroll
  for (int o = 32; o > 0; o >>= 1) sq += __shfl_xor(sq, o, 64);
  if ((tid & 63) == 0) redB[tid >> 6] = sq;
  __syncthreads();
  float var = (redB[0] + redB[1] + redB[2] + redB[3]) * (1.0f / CM);
  float rstd = rsqrtf(var + EPSV);
#pragma unroll
  for (int e = 0; e < NE; ++e) {
    int cp = tid + e * 256;
    outH[(size_t)ot * CM + cp] = f2bf((v[e] - mean) * rstd * nw[cp] + nb[cp]);
  }
}

// ---------------------------------------------------------------------------
// Pure-bf16 MFMA GEMM (single product). Tile BM x 128, BK=32, 256 thr.
// EP 0: bias->f32. EP 1: +pos->f32. EP 2: +extra->f32 (residual).
// EP 3: gelu(acc+bias) -> bf16 plane.
// ---------------------------------------------------------------------------
template <int EP, int BM>
__global__ __launch_bounds__(256) void mgemm3_kernel(
    const ushort* __restrict__ Ah, const ushort* __restrict__ Wh,
    const float* __restrict__ bias, const float* __restrict__ extra,
    float* __restrict__ outF, ushort* __restrict__ outH, int M, int N, int K) {
  constexpr int NI = BM / 32;
  constexpr int APL = BM * 32;  // A tile shorts
  __shared__ __align__(16) ushort Lds[APL + 4096];
  int nb = N >> 7;
  int bx = blockIdx.x % nb, by = blockIdx.x / nb;
  int tid = threadIdx.x;
  int r0 = tid >> 2;
  int cc = (tid & 3) << 3;
  const ushort* aS0 = Ah + (size_t)(by * BM + r0) * K + cc;
  const ushort* wS0 = Wh + (size_t)(bx * 128 + r0) * K + cc;
  const ushort* wS1 = wS0 + (size_t)64 * K;
  int wv = tid >> 6;
  ushort* dA0 = Lds + wv * 512;
  ushort* dW0 = Lds + APL + wv * 512;
  ushort* dW1 = Lds + APL + 2048 + wv * 512;

  int lane = tid & 63;
  int wm = (wv >> 1) * (BM / 2), wn = (wv & 1) * 64;
  int fr = lane & 15, fq = lane >> 4;
  const ushort* raA = Lds + (wm + fr) * 32 + fq * 8;
  const ushort* raW = Lds + APL + (wn + fr) * 32 + fq * 8;

  f32x4 acc[NI][4];
#pragma unroll
  for (int i = 0; i < NI; ++i)
#pragma unroll
    for (int j = 0; j < 4; ++j) acc[i][j] = {0.f, 0.f, 0.f, 0.f};

  for (int k0 = 0; k0 < K; k0 += 32) {
    GLOAD16(dA0, aS0 + k0);
    if (BM == 128) GLOAD16(dA0 + 2048, aS0 + (size_t)64 * K + k0);
    GLOAD16(dW0, wS0 + k0);
    GLOAD16(dW1, wS1 + k0);
    __syncthreads();

    bf16x8 fa[NI], fb[4];
#pragma unroll
    for (int i = 0; i < NI; ++i) fa[i] = *(const bf16x8*)(raA + i * 512);
#pragma unroll
    for (int j = 0; j < 4; ++j) fb[j] = *(const bf16x8*)(raW + j * 512);
#pragma unroll
    for (int i = 0; i < NI; ++i)
#pragma unroll
      for (int j = 0; j < 4; ++j)
        acc[i][j] = __builtin_amdgcn_mfma_f32_16x16x32_bf16(fa[i], fb[j],
                                                            acc[i][j], 0, 0, 0);
    __syncthreads();
  }

  int row0 = by * BM + wm;
  int col0 = bx * 128 + wn;
#pragma unroll
  for (int j = 0; j < 4; ++j) {
    int col = col0 + j * 16 + fr;
    float bvv = bias ? bias[col] : 0.f;
#pragma unroll
    for (int i = 0; i < NI; ++i) {
#pragma unroll
      for (int e = 0; e < 4; ++e) {
        int row = row0 + i * 16 + fq * 4 + e;
        float o = acc[i][j][e] + bvv;
        if (EP == 1) {
          o += extra[(row & 255) * N + col];
          outF[(size_t)row * N + col] = o;
        } else if (EP == 2) {
          o += extra[(size_t)row * N + col];
          outF[(size_t)row * N + col] = o;
        } else if (EP == 3) {
          o = 0.5f * o * (1.0f + erff(o * 0.70710678118654752f));
          outH[(size_t)row * N + col] = f2bf(o);
        } else {
          outF[(size_t)row * N + col] = o;
        }
      }
    }
  }
}

// ---------------------------------------------------------------------------
// Attention scores + softmax. Block = (b,h, 32 q-rows), 256 thr (4 waves).
// K transposed in-LDS from qkv (stride-65 pad).
// ---------------------------------------------------------------------------
__global__ __launch_bounds__(256) void attn_score_kernel(
    const float* __restrict__ qkv, const float* __restrict__ rpb,
    const int* __restrict__ rpe, float* __restrict__ P) {
  int bid = blockIdx.x;
  int nb = bid & 7, bh = bid >> 3;
  int b = bh >> 3, h = bh & 7;
  int n0 = nb * 32;
  int tid = threadIdx.x;
  int wv = tid >> 6, lane = tid & 63;
  __shared__ float qs[32][68];
  __shared__ float kts[64][65];
  {
    int r = tid >> 3, seg = (tid & 7) * 8;
    const float* src =
        qkv + ((size_t)(b * 256 + n0 + r)) * 1536 + h * 64 + seg;
    float4 a0 = ((const float4*)src)[0];
    float4 a1 = ((const float4*)src)[1];
    float4 s0 = {a0.x * 0.125f, a0.y * 0.125f, a0.z * 0.125f, a0.w * 0.125f};
    float4 s1 = {a1.x * 0.125f, a1.y * 0.125f, a1.z * 0.125f, a1.w * 0.125f};
    *(float4*)&qs[r][seg] = s0;
    *(float4*)&qs[r][seg + 4] = s1;
  }
  float sreg[8][4];
#pragma unroll 1
  for (int c = 0; c < 4; ++c) {
    __syncthreads();
    {
      int mi = tid >> 2, sg = (tid & 3) * 16;
      const float* ksrc =
          qkv + ((size_t)(b * 256 + c * 64 + mi)) * 1536 + 512 + h * 64 + sg;
#pragma unroll
      for (int e = 0; e < 4; ++e) {
        float4 k4 = ((const float4*)ksrc)[e];
        kts[sg + e * 4 + 0][mi] = k4.x;
        kts[sg + e * 4 + 1][mi] = k4.y;
        kts[sg + e * 4 + 2][mi] = k4.z;
        kts[sg + e * 4 + 3][mi] = k4.w;
      }
    }
    __syncthreads();
    float acc[8];
#pragma unroll
    for (int nn = 0; nn < 8; ++nn) acc[nn] = 0.f;
#pragma unroll 4
    for (int d0 = 0; d0 < 64; d0 += 4) {
      float kv0 = kts[d0 + 0][lane];
      float kv1 = kts[d0 + 1][lane];
      float kv2 = kts[d0 + 2][lane];
      float kv3 = kts[d0 + 3][lane];
#pragma unroll
      for (int nn = 0; nn < 8; ++nn) {
        float4 q4 = *(const float4*)&qs[wv * 8 + nn][d0];
        acc[nn] += q4.x * kv0 + q4.y * kv1 + q4.z * kv2 + q4.w * kv3;
      }
    }
#pragma unroll
    for (int nn = 0; nn < 8; ++nn) {
      int n = n0 + wv * 8 + nn;
      int idx = rpe[n * 256 + c * 64 + lane];
      sreg[nn][c] = acc[nn] + rpb[idx * 8 + h];
    }
  }
#pragma unroll
  for (int nn = 0; nn < 8; ++nn) {
    int n = n0 + wv * 8 + nn;
    float mx = fmaxf(fmaxf(sreg[nn][0], sreg[nn][1]),
                     fmaxf(sreg[nn][2], sreg[nn][3]));
#pragma unroll
    for (int o = 32; o > 0; o >>= 1) mx = fmaxf(mx, __shfl_xor(mx, o, 64));
    float sum = 0.f;
#pragma unroll
    for (int c = 0; c < 4; ++c) {
      sreg[nn][c] = expf(sreg[nn][c] - mx);
      sum += sreg[nn][c];
    }
#pragma unroll
    for (int o = 32; o > 0; o >>= 1) sum += __shfl_xor(sum, o, 64);
    float inv = 1.0f / sum;
    float* Pr = P + ((size_t)bh * 256 + n) * 256;
#pragma unroll
    for (int c = 0; c < 4; ++c) Pr[c * 64 + lane] = sreg[nn][c] * inv;
  }
}

// ---------------------------------------------------------------------------
// O = P @ V -> bf16 plane. Block per (b,h,64-q tile).
// ---------------------------------------------------------------------------
__global__ __launch_bounds__(256) void attn_pv_kernel(
    const float* __restrict__ P, const float* __restrict__ qkv,
    ushort* __restrict__ outH) {
  int bid = blockIdx.x;  // b*32 + h*4 + nt
  int nt = bid & 3, h = (bid >> 2) & 7, b = bid >> 5;
  int tid = threadIdx.x;
  __shared__ float4 Vs4[256 * 16];
  for (int idx = tid; idx < 4096; idx += 256) {
    int m = idx >> 4, d4 = idx & 15;
    Vs4[m * 16 + d4] = *(const float4*)(
        qkv + ((size_t)(b * 256 + m)) * 1536 + 1024 + h * 64 + d4 * 4);
  }
  __syncthreads();

  int d4 = tid & 15, ng = tid >> 4;
  int nbase = nt * 64 + ng * 4;
  const float* P0 = P + ((size_t)((b * 8 + h) * 256 + nbase)) * 256;
  float4 a0 = {0, 0, 0, 0}, a1 = a0, a2 = a0, a3 = a0;
#pragma unroll 2
  for (int m4 = 0; m4 < 64; ++m4) {
    float4 v0 = Vs4[(m4 * 4 + 0) * 16 + d4];
    float4 v1 = Vs4[(m4 * 4 + 1) * 16 + d4];
    float4 v2 = Vs4[(m4 * 4 + 2) * 16 + d4];
    float4 v3 = Vs4[(m4 * 4 + 3) * 16 + d4];
    float4 p;
#define PVACC(A, ROW)                                              \
  p = ((const float4*)(P0 + (ROW)*256))[m4];                       \
  A.x += p.x * v0.x + p.y * v1.x + p.z * v2.x + p.w * v3.x;        \
  A.y += p.x * v0.y + p.y * v1.y + p.z * v2.y + p.w * v3.y;        \
  A.z += p.x * v0.z + p.y * v1.z + p.z * v2.z + p.w * v3.z;        \
  A.w += p.x * v0.w + p.y * v1.w + p.z * v2.w + p.w * v3.w;
    PVACC(a0, 0)
    PVACC(a1, 1)
    PVACC(a2, 2)
    PVACC(a3, 3)
#undef PVACC
  }
  float4 accs[4] = {a0, a1, a2, a3};
#pragma unroll
  for (int i = 0; i < 4; ++i) {
    int n = nbase + i;
    size_t oidx = ((size_t)(b * 256 + n)) * 512 + h * 64 + d4 * 4;
    float vv[4] = {accs[i].x, accs[i].y, accs[i].z, accs[i].w};
    unsigned hw[4];
#pragma unroll
    for (int e = 0; e < 4; ++e) hw[e] = f2bf(vv[e]);
    *(uint2*)(outH + oidx) =
        make_uint2(hw[0] | (hw[1] << 16), hw[2] | (hw[3] << 16));
  }
}

// ---------------------------------------------------------------------------
// LayerNorm over 512, wave per row, 4 rows/block. HL=0 f32, HL=1 bf16 plane.
// ---------------------------------------------------------------------------
template <int HL>
__global__ __launch_bounds__(256) void ln512_kernel(
    const float* __restrict__ X, const float* __restrict__ w,
    const float* __restrict__ bb, float* __restrict__ outF,
    ushort* __restrict__ outH) {
  int row = blockIdx.x * 4 + (threadIdx.x >> 6);
  int t = threadIdx.x & 63;
  const float4* xr = (const float4*)(X + (size_t)row * 512);
  float4 v0 = xr[t * 2], v1 = xr[t * 2 + 1];
  float s = v0.x + v0.y + v0.z + v0.w + v1.x + v1.y + v1.z + v1.w;
#pragma unroll
  for (int o = 32; o > 0; o >>= 1) s += __shfl_xor(s, o, 64);
  float mean = s * (1.0f / 512.0f);
  float dv[8] = {v0.x - mean, v0.y - mean, v0.z - mean, v0.w - mean,
                 v1.x - mean, v1.y - mean, v1.z - mean, v1.w - mean};
  float sq = 0.f;
#pragma unroll
  for (int e = 0; e < 8; ++e) sq += dv[e] * dv[e];
#pragma unroll
  for (int o = 32; o > 0; o >>= 1) sq += __shfl_xor(sq, o, 64);
  float rstd = rsqrtf(sq * (1.0f / 512.0f) + EPSV);
  int c = t * 8;
  float ov[8];
#pragma unroll
  for (int e = 0; e < 8; ++e) ov[e] = dv[e] * rstd * w[c + e] + bb[c + e];
  if (HL == 0) {
    float4 o0 = {ov[0], ov[1], ov[2], ov[3]};
    float4 o1 = {ov[4], ov[5], ov[6], ov[7]};
    ((float4*)(outF + (size_t)row * 512))[t * 2] = o0;
    ((float4*)(outF + (size_t)row * 512))[t * 2 + 1] = o1;
  } else {
    __align__(16) ushort h8[8];
#pragma unroll
    for (int e = 0; e < 8; ++e) h8[e] = f2bf(ov[e]);
    *(bf16x8*)(outH + (size_t)row * 512 + c) = *(bf16x8*)h8;
  }
}

// ---------------------------------------------------------------------------
extern "C" void kernel_launch(void* const* d_in, const int* in_sizes, int n_in,
                              void* d_out, int out_size, void* d_ws,
                              size_t ws_size, hipStream_t stream) {
  const float* x = (const float*)d_in[0];
  const float* patch_w = (const float*)d_in[1];
  const float* patch_b = (const float*)d_in[2];
  const float* pnorm_w = (const float*)d_in[3];
  const float* pnorm_b = (const float*)d_in[4];
  const float* s0_n2w = (const float*)d_in[5];
  const float* s0_n2b = (const float*)d_in[6];
  const float* s0_f1w = (const float*)d_in[7];
  const float* s0_f1b = (const float*)d_in[8];
  const float* s0_f2w = (const float*)d_in[9];
  const float* s0_f2b = (const float*)d_in[10];
  const float* m0_nw = (const float*)d_in[11];
  const float* m0_nb = (const float*)d_in[12];
  const float* m0_rw = (const float*)d_in[13];
  const float* s1_n2w = (const float*)d_in[14];
  const float* s1_n2b = (const float*)d_in[15];
  const float* s1_f1w = (const float*)d_in[16];
  const float* s1_f1b = (const float*)d_in[17];
  const float* s1_f2w = (const float*)d_in[18];
  const float* s1_f2b = (const float*)d_in[19];
  const float* m1_nw = (const float*)d_in[20];
  const float* m1_nb = (const float*)d_in[21];
  const float* m1_rw = (const float*)d_in[22];
  const float* pos_embed = (const float*)d_in[23];
  const float* mb_n1w = (const float*)d_in[24];
  const float* mb_n1b = (const float*)d_in[25];
  const float* mb_qkvw = (const float*)d_in[26];
  const float* mb_qkvb = (const float*)d_in[27];
  const float* mb_rpb = (const float*)d_in[28];
  const float* mb_projw = (const float*)d_in[29];
  const float* mb_projb = (const float*)d_in[30];
  const float* mb_n2w = (const float*)d_in[31];
  const float* mb_n2b = (const float*)d_in[32];
  const float* mb_f1w = (const float*)d_in[33];
  const float* mb_f1b = (const float*)d_in[34];
  const float* mb_f2w = (const float*)d_in[35];
  const float* mb_f2b = (const float*)d_in[36];
  const float* fnorm_w = (const float*)d_in[37];
  const float* fnorm_b = (const float*)d_in[38];
  const int* rpe = (const int*)d_in[39];

  // Workspace layout (same base offsets as round 8; lo planes unused)
  float* Xa = (float*)d_ws;                     // 8,388,608 f (residual)
  ushort* R1h = (ushort*)(Xa + 8388608);        // 2,097,152 sh
  float* R2f = (float*)(R1h + 4194304);         // 8,388,608 f (P buffer)
  ushort* R2h = (ushort*)R2f;                   // 8,388,608 sh
  float* Qkv = R2f + 8388608;                   // 6,291,456 f
  ushort* Hh = (ushort*)Qkv;                    // stem hidden (aliases Qkv)
  ushort* W1h = (ushort*)(Qkv + 6291456);       // 1,048,576 sh
  ushort* W2h = W1h + 1048576;                  // 1,048,576 sh

#define CONVH(src, cnt, dh)                                              \
  convh_kernel<<<((cnt) / 4 + 255) / 256, 256, 0, stream>>>(src, dh, (cnt) / 4)

  // Patch embed + pnorm LN -> Xa [65536,128]
  patch_ln2_kernel<<<4096, 256, 0, stream>>>(x, patch_w, patch_b, pnorm_w,
                                             pnorm_b, Xa);

  // Stem stage 0: 8 MLP blocks, dim 128, hidden 384 (GEMM token-chunked x4)
  for (int i = 0; i < 8; ++i) {
    CONVH(s0_f1w + i * 49152, 49152, W1h);
    CONVH(s0_f2w + i * 49152, 49152, W2h);
    lnC_kernel<128><<<65536 / 4, 256, 0, stream>>>(Xa, s0_n2w + i * 128,
                                                   s0_n2b + i * 128, R2h);
    for (int c = 0; c < 4; ++c) {
      size_t off = (size_t)c * 16384 * 128;
      float* Xc = Xa + off;
      mgemm3_kernel<3, 128><<<(16384 / 128) * (384 / 128), 256, 0, stream>>>(
          R2h + off, W1h, s0_f1b + i * 384, nullptr, nullptr, Hh, 16384, 384,
          128);
      mgemm3_kernel<2, 64><<<(16384 / 64) * (128 / 128), 256, 0, stream>>>(
          Hh, W2h, s0_f2b + i * 128, Xc, Xc, nullptr, 16384, 128, 384);
    }
  }
  // Merge 0 -> R2 plane [16384,512] -> GEMM -> Xa [16384,256]
  merge_ln_kernel<0><<<16384, 256, 0, stream>>>(Xa, m0_nw, m0_nb, R2h);
  CONVH(m0_rw, 131072, W1h);
  mgemm3_kernel<0, 128><<<(16384 / 128) * (256 / 128), 256, 0, stream>>>(
      R2h, W1h, nullptr, nullptr, Xa, nullptr, 16384, 256, 512);

  // Stem stage 1: 8 MLP blocks, dim 256, hidden 768 (GEMM token-chunked x2)
  for (int i = 0; i < 8; ++i) {
    CONVH(s1_f1w + i * 196608, 196608, W1h);
    CONVH(s1_f2w + i * 196608, 196608, W2h);
    lnC_kernel<256><<<16384 / 4, 256, 0, stream>>>(Xa, s1_n2w + i * 256,
                                                   s1_n2b + i * 256, R2h);
    for (int c = 0; c < 2; ++c) {
      size_t off = (size_t)c * 8192 * 256;
      float* Xc = Xa + off;
      mgemm3_kernel<3, 128><<<(8192 / 128) * (768 / 128), 256, 0, stream>>>(
          R2h + off, W1h, s1_f1b + i * 768, nullptr, nullptr, Hh, 8192, 768,
          256);
      mgemm3_kernel<2, 64><<<(8192 / 64) * (256 / 128), 256, 0, stream>>>(
          Hh, W2h, s1_f2b + i * 256, Xc, Xc, nullptr, 8192, 256, 768);
    }
  }
  // Merge 1 -> R2 plane [4096,1024] -> GEMM + pos -> Xa [4096,512]
  merge_ln_kernel<1><<<4096, 256, 0, stream>>>(Xa, m1_nw, m1_nb, R2h);
  CONVH(m1_rw, 524288, W1h);
  mgemm3_kernel<1, 64><<<(4096 / 64) * (512 / 128), 256, 0, stream>>>(
      R2h, W1h, nullptr, pos_embed, Xa, nullptr, 4096, 512, 1024);

  // 20 main attention blocks
  for (int l = 0; l < 20; ++l) {
    ln512_kernel<1><<<1024, 256, 0, stream>>>(Xa, mb_n1w + l * 512,
                                              mb_n1b + l * 512, nullptr, R1h);
    CONVH(mb_qkvw + l * 786432, 786432, W1h);
    mgemm3_kernel<0, 128><<<(4096 / 128) * (1536 / 128), 256, 0, stream>>>(
        R1h, W1h, mb_qkvb + l * 1536, nullptr, Qkv, nullptr, 4096, 1536, 512);
    attn_score_kernel<<<1024, 256, 0, stream>>>(Qkv, mb_rpb + l * 7688, rpe,
                                                R2f);
    attn_pv_kernel<<<512, 256, 0, stream>>>(R2f, Qkv, R1h);
    CONVH(mb_projw + l * 262144, 262144, W1h);
    mgemm3_kernel<2, 64><<<(4096 / 64) * (512 / 128), 256, 0, stream>>>(
        R1h, W1h, mb_projb + l * 512, Xa, Xa, nullptr, 4096, 512, 512);
    ln512_kernel<1><<<1024, 256, 0, stream>>>(Xa, mb_n2w + l * 512,
                                              mb_n2b + l * 512, nullptr, R1h);
    CONVH(mb_f1w + l * 1048576, 1048576, W1h);
    CONVH(mb_f2w + l * 1048576, 1048576, W2h);
    mgemm3_kernel<3, 128><<<(4096 / 128) * (2048 / 128), 256, 0, stream>>>(
        R1h, W1h, mb_f1b + l * 2048, nullptr, nullptr, R2h, 4096, 2048, 512);
    mgemm3_kernel<2, 64><<<(4096 / 64) * (512 / 128), 256, 0, stream>>>(
        R2h, W2h, mb_f2b + l * 512, Xa, Xa, nullptr, 4096, 512, 2048);
  }
  // Final LN -> d_out (f32)
  ln512_kernel<0><<<1024, 256, 0, stream>>>(Xa, fnorm_w, fnorm_b,
                                            (float*)d_out, nullptr);
}

// Round 10
// 4987.547 us; speedup vs baseline: 15.5686x; 1.0654x over previous
//
#include <hip/hip_runtime.h>
#include <math.h>

#define EPSV 1e-5f

typedef __attribute__((ext_vector_type(8))) short bf16x8;
typedef __attribute__((ext_vector_type(4))) float f32x4;
typedef unsigned short ushort;

__device__ inline ushort f2bf(float x) {
  unsigned u = __builtin_bit_cast(unsigned, x);
  u += 0x7FFFu + ((u >> 16) & 1u);
  return (ushort)(u >> 16);
}

// async global->LDS, 16 bytes per lane; dest = wave-uniform base + lane*16
#define GLOAD16(lptr, gptr)                                              \
  __builtin_amdgcn_global_load_lds(                                      \
      (const __attribute__((address_space(1))) unsigned int*)(gptr),     \
      (__attribute__((address_space(3))) unsigned int*)(lptr), 16, 0, 0)

// ---------------------------------------------------------------------------
// f32 -> bf16 plane conversion (weights). n4 = count/4.
// ---------------------------------------------------------------------------
__global__ __launch_bounds__(256) void convh_kernel(
    const float* __restrict__ in, ushort* __restrict__ hi, int n4) {
  int i = blockIdx.x * 256 + threadIdx.x;
  if (i >= n4) return;
  float4 v = ((const float4*)in)[i];
  float vv[4] = {v.x, v.y, v.z, v.w};
  unsigned hw[4];
#pragma unroll
  for (int e = 0; e < 4; ++e) hw[e] = f2bf(vv[e]);
  ((uint2*)hi)[i] = make_uint2(hw[0] | (hw[1] << 16), hw[2] | (hw[3] << 16));
}

// ---------------------------------------------------------------------------
// Fused 4-source weight conversion for one main layer.
// el/4 sizes: qkv 196608, proj 65536, f1 262144, f2 262144 (sum 786432).
// dst offsets (shorts): 0, 786432, 1048576, 2097152. Grid = 3072 x 256.
// ---------------------------------------------------------------------------
__global__ __launch_bounds__(256) void conv4_kernel(
    const float* __restrict__ s0, const float* __restrict__ s1,
    const float* __restrict__ s2, const float* __restrict__ s3,
    ushort* __restrict__ dst) {
  int i = blockIdx.x * 256 + threadIdx.x;
  const float* src;
  ushort* d;
  int off4;
  if (i < 196608) {
    src = s0; off4 = i; d = dst;
  } else if (i < 262144) {
    src = s1; off4 = i - 196608; d = dst + 786432;
  } else if (i < 524288) {
    src = s2; off4 = i - 262144; d = dst + 1048576;
  } else {
    src = s3; off4 = i - 524288; d = dst + 2097152;
  }
  float4 v = ((const float4*)src)[off4];
  float vv[4] = {v.x, v.y, v.z, v.w};
  unsigned hw[4];
#pragma unroll
  for (int e = 0; e < 4; ++e) hw[e] = f2bf(vv[e]);
  ((uint2*)d)[off4] = make_uint2(hw[0] | (hw[1] << 16), hw[2] | (hw[3] << 16));
}

// ---------------------------------------------------------------------------
// Patch embed + pnorm LN v2. Block = (b, n): 16 tokens x 128 ch, 256 thr.
// ---------------------------------------------------------------------------
__global__ __launch_bounds__(256) void patch_ln2_kernel(
    const float* __restrict__ x, const float* __restrict__ pw,
    const float* __restrict__ pbias, const float* __restrict__ nw,
    const float* __restrict__ nb, float* __restrict__ out) {
  int bid = blockIdx.x;  // b*256 + n
  int b = bid >> 8, n = bid & 255;
  int py = (n >> 4) * 16, px0 = (n & 15) * 16;
  __shared__ float xin[3][16][16];
  __shared__ float wls[128][52];
  __shared__ float pbs[128];
  int tid = threadIdx.x;
  if (tid < 192) {
    int ci = tid / 64, rr = (tid % 64) >> 2, c4 = tid & 3;
    const float* src =
        x + ((size_t)(b * 3 + ci) * 256 + (py + rr)) * 256 + px0 + c4 * 4;
    *(float4*)&xin[ci][rr][c4 * 4] = *(const float4*)src;
  }
  for (int idx = tid; idx < 6144; idx += 256) {
    int c = idx / 48, q = idx % 48;
    wls[c][q] = pw[c * 48 + q];
  }
  if (tid < 128) pbs[tid] = pbias[tid];
  __syncthreads();

  int tt = tid >> 4, cg = tid & 15;
  int ii = tt >> 2, jj = tt & 3;
  float xv[48];
#pragma unroll
  for (int ci = 0; ci < 3; ++ci)
#pragma unroll
    for (int dy = 0; dy < 4; ++dy)
#pragma unroll
      for (int dx = 0; dx < 4; ++dx)
        xv[ci * 16 + dy * 4 + dx] = xin[ci][ii * 4 + dy][jj * 4 + dx];

  float o[8];
#pragma unroll
  for (int e = 0; e < 8; ++e) {
    int c = cg + e * 16;
    float a = pbs[c];
#pragma unroll
    for (int q4 = 0; q4 < 12; ++q4) {
      float4 w4 = *(const float4*)&wls[c][q4 * 4];
      a += w4.x * xv[q4 * 4] + w4.y * xv[q4 * 4 + 1] + w4.z * xv[q4 * 4 + 2] +
           w4.w * xv[q4 * 4 + 3];
    }
    o[e] = a;
  }
  float s = 0.f;
#pragma unroll
  for (int e = 0; e < 8; ++e) s += o[e];
#pragma unroll
  for (int off = 8; off > 0; off >>= 1) s += __shfl_xor(s, off, 16);
  float mean = s * (1.0f / 128.0f);
  float sq = 0.f;
#pragma unroll
  for (int e = 0; e < 8; ++e) {
    float d = o[e] - mean;
    sq += d * d;
  }
#pragma unroll
  for (int off = 8; off > 0; off >>= 1) sq += __shfl_xor(sq, off, 16);
  float rstd = rsqrtf(sq * (1.0f / 128.0f) + EPSV);
  size_t base = ((size_t)bid * 16 + tt) * 128;
#pragma unroll
  for (int e = 0; e < 8; ++e) {
    int c = cg + e * 16;
    out[base + c] = (o[e] - mean) * rstd * nw[c] + nb[c];
  }
}

// ---------------------------------------------------------------------------
// LayerNorm over C (128/256), one wave per row, 4 rows/block -> bf16 plane.
// ---------------------------------------------------------------------------
template <int C>
__global__ __launch_bounds__(256) void lnC_kernel(
    const float* __restrict__ X, const float* __restrict__ w,
    const float* __restrict__ bb, ushort* __restrict__ outH) {
  constexpr int NV = C / 64;
  int wave = threadIdx.x >> 6, lane = threadIdx.x & 63;
  int row = blockIdx.x * 4 + wave;
  const float* xr = X + (size_t)row * C + lane * NV;
  float v[NV];
  if (NV == 2) {
    float2 t2 = *(const float2*)xr;
    v[0] = t2.x; v[1] = t2.y;
  } else {
#pragma unroll
    for (int q = 0; q < NV; q += 4) {
      float4 t4 = *(const float4*)(xr + q);
      v[q] = t4.x; v[q + 1] = t4.y; v[q + 2] = t4.z; v[q + 3] = t4.w;
    }
  }
  float s = 0.f;
#pragma unroll
  for (int q = 0; q < NV; ++q) s += v[q];
#pragma unroll
  for (int o = 32; o > 0; o >>= 1) s += __shfl_xor(s, o, 64);
  float mean = s * (1.0f / C);
  float sq = 0.f;
#pragma unroll
  for (int q = 0; q < NV; ++q) {
    float d = v[q] - mean;
    sq += d * d;
  }
#pragma unroll
  for (int o = 32; o > 0; o >>= 1) sq += __shfl_xor(sq, o, 64);
  float rstd = rsqrtf(sq * (1.0f / C) + EPSV);
#pragma unroll
  for (int q = 0; q < NV; ++q) {
    int c = lane * NV + q;
    outH[(size_t)row * C + c] = f2bf((v[q] - mean) * rstd * w[c] + bb[c]);
  }
}

// ---------------------------------------------------------------------------
// Patch merge gather + LN -> bf16 plane.
// ---------------------------------------------------------------------------
template <int MODE>
__global__ __launch_bounds__(256) void merge_ln_kernel(
    const float* __restrict__ Xin, const float* __restrict__ nw,
    const float* __restrict__ nb, ushort* __restrict__ outH) {
  constexpr int CM = MODE ? 1024 : 512;
  constexpr int NE = CM / 256;
  int ot = blockIdx.x;
  int tid = threadIdx.x;
  __shared__ float redA[4];
  __shared__ float redB[4];

  float v[NE];
#pragma unroll
  for (int e = 0; e < NE; ++e) {
    int cp = tid + e * 256;
    if (MODE == 0) {
      int b = ot >> 10, r = ot & 1023;
      int n = r >> 2, di = (r >> 1) & 1, dj = r & 1;
      int q = cp >> 7, c = cp & 127;
      int i = 2 * di + (q & 1), j = 2 * dj + (q >> 1);
      v[e] = Xin[((b * 256 + n) * 16 + i * 4 + j) * 128 + c];
    } else {
      int b = ot >> 8, n = ot & 255;
      int q = cp >> 8, c = cp & 255;
      int di = q & 1, dj = q >> 1;
      v[e] = Xin[((b * 256 + n) * 4 + di * 2 + dj) * 256 + c];
    }
  }
  float s = 0.f;
#pragma unroll
  for (int e = 0; e < NE; ++e) s += v[e];
#pragma unroll
  for (int o = 32; o > 0; o >>= 1) s += __shfl_xor(s, o, 64);
  if ((tid & 63) == 0) redA[tid >> 6] = s;
  __syncthreads();
  float mean = (redA[0] + redA[1] + redA[2] + redA[3]) * (1.0f / CM);
  float sq = 0.f;
#pragma unroll
  for (int e = 0; e < NE; ++e) {
    float d = v[e] - mean;
    sq += d * d;
  }
#pragma unroll
  for (int o = 32; o > 0; o >>= 1) sq += __shfl_xor(sq, o, 64);
  if ((tid & 63) == 0) redB[tid >> 6] = sq;
  __syncthreads();
  float var = (redB[0] + redB[1] + redB[2] + redB[3]) * (1.0f / CM);
  float rstd = rsqrtf(var + EPSV);
#pragma unroll
  for (int e = 0; e < NE; ++e) {
    int cp = tid + e * 256;
    outH[(size_t)ot * CM + cp] = f2bf((v[e] - mean) * rstd * nw[cp] + nb[cp]);
  }
}

// ---------------------------------------------------------------------------
// bf16 MFMA GEMM v4: BK=64, XOR-swizzled LDS (linear dest + pre-swizzled
// global source + swizzled ds_read -> conflict-free, half the barriers).
// Tile BM x 128, 256 thr (4 waves). EP as before.
// ---------------------------------------------------------------------------
template <int EP, int BM>
__global__ __launch_bounds__(256) void mgemm4_kernel(
    const ushort* __restrict__ Ah, const ushort* __restrict__ Wh,
    const float* __restrict__ bias, const float* __restrict__ extra,
    float* __restrict__ outF, ushort* __restrict__ outH, int M, int N, int K) {
  constexpr int NI = BM / 32;
  constexpr int ASH = BM * 64;  // A tile shorts
  __shared__ __align__(16) ushort Lds[ASH + 8192];
  int nb = N >> 7;
  int bx = blockIdx.x % nb, by = blockIdx.x / nb;
  int tid = threadIdx.x;
  int wv = tid >> 6, lane = tid & 63;
  // staging: call q covers rows q*32 + (tid>>3); physical 16B-chunk (tid&7)
  // holds logical chunk (tid&7)^((tid>>3)&7)  [source-side swizzle]
  int srow = tid >> 3;
  int scol = ((tid & 7) ^ (srow & 7)) << 3;  // shorts
  const ushort* aS = Ah + (size_t)(by * BM + srow) * K + scol;
  const ushort* wS = Wh + (size_t)(bx * 128 + srow) * K + scol;
  ushort* dA = Lds + wv * 512;
  ushort* dW = Lds + ASH + wv * 512;

  int wm = (wv >> 1) * (BM / 2), wn = (wv & 1) * 64;
  int fr = lane & 15, fq = lane >> 4;
  int rsw = fr & 7;  // read-side swizzle key

  f32x4 acc[NI][4];
#pragma unroll
  for (int i = 0; i < NI; ++i)
#pragma unroll
    for (int j = 0; j < 4; ++j) acc[i][j] = {0.f, 0.f, 0.f, 0.f};

  for (int k0 = 0; k0 < K; k0 += 64) {
#pragma unroll
    for (int q = 0; q < BM / 32; ++q)
      GLOAD16(dA + q * 2048, aS + (size_t)q * 32 * K + k0);
#pragma unroll
    for (int q = 0; q < 4; ++q)
      GLOAD16(dW + q * 2048, wS + (size_t)q * 32 * K + k0);
    __syncthreads();

#pragma unroll
    for (int kh = 0; kh < 2; ++kh) {
      bf16x8 fa[NI], fb[4];
#pragma unroll
      for (int i = 0; i < NI; ++i) {
        int row = wm + i * 16 + fr;
        fa[i] = *(const bf16x8*)(Lds + row * 64 + ((((kh << 2) + fq) ^ rsw) << 3));
      }
#pragma unroll
      for (int j = 0; j < 4; ++j) {
        int row = wn + j * 16 + fr;
        fb[j] = *(const bf16x8*)(Lds + ASH + row * 64 +
                                 ((((kh << 2) + fq) ^ rsw) << 3));
      }
#pragma unroll
      for (int i = 0; i < NI; ++i)
#pragma unroll
        for (int j = 0; j < 4; ++j)
          acc[i][j] = __builtin_amdgcn_mfma_f32_16x16x32_bf16(fa[i], fb[j],
                                                              acc[i][j], 0, 0,
                                                              0);
    }
    __syncthreads();
  }

  int row0 = by * BM + wm;
  int col0 = bx * 128 + wn;
#pragma unroll
  for (int j = 0; j < 4; ++j) {
    int col = col0 + j * 16 + fr;
    float bvv = bias ? bias[col] : 0.f;
#pragma unroll
    for (int i = 0; i < NI; ++i) {
#pragma unroll
      for (int e = 0; e < 4; ++e) {
        int row = row0 + i * 16 + fq * 4 + e;
        float o = acc[i][j][e] + bvv;
        if (EP == 1) {
          o += extra[(row & 255) * N + col];
          outF[(size_t)row * N + col] = o;
        } else if (EP == 2) {
          o += extra[(size_t)row * N + col];
          outF[(size_t)row * N + col] = o;
        } else if (EP == 3) {
          o = 0.5f * o * (1.0f + erff(o * 0.70710678118654752f));
          outH[(size_t)row * N + col] = f2bf(o);
        } else {
          outF[(size_t)row * N + col] = o;
        }
      }
    }
  }
}

// ---------------------------------------------------------------------------
// Attention scores + softmax. Block = (b,h, 32 q-rows), 256 thr (4 waves).
// ---------------------------------------------------------------------------
__global__ __launch_bounds__(256) void attn_score_kernel(
    const float* __restrict__ qkv, const float* __restrict__ rpb,
    const int* __restrict__ rpe, float* __restrict__ P) {
  int bid = blockIdx.x;
  int nb = bid & 7, bh = bid >> 3;
  int b = bh >> 3, h = bh & 7;
  int n0 = nb * 32;
  int tid = threadIdx.x;
  int wv = tid >> 6, lane = tid & 63;
  __shared__ float qs[32][68];
  __shared__ float kts[64][65];
  {
    int r = tid >> 3, seg = (tid & 7) * 8;
    const float* src =
        qkv + ((size_t)(b * 256 + n0 + r)) * 1536 + h * 64 + seg;
    float4 a0 = ((const float4*)src)[0];
    float4 a1 = ((const float4*)src)[1];
    float4 s0 = {a0.x * 0.125f, a0.y * 0.125f, a0.z * 0.125f, a0.w * 0.125f};
    float4 s1 = {a1.x * 0.125f, a1.y * 0.125f, a1.z * 0.125f, a1.w * 0.125f};
    *(float4*)&qs[r][seg] = s0;
    *(float4*)&qs[r][seg + 4] = s1;
  }
  float sreg[8][4];
#pragma unroll 1
  for (int c = 0; c < 4; ++c) {
    __syncthreads();
    {
      int mi = tid >> 2, sg = (tid & 3) * 16;
      const float* ksrc =
          qkv + ((size_t)(b * 256 + c * 64 + mi)) * 1536 + 512 + h * 64 + sg;
#pragma unroll
      for (int e = 0; e < 4; ++e) {
        float4 k4 = ((const float4*)ksrc)[e];
        kts[sg + e * 4 + 0][mi] = k4.x;
        kts[sg + e * 4 + 1][mi] = k4.y;
        kts[sg + e * 4 + 2][mi] = k4.z;
        kts[sg + e * 4 + 3][mi] = k4.w;
      }
    }
    __syncthreads();
    float acc[8];
#pragma unroll
    for (int nn = 0; nn < 8; ++nn) acc[nn] = 0.f;
#pragma unroll 4
    for (int d0 = 0; d0 < 64; d0 += 4) {
      float kv0 = kts[d0 + 0][lane];
      float kv1 = kts[d0 + 1][lane];
      float kv2 = kts[d0 + 2][lane];
      float kv3 = kts[d0 + 3][lane];
#pragma unroll
      for (int nn = 0; nn < 8; ++nn) {
        float4 q4 = *(const float4*)&qs[wv * 8 + nn][d0];
        acc[nn] += q4.x * kv0 + q4.y * kv1 + q4.z * kv2 + q4.w * kv3;
      }
    }
#pragma unroll
    for (int nn = 0; nn < 8; ++nn) {
      int n = n0 + wv * 8 + nn;
      int idx = rpe[n * 256 + c * 64 + lane];
      sreg[nn][c] = acc[nn] + rpb[idx * 8 + h];
    }
  }
#pragma unroll
  for (int nn = 0; nn < 8; ++nn) {
    int n = n0 + wv * 8 + nn;
    float mx = fmaxf(fmaxf(sreg[nn][0], sreg[nn][1]),
                     fmaxf(sreg[nn][2], sreg[nn][3]));
#pragma unroll
    for (int o = 32; o > 0; o >>= 1) mx = fmaxf(mx, __shfl_xor(mx, o, 64));
    float sum = 0.f;
#pragma unroll
    for (int c = 0; c < 4; ++c) {
      sreg[nn][c] = expf(sreg[nn][c] - mx);
      sum += sreg[nn][c];
    }
#pragma unroll
    for (int o = 32; o > 0; o >>= 1) sum += __shfl_xor(sum, o, 64);
    float inv = 1.0f / sum;
    float* Pr = P + ((size_t)bh * 256 + n) * 256;
#pragma unroll
    for (int c = 0; c < 4; ++c) Pr[c * 64 + lane] = sreg[nn][c] * inv;
  }
}

// ---------------------------------------------------------------------------
// O = P @ V -> bf16 plane. Block per (b,h,64-q tile).
// ---------------------------------------------------------------------------
__global__ __launch_bounds__(256) void attn_pv_kernel(
    const float* __restrict__ P, const float* __restrict__ qkv,
    ushort* __restrict__ outH) {
  int bid = blockIdx.x;  // b*32 + h*4 + nt
  int nt = bid & 3, h = (bid >> 2) & 7, b = bid >> 5;
  int tid = threadIdx.x;
  __shared__ float4 Vs4[256 * 16];
  for (int idx = tid; idx < 4096; idx += 256) {
    int m = idx >> 4, d4 = idx & 15;
    Vs4[m * 16 + d4] = *(const float4*)(
        qkv + ((size_t)(b * 256 + m)) * 1536 + 1024 + h * 64 + d4 * 4);
  }
  __syncthreads();

  int d4 = tid & 15, ng = tid >> 4;
  int nbase = nt * 64 + ng * 4;
  const float* P0 = P + ((size_t)((b * 8 + h) * 256 + nbase)) * 256;
  float4 a0 = {0, 0, 0, 0}, a1 = a0, a2 = a0, a3 = a0;
#pragma unroll 2
  for (int m4 = 0; m4 < 64; ++m4) {
    float4 v0 = Vs4[(m4 * 4 + 0) * 16 + d4];
    float4 v1 = Vs4[(m4 * 4 + 1) * 16 + d4];
    float4 v2 = Vs4[(m4 * 4 + 2) * 16 + d4];
    float4 v3 = Vs4[(m4 * 4 + 3) * 16 + d4];
    float4 p;
#define PVACC(A, ROW)                                              \
  p = ((const float4*)(P0 + (ROW)*256))[m4];                       \
  A.x += p.x * v0.x + p.y * v1.x + p.z * v2.x + p.w * v3.x;        \
  A.y += p.x * v0.y + p.y * v1.y + p.z * v2.y + p.w * v3.y;        \
  A.z += p.x * v0.z + p.y * v1.z + p.z * v2.z + p.w * v3.z;        \
  A.w += p.x * v0.w + p.y * v1.w + p.z * v2.w + p.w * v3.w;
    PVACC(a0, 0)
    PVACC(a1, 1)
    PVACC(a2, 2)
    PVACC(a3, 3)
#undef PVACC
  }
  float4 accs[4] = {a0, a1, a2, a3};
#pragma unroll
  for (int i = 0; i < 4; ++i) {
    int n = nbase + i;
    size_t oidx = ((size_t)(b * 256 + n)) * 512 + h * 64 + d4 * 4;
    float vv[4] = {accs[i].x, accs[i].y, accs[i].z, accs[i].w};
    unsigned hw[4];
#pragma unroll
    for (int e = 0; e < 4; ++e) hw[e] = f2bf(vv[e]);
    *(uint2*)(outH + oidx) =
        make_uint2(hw[0] | (hw[1] << 16), hw[2] | (hw[3] << 16));
  }
}

// ---------------------------------------------------------------------------
// LayerNorm over 512, wave per row, 4 rows/block. HL=0 f32, HL=1 bf16 plane.
// ---------------------------------------------------------------------------
template <int HL>
__global__ __launch_bounds__(256) void ln512_kernel(
    const float* __restrict__ X, const float* __restrict__ w,
    const float* __restrict__ bb, float* __restrict__ outF,
    ushort* __restrict__ outH) {
  int row = blockIdx.x * 4 + (threadIdx.x >> 6);
  int t = threadIdx.x & 63;
  const float4* xr = (const float4*)(X + (size_t)row * 512);
  float4 v0 = xr[t * 2], v1 = xr[t * 2 + 1];
  float s = v0.x + v0.y + v0.z + v0.w + v1.x + v1.y + v1.z + v1.w;
#pragma unroll
  for (int o = 32; o > 0; o >>= 1) s += __shfl_xor(s, o, 64);
  float mean = s * (1.0f / 512.0f);
  float dv[8] = {v0.x - mean, v0.y - mean, v0.z - mean, v0.w - mean,
                 v1.x - mean, v1.y - mean, v1.z - mean, v1.w - mean};
  float sq = 0.f;
#pragma unroll
  for (int e = 0; e < 8; ++e) sq += dv[e] * dv[e];
#pragma unroll
  for (int o = 32; o > 0; o >>= 1) sq += __shfl_xor(sq, o, 64);
  float rstd = rsqrtf(sq * (1.0f / 512.0f) + EPSV);
  int c = t * 8;
  float ov[8];
#pragma unroll
  for (int e = 0; e < 8; ++e) ov[e] = dv[e] * rstd * w[c + e] + bb[c + e];
  if (HL == 0) {
    float4 o0 = {ov[0], ov[1], ov[2], ov[3]};
    float4 o1 = {ov[4], ov[5], ov[6], ov[7]};
    ((float4*)(outF + (size_t)row * 512))[t * 2] = o0;
    ((float4*)(outF + (size_t)row * 512))[t * 2 + 1] = o1;
  } else {
    __align__(16) ushort h8[8];
#pragma unroll
    for (int e = 0; e < 8; ++e) h8[e] = f2bf(ov[e]);
    *(bf16x8*)(outH + (size_t)row * 512 + c) = *(bf16x8*)h8;
  }
}

// ---------------------------------------------------------------------------
extern "C" void kernel_launch(void* const* d_in, const int* in_sizes, int n_in,
                              void* d_out, int out_size, void* d_ws,
                              size_t ws_size, hipStream_t stream) {
  const float* x = (const float*)d_in[0];
  const float* patch_w = (const float*)d_in[1];
  const float* patch_b = (const float*)d_in[2];
  const float* pnorm_w = (const float*)d_in[3];
  const float* pnorm_b = (const float*)d_in[4];
  const float* s0_n2w = (const float*)d_in[5];
  const float* s0_n2b = (const float*)d_in[6];
  const float* s0_f1w = (const float*)d_in[7];
  const float* s0_f1b = (const float*)d_in[8];
  const float* s0_f2w = (const float*)d_in[9];
  const float* s0_f2b = (const float*)d_in[10];
  const float* m0_nw = (const float*)d_in[11];
  const float* m0_nb = (const float*)d_in[12];
  const float* m0_rw = (const float*)d_in[13];
  const float* s1_n2w = (const float*)d_in[14];
  const float* s1_n2b = (const float*)d_in[15];
  const float* s1_f1w = (const float*)d_in[16];
  const float* s1_f1b = (const float*)d_in[17];
  const float* s1_f2w = (const float*)d_in[18];
  const float* s1_f2b = (const float*)d_in[19];
  const float* m1_nw = (const float*)d_in[20];
  const float* m1_nb = (const float*)d_in[21];
  const float* m1_rw = (const float*)d_in[22];
  const float* pos_embed = (const float*)d_in[23];
  const float* mb_n1w = (const float*)d_in[24];
  const float* mb_n1b = (const float*)d_in[25];
  const float* mb_qkvw = (const float*)d_in[26];
  const float* mb_qkvb = (const float*)d_in[27];
  const float* mb_rpb = (const float*)d_in[28];
  const float* mb_projw = (const float*)d_in[29];
  const float* mb_projb = (const float*)d_in[30];
  const float* mb_n2w = (const float*)d_in[31];
  const float* mb_n2b = (const float*)d_in[32];
  const float* mb_f1w = (const float*)d_in[33];
  const float* mb_f1b = (const float*)d_in[34];
  const float* mb_f2w = (const float*)d_in[35];
  const float* mb_f2b = (const float*)d_in[36];
  const float* fnorm_w = (const float*)d_in[37];
  const float* fnorm_b = (const float*)d_in[38];
  const int* rpe = (const int*)d_in[39];

  // Workspace layout (104 MB):
  float* Xa = (float*)d_ws;                     // 8,388,608 f (residual)
  ushort* R1h = (ushort*)(Xa + 8388608);        // 4,194,304 sh region
  float* R2f = (float*)(R1h + 4194304);         // 8,388,608 f (P buffer)
  ushort* R2h = (ushort*)R2f;
  float* Qkv = R2f + 8388608;                   // 6,291,456 f
  ushort* Hh = (ushort*)Qkv;                    // stem hidden (aliases Qkv)
  ushort* Wall = (ushort*)(Qkv + 6291456);      // 4,194,304 sh (8 MB)
  ushort* W1h = Wall;                           // stem: up to 1,572,864 sh
  ushort* W2h = Wall + 1572864;

#define CONVH(src, cnt, dh)                                              \
  convh_kernel<<<((cnt) / 4 + 255) / 256, 256, 0, stream>>>(src, dh, (cnt) / 4)

  // Patch embed + pnorm LN -> Xa [65536,128]
  patch_ln2_kernel<<<4096, 256, 0, stream>>>(x, patch_w, patch_b, pnorm_w,
                                             pnorm_b, Xa);

  // Stem stage 0: batch-convert all 8 blocks' weights, then 8 MLP blocks
  CONVH(s0_f1w, 8 * 49152, W1h);
  CONVH(s0_f2w, 8 * 49152, W2h);
  for (int i = 0; i < 8; ++i) {
    lnC_kernel<128><<<65536 / 4, 256, 0, stream>>>(Xa, s0_n2w + i * 128,
                                                   s0_n2b + i * 128, R2h);
    for (int c = 0; c < 4; ++c) {
      size_t off = (size_t)c * 16384 * 128;
      float* Xc = Xa + off;
      mgemm4_kernel<3, 128><<<(16384 / 128) * (384 / 128), 256, 0, stream>>>(
          R2h + off, W1h + i * 49152, s0_f1b + i * 384, nullptr, nullptr, Hh,
          16384, 384, 128);
      mgemm4_kernel<2, 64><<<(16384 / 64) * (128 / 128), 256, 0, stream>>>(
          Hh, W2h + i * 49152, s0_f2b + i * 128, Xc, Xc, nullptr, 16384, 128,
          384);
    }
  }
  // Merge 0 -> R2 plane [16384,512] -> GEMM -> Xa [16384,256]
  merge_ln_kernel<0><<<16384, 256, 0, stream>>>(Xa, m0_nw, m0_nb, R2h);
  CONVH(m0_rw, 131072, Wall);
  mgemm4_kernel<0, 128><<<(16384 / 128) * (256 / 128), 256, 0, stream>>>(
      R2h, Wall, nullptr, nullptr, Xa, nullptr, 16384, 256, 512);

  // Stem stage 1: batch-convert, then 8 MLP blocks
  CONVH(s1_f1w, 8 * 196608, W1h);
  CONVH(s1_f2w, 8 * 196608, W2h);
  for (int i = 0; i < 8; ++i) {
    lnC_kernel<256><<<16384 / 4, 256, 0, stream>>>(Xa, s1_n2w + i * 256,
                                                   s1_n2b + i * 256, R2h);
    for (int c = 0; c < 2; ++c) {
      size_t off = (size_t)c * 8192 * 256;
      float* Xc = Xa + off;
      mgemm4_kernel<3, 128><<<(8192 / 128) * (768 / 128), 256, 0, stream>>>(
          R2h + off, W1h + i * 196608, s1_f1b + i * 768, nullptr, nullptr, Hh,
          8192, 768, 256);
      mgemm4_kernel<2, 64><<<(8192 / 64) * (256 / 128), 256, 0, stream>>>(
          Hh, W2h + i * 196608, s1_f2b + i * 256, Xc, Xc, nullptr, 8192, 256,
          768);
    }
  }
  // Merge 1 -> R2 plane [4096,1024] -> GEMM + pos -> Xa [4096,512]
  merge_ln_kernel<1><<<4096, 256, 0, stream>>>(Xa, m1_nw, m1_nb, R2h);
  CONVH(m1_rw, 524288, Wall);
  mgemm4_kernel<1, 64><<<(4096 / 64) * (512 / 128), 256, 0, stream>>>(
      R2h, Wall, nullptr, pos_embed, Xa, nullptr, 4096, 512, 1024);

  // 20 main attention blocks. Wall: qkvh@0, projh@786432, f1h@1048576,
  // f2h@2097152 (shorts).
  for (int l = 0; l < 20; ++l) {
    conv4_kernel<<<3072, 256, 0, stream>>>(
        mb_qkvw + (size_t)l * 786432, mb_projw + (size_t)l * 262144,
        mb_f1w + (size_t)l * 1048576, mb_f2w + (size_t)l * 1048576, Wall);
    ln512_kernel<1><<<1024, 256, 0, stream>>>(Xa, mb_n1w + l * 512,
                                              mb_n1b + l * 512, nullptr, R1h);
    mgemm4_kernel<0, 128><<<(4096 / 128) * (1536 / 128), 256, 0, stream>>>(
        R1h, Wall, mb_qkvb + l * 1536, nullptr, Qkv, nullptr, 4096, 1536, 512);
    attn_score_kernel<<<1024, 256, 0, stream>>>(Qkv, mb_rpb + l * 7688, rpe,
                                                R2f);
    attn_pv_kernel<<<512, 256, 0, stream>>>(R2f, Qkv, R1h);
    mgemm4_kernel<2, 64><<<(4096 / 64) * (512 / 128), 256, 0, stream>>>(
        R1h, Wall + 786432, mb_projb + l * 512, Xa, Xa, nullptr, 4096, 512,
        512);
    ln512_kernel<1><<<1024, 256, 0, stream>>>(Xa, mb_n2w + l * 512,
                                              mb_n2b + l * 512, nullptr, R1h);
    mgemm4_kernel<3, 128><<<(4096 / 128) * (2048 / 128), 256, 0, stream>>>(
        R1h, Wall + 1048576, mb_f1b + l * 2048, nullptr, nullptr, R2h, 4096,
        2048, 512);
    mgemm4_kernel<2, 64><<<(4096 / 64) * (512 / 128), 256, 0, stream>>>(
        R2h, Wall + 2097152, mb_f2b + l * 512, Xa, Xa, nullptr, 4096, 512,
        2048);
  }
  // Final LN -> d_out (f32)
  ln512_kernel<0><<<1024, 256, 0, stream>>>(Xa, fnorm_w, fnorm_b,
                                            (float*)d_out, nullptr);
}